// Round 3
// baseline (368.891 us; speedup 1.0000x reference)
//
#include <hip/hip_runtime.h>
#include <cstdint>

#define NPRI 33600
#define NGT  256
#define NCLS 80
#define KTOP 13
#define INF_F 1.0e8f
#define EPS_F 1e-7f
#define LOG2_10 3.3219280948873623f
#define SEL_T 1024
#define SEL_W (SEL_T / 64)
#define SCAP 2048

typedef unsigned long long u64;

__device__ __forceinline__ int get_label(const void* p, int j, int is64) {
    if (is64) return (int)((const long long*)p)[j];
    return ((const int*)p)[j];
}

// ---------- fused prep: detect int64 labels + init count/firstgt/nmulti + valid mask ----------
__global__ __launch_bounds__(256) void k_prep(const float* __restrict__ priors,
                                              const float* __restrict__ gt,
                                              const void* labels,
                                              int* valid, int* count, int* firstgt,
                                              int* flag, int* nmulti) {
    __shared__ float4 gbox[NGT];
    __shared__ int    gpad[NGT];
    __shared__ int    bad;
    const int tid = threadIdx.x;
    const int b = blockIdx.x;
    if (b == 0 && tid == 0) { bad = 0; *nmulti = 0; }
    {
        float4 bx = ((const float4*)gt)[tid];
        gbox[tid] = bx;
        gpad[tid] = ((bx.x + bx.y + bx.z + bx.w) > 0.0f) ? 1 : 0;
    }
    __syncthreads();
    if (b == 0 && tid < 128) {
        long long v = ((const long long*)labels)[tid];   // first 1024B, in-bounds for both layouts
        if (v < 0 || v >= NCLS) atomicOr(&bad, 1);
    }
    int i = b * 256 + tid;
    if (i < NPRI) {
        count[i] = 0; firstgt[i] = NGT;
        float4 pr = ((const float4*)priors)[i];
        float px = pr.x, py = pr.y;
        int v = 0;
        for (int j = 0; j < NGT; ++j) {
            float4 bx = gbox[j];
            float m = fminf(fminf(px - bx.x, py - bx.y), fminf(bx.z - px, bx.w - py));
            if (m > 0.0f && gpad[j]) { v = 1; break; }
        }
        valid[i] = v;
    }
    if (b == 0) {
        __syncthreads();
        if (tid == 0) *flag = bad ? 0 : 1;   // 1 => int64 layout
    }
}

// ---------- scores[i][c] -> scoresT[c][i], 64-row tiles ----------
__global__ __launch_bounds__(256) void k_transpose(const float* __restrict__ scores,
                                                   float* __restrict__ scoresT) {
    __shared__ float tile[64][NCLS + 1];
    const int base_i = blockIdx.x * 64;
    const int tid = threadIdx.x;
    for (int k = tid; k < 64 * NCLS; k += 256) {
        int ip = k / NCLS, c = k - ip * NCLS;
        tile[ip][c] = scores[(size_t)(base_i + ip) * NCLS + c];
    }
    __syncthreads();
    for (int k = tid; k < 64 * NCLS; k += 256) {
        int c = k >> 6, ip = k & 63;
        scoresT[(size_t)c * NPRI + base_i + ip] = tile[ip][c];   // 256B contiguous per column
    }
}

__device__ __forceinline__ u64 wave_red_minmax(u64 vmin, u64 vmax, u64* outmax) {
    #pragma unroll
    for (int off = 32; off > 0; off >>= 1) {
        u64 a = __shfl_down(vmin, off, 64);
        u64 b = __shfl_down(vmax, off, 64);
        vmin = (a < vmin) ? a : vmin;
        vmax = (b > vmax) ? b : vmax;
    }
    *outmax = vmax;
    return vmin;
}

// exact formulas — verbatim round-2 (bit-identical selection semantics)
__device__ __forceinline__ float iou_exact(float4 pb, float areap, float gx1, float gy1,
                                           float gx2, float gy2, float areag) {
    float iw = fmaxf(fminf(pb.z, gx2) - fmaxf(pb.x, gx1), 0.0f);
    float ih = fmaxf(fminf(pb.w, gy2) - fmaxf(pb.y, gy1), 0.0f);
    float inter = iw * ih;
    return inter / fmaxf(areap + areag - inter, 1e-6f);
}
__device__ __forceinline__ float cost_exact(float4 pr, float gcx, float gcy,
                                            float l, float iou) {
    float dx = pr.x - gcx, dy = pr.y - gcy;
    float dist = sqrtf(dx * dx + dy * dy) / pr.z;
    float soft = exp2f((dist - 3.0f) * LOG2_10);
    float sig = 1.0f / (1.0f + expf(-l));
    float dd = iou - sig;
    float bce = fmaxf(l, 0.0f) - l * iou + log1pf(expf(-fabsf(l)));
    float iouc = -logf(iou + EPS_F) * 3.0f;
    return bce * (dd * dd) + iouc + soft;
}
// fast approximations (filter only — margins cover their error)
__device__ __forceinline__ float iou_fast(float4 pb, float areap, float gx1, float gy1,
                                          float gx2, float gy2, float areag) {
    float iw = fmaxf(fminf(pb.z, gx2) - fmaxf(pb.x, gx1), 0.0f);
    float ih = fmaxf(fminf(pb.w, gy2) - fmaxf(pb.y, gy1), 0.0f);
    float inter = iw * ih;
    return __fdividef(inter, fmaxf(areap + areag - inter, 1e-6f));
}
__device__ __forceinline__ float cost_fast(float4 pr, float gcx, float gcy,
                                           float l, float iou) {
    float dx = pr.x - gcx, dy = pr.y - gcy;
    float dist = __fdividef(__fsqrt_rn(dx * dx + dy * dy), pr.z);
    float soft = exp2f((dist - 3.0f) * LOG2_10);
    float sig = __fdividef(1.0f, 1.0f + __expf(-l));
    float dd = iou - sig;
    float bce = fmaxf(l, 0.0f) - l * iou + __logf(1.0f + __expf(-fabsf(l)));
    float iouc = -__logf(iou + EPS_F) * 3.0f;
    return bce * (dd * dd) + iouc + soft;
}

// One block per GT: sample->threshold, filtered scan->LDS candidates,
// exact re-select over survivors (fallback: exact full scan on overflow).
__global__ __launch_bounds__(SEL_T, 4) void k_select(
        const float* __restrict__ sc, int rs, int cs,
        const float* __restrict__ priors,
        const float* __restrict__ pboxes, const float* __restrict__ gt,
        const void* labels, const int* flag, const int* __restrict__ valid,
        int* count, int* firstgt) {
    const int tid = threadIdx.x;
    const int j = blockIdx.x;
    const int is64 = *flag;

    const float4 gb = ((const float4*)gt)[j];
    const float gx1 = gb.x, gy1 = gb.y, gx2 = gb.z, gy2 = gb.w;
    const float areag = (gx2 - gx1) * (gy2 - gy1);
    const float gcx = (gx1 + gx2) * 0.5f, gcy = (gy1 + gy2) * 0.5f;
    const int lab = get_label(labels, j, is64);
    const float* scol = sc + (size_t)lab * cs;   // element i at scol[i*rs]

    __shared__ int s_nc, s_ni;
    __shared__ int candc[SCAP];
    __shared__ int candi[SCAP];
    __shared__ u64 redc[SEL_W], redi[SEL_W];
    __shared__ u64 csel[KTOP];
    __shared__ float tiou[KTOP];
    __shared__ int sks;
    const int wid = tid >> 6;

    if (tid == 0) { s_nc = 0; s_ni = 0; }
    __syncthreads();

    // ---- Phase A: per-thread single sample, extract 13th values -> thresholds ----
    float tauc, taui;
    {
        int si = tid * 32;   // < 33600
        float4 pb = ((const float4*)pboxes)[si];
        float areap = (pb.z - pb.x) * (pb.w - pb.y);
        float ai = iou_fast(pb, areap, gx1, gy1, gx2, gy2, areag);
        float ac = INF_F;
        if (valid[si]) {
            float4 pr = ((const float4*)priors)[si];
            ac = cost_fast(pr, gcx, gcy, scol[(size_t)si * rs], ai);
        }
        u64 hc = (((u64)__float_as_uint(ac)) << 32) | (unsigned)si;
        u64 hi = (((u64)__float_as_uint(ai)) << 32) | (unsigned)si;
        for (int r = 0; r < KTOP; ++r) {
            u64 wmax;
            u64 wmin = wave_red_minmax(hc, hi, &wmax);
            if ((tid & 63) == 0) { redc[wid] = wmin; redi[wid] = wmax; }
            __syncthreads();
            u64 bc = redc[0], bi = redi[0];
            #pragma unroll
            for (int q = 1; q < SEL_W; ++q) {
                bc = (redc[q] < bc) ? redc[q] : bc;
                bi = (redi[q] > bi) ? redi[q] : bi;
            }
            if (hc == bc) hc = ~0ull;
            if (hi == bi && bi != 0ull) hi = 0ull;
            if (r == KTOP - 1) {
                tauc = __uint_as_float((unsigned)(bc >> 32));
                taui = __uint_as_float((unsigned)(bi >> 32));
            }
            __syncthreads();
        }
    }
    const float thrc = tauc * 1.004f + 4e-3f;          // loosened: covers approx error
    const float thri = taui * 0.999f - 1e-4f;

    // ---- Phase B: filtered scan, indices -> LDS ----
    for (int i = tid; i < NPRI; i += SEL_T) {
        float4 pb = ((const float4*)pboxes)[i];
        float areap = (pb.z - pb.x) * (pb.w - pb.y);
        float ai = iou_fast(pb, areap, gx1, gy1, gx2, gy2, areag);
        if (ai >= thri) {
            int p = atomicAdd(&s_ni, 1);
            if (p < SCAP) candi[p] = i;
        }
        float ac = INF_F;
        if (valid[i]) {
            float4 pr = ((const float4*)priors)[i];
            ac = cost_fast(pr, gcx, gcy, scol[(size_t)i * rs], ai);
        }
        if (ac <= thrc) {
            int p = atomicAdd(&s_nc, 1);
            if (p < SCAP) candc[p] = i;
        }
    }
    __syncthreads();
    const int nc = s_nc, ni = s_ni;
    const bool ovf = (nc > SCAP) || (ni > SCAP);

    // ---- Phase C: exact selection over survivors (or full fallback) ----
    u64 lc[KTOP];   // min-cost, ascending
    u64 li[KTOP];   // max-iou, ascending
    #pragma unroll
    for (int s = 0; s < KTOP; ++s) { lc[s] = ~0ull; li[s] = 0ull; }

    if (!ovf) {
        for (int k = tid; k < nc; k += SEL_T) {
            int i = candc[k];
            float4 pb = ((const float4*)pboxes)[i];
            float areap = (pb.z - pb.x) * (pb.w - pb.y);
            float iou = iou_exact(pb, areap, gx1, gy1, gx2, gy2, areag);
            float ec = INF_F;
            if (valid[i]) {
                float4 pr = ((const float4*)priors)[i];
                ec = cost_exact(pr, gcx, gcy, scol[(size_t)i * rs], iou);
            }
            u64 ck = (((u64)__float_as_uint(ec)) << 32) | (unsigned)i;
            if (ck < lc[KTOP - 1]) {
                lc[KTOP - 1] = ck;
                #pragma unroll
                for (int s = KTOP - 1; s > 0; --s)
                    if (lc[s] < lc[s - 1]) { u64 t = lc[s]; lc[s] = lc[s - 1]; lc[s - 1] = t; }
            }
        }
        for (int k = tid; k < ni; k += SEL_T) {
            int i = candi[k];
            float4 pb = ((const float4*)pboxes)[i];
            float areap = (pb.z - pb.x) * (pb.w - pb.y);
            float iou = iou_exact(pb, areap, gx1, gy1, gx2, gy2, areag);
            u64 ik = (((u64)__float_as_uint(iou)) << 32) | (unsigned)i;
            if (ik > li[0]) {
                li[0] = ik;
                #pragma unroll
                for (int s = 0; s < KTOP - 1; ++s)
                    if (li[s] > li[s + 1]) { u64 t = li[s]; li[s] = li[s + 1]; li[s + 1] = t; }
            }
        }
    } else {
        // exact full scan (round-2 path) — correctness net, never expected to run
        for (int i = tid; i < NPRI; i += SEL_T) {
            float4 pb = ((const float4*)pboxes)[i];
            float areap = (pb.z - pb.x) * (pb.w - pb.y);
            float iou = iou_exact(pb, areap, gx1, gy1, gx2, gy2, areag);
            u64 ik = (((u64)__float_as_uint(iou)) << 32) | (unsigned)i;
            if (ik > li[0]) {
                li[0] = ik;
                #pragma unroll
                for (int s = 0; s < KTOP - 1; ++s)
                    if (li[s] > li[s + 1]) { u64 t = li[s]; li[s] = li[s + 1]; li[s + 1] = t; }
            }
            float ec = INF_F;
            if (valid[i]) {
                float4 pr = ((const float4*)priors)[i];
                ec = cost_exact(pr, gcx, gcy, scol[(size_t)i * rs], iou);
            }
            u64 ck = (((u64)__float_as_uint(ec)) << 32) | (unsigned)i;
            if (ck < lc[KTOP - 1]) {
                lc[KTOP - 1] = ck;
                #pragma unroll
                for (int s = KTOP - 1; s > 0; --s)
                    if (lc[s] < lc[s - 1]) { u64 t = lc[s]; lc[s] = lc[s - 1]; lc[s - 1] = t; }
            }
        }
    }

    // ---- fused 13-round merge (round-2 verbatim) ----
    int pc = 0, pi = 0;
    for (int r = 0; r < KTOP; ++r) {
        u64 curc = ~0ull, curi = 0ull;
        #pragma unroll
        for (int s = 0; s < KTOP; ++s) {
            if (s == pc) curc = lc[s];
            if (s == pi) curi = li[KTOP - 1 - s];
        }
        u64 wmax;
        u64 wmin = wave_red_minmax(curc, curi, &wmax);
        if ((tid & 63) == 0) { redc[wid] = wmin; redi[wid] = wmax; }
        __syncthreads();
        u64 bc = redc[0], bi = redi[0];
        #pragma unroll
        for (int q = 1; q < SEL_W; ++q) {
            bc = (redc[q] < bc) ? redc[q] : bc;
            bi = (redi[q] > bi) ? redi[q] : bi;
        }
        if (curc == bc) pc++;
        if (curi == bi && bi != 0ull) pi++;
        if (tid == 0) { csel[r] = bc; tiou[r] = __uint_as_float((unsigned)(bi >> 32)); }
        __syncthreads();
    }

    if (tid == 0) {
        float s = 0.0f;
        for (int r = 0; r < KTOP; ++r) s += tiou[r];  // descending-order sum
        int ks = (int)s;
        if (ks < 1) ks = 1;
        sks = ks;
    }
    __syncthreads();
    if (tid < KTOP && tid < sks) {
        int idx = (int)(unsigned)(csel[tid] & 0xFFFFFFFFull);
        atomicAdd(&count[idx], 1);
        atomicMin(&firstgt[idx], j);
    }
}

// ---------- per-prior finalize; multi-matched priors -> worklist ----------
__global__ __launch_bounds__(256) void k_assign(
        const float* __restrict__ pboxes, const float* __restrict__ gt,
        const void* labels, const int* flag, const int* __restrict__ valid,
        const int* __restrict__ count, const int* __restrict__ firstgt,
        int* nmulti, int* mlist, float* __restrict__ out) {
    __shared__ float4 gbox[NGT];
    __shared__ int glab[NGT];
    __shared__ float gareas[NGT];
    int tid = threadIdx.x;
    int is64 = *flag;
    {
        float4 b = ((const float4*)gt)[tid];
        gbox[tid] = b;
        glab[tid] = get_label(labels, tid, is64);
        gareas[tid] = (b.z - b.x) * (b.w - b.y);
    }
    __syncthreads();
    int i = blockIdx.x * 256 + tid;
    if (i >= NPRI) return;
    int v = valid[i];
    int c = count[i];
    float o0 = 0.0f, o1 = -INF_F, o2 = -1.0f;
    if (v && c == 1) {
        int j = firstgt[i];
        float4 pb = ((const float4*)pboxes)[i];
        float areap = (pb.z - pb.x) * (pb.w - pb.y);
        float4 g = gbox[j];
        float iw = fmaxf(fminf(pb.z, g.z) - fmaxf(pb.x, g.x), 0.0f);
        float ih = fmaxf(fminf(pb.w, g.w) - fmaxf(pb.y, g.y), 0.0f);
        float inter = iw * ih;
        float iou = inter / fmaxf(areap + gareas[j] - inter, 1e-6f);
        o0 = (float)(j + 1); o1 = iou; o2 = (float)glab[j];
    } else if (v && c > 1) {
        int pos = atomicAdd(nmulti, 1);
        mlist[pos] = i;
    }
    out[i] = o0;
    out[NPRI + i] = o1;
    out[2 * NPRI + i] = o2;
}

// ---------- one block per multi prior: block argmin over 256 GT costs ----------
__global__ __launch_bounds__(256) void k_multi(
        const float* __restrict__ sc, int rs, int cs,
        const float* __restrict__ priors,
        const float* __restrict__ pboxes, const float* __restrict__ gt,
        const void* labels, const int* flag,
        const int* __restrict__ nmulti, const int* __restrict__ mlist,
        float* __restrict__ out) {
    __shared__ float4 gbox[NGT];
    __shared__ int glab[NGT];
    __shared__ float gcxs[NGT], gcys[NGT], gareas[NGT];
    __shared__ u64 red4[4];
    const int tid = threadIdx.x;
    const int is64 = *flag;
    {
        float4 b = ((const float4*)gt)[tid];
        gbox[tid] = b;
        glab[tid] = get_label(labels, tid, is64);
        gcxs[tid] = (b.x + b.z) * 0.5f;
        gcys[tid] = (b.y + b.w) * 0.5f;
        gareas[tid] = (b.z - b.x) * (b.w - b.y);
    }
    __syncthreads();
    const int nm = *nmulti;
    const int j = tid;
    for (int m = blockIdx.x; m < nm; m += gridDim.x) {
        const int i = mlist[m];
        float4 pb = ((const float4*)pboxes)[i];
        float areap = (pb.z - pb.x) * (pb.w - pb.y);
        float4 pr = ((const float4*)priors)[i];

        float4 g = gbox[j];
        float iw = fmaxf(fminf(pb.z, g.z) - fmaxf(pb.x, g.x), 0.0f);
        float ih = fmaxf(fminf(pb.w, g.w) - fmaxf(pb.y, g.y), 0.0f);
        float inter = iw * ih;
        float iou = inter / fmaxf(areap + gareas[j] - inter, 1e-6f);
        float dx = pr.x - gcxs[j], dy = pr.y - gcys[j];
        float dist = sqrtf(dx * dx + dy * dy) / pr.z;
        float soft = exp2f((dist - 3.0f) * LOG2_10);
        float l = sc[(size_t)i * rs + (size_t)glab[j] * cs];
        float sig = 1.0f / (1.0f + expf(-l));
        float dd = iou - sig;
        float bce = fmaxf(l, 0.0f) - l * iou + log1pf(expf(-fabsf(l)));
        float cost = bce * (dd * dd) + (-logf(iou + EPS_F) * 3.0f) + soft;

        u64 key = (((u64)__float_as_uint(cost)) << 32) | (unsigned)j;
        u64 v = key;
        #pragma unroll
        for (int off = 32; off > 0; off >>= 1) {
            u64 o = __shfl_down(v, off, 64);
            v = (o < v) ? o : v;
        }
        if ((tid & 63) == 0) red4[tid >> 6] = v;
        __syncthreads();
        u64 best = red4[0];
        #pragma unroll
        for (int q = 1; q < 4; ++q) best = (red4[q] < best) ? red4[q] : best;
        if (key == best) {
            out[i] = (float)(j + 1);
            out[NPRI + i] = iou;
            out[2 * NPRI + i] = (float)glab[j];
        }
        __syncthreads();
    }
}

extern "C" void kernel_launch(void* const* d_in, const int* in_sizes, int n_in,
                              void* d_out, int out_size, void* d_ws, size_t ws_size,
                              hipStream_t stream) {
    const float* scores = (const float*)d_in[0];
    const float* priors = (const float*)d_in[1];
    const float* pboxes = (const float*)d_in[2];
    const float* gt     = (const float*)d_in[3];
    const void*  labels = d_in[4];
    float* out = (float*)d_out;

    char* ws = (char*)d_ws;
    int*   flag    = (int*)ws;
    int*   nmulti  = (int*)(ws + 64);
    int*   count   = (int*)(ws + 128);
    int*   firstgt = (int*)(ws + 128 + (size_t)NPRI * 4);
    int*   valid   = (int*)(ws + 128 + (size_t)NPRI * 8);
    int*   mlist   = (int*)(ws + 128 + (size_t)NPRI * 12);         // 16 KiB
    float* scoresT = (float*)(ws + 128 + (size_t)NPRI * 12 + 16384 + 192);
    const size_t need_T = 128 + (size_t)NPRI * 12 + 16384 + 192 + (size_t)NPRI * NCLS * 4;
    const bool useT = (ws_size >= need_T);

    hipLaunchKernelGGL(k_prep, dim3((NPRI + 255) / 256), dim3(256), 0, stream,
                       priors, gt, labels, valid, count, firstgt, flag, nmulti);

    const float* sc = scores; int rs = NCLS, cs = 1;
    if (useT) {
        hipLaunchKernelGGL(k_transpose, dim3(NPRI / 64), dim3(256), 0, stream, scores, scoresT);
        sc = scoresT; rs = 1; cs = NPRI;
    }
    hipLaunchKernelGGL(k_select, dim3(NGT), dim3(SEL_T), 0, stream,
                       sc, rs, cs, priors, pboxes, gt, labels, flag, valid, count, firstgt);
    hipLaunchKernelGGL(k_assign, dim3((NPRI + 255) / 256), dim3(256), 0, stream,
                       pboxes, gt, labels, flag, valid, count, firstgt, nmulti, mlist, out);
    hipLaunchKernelGGL(k_multi, dim3(96), dim3(256), 0, stream,
                       sc, rs, cs, priors, pboxes, gt, labels, flag, nmulti, mlist, out);
}

// Round 4
// 281.670 us; speedup vs baseline: 1.3097x; 1.3097x over previous
//
#include <hip/hip_runtime.h>
#include <cstdint>

#define NPRI 33600
#define NGT  256
#define NCLS 80
#define KTOP 13
#define INF_F 1.0e8f
#define EPS_F 1e-7f
#define LOG2_10 3.3219280948873623f
#define SEL_T 1024
#define SEL_W (SEL_T / 64)
#define SCAP 2048
#define PREP_BLKS ((NPRI + 255) / 256)
#define TR_BLKS (NPRI / 64)

typedef unsigned long long u64;

__device__ __forceinline__ int get_label(const void* p, int j, int is64) {
    if (is64) return (int)((const long long*)p)[j];
    return ((const int*)p)[j];
}

// ---------- fused: prep (detect int64 + init + valid mask) and scores transpose ----------
__global__ __launch_bounds__(256) void k_prep_tr(
        const float* __restrict__ priors, const float* __restrict__ gt,
        const void* labels, const float* __restrict__ scores,
        float* __restrict__ scoresT,
        int* valid, int* count, int* firstgt, int* flag, int* nmulti, int useT) {
    const int tid = threadIdx.x;
    if (blockIdx.x < PREP_BLKS) {
        __shared__ float4 gbox[NGT];
        __shared__ int    gpad[NGT];
        __shared__ int    bad;
        const int b = blockIdx.x;
        if (b == 0 && tid == 0) { bad = 0; *nmulti = 0; }
        {
            float4 bx = ((const float4*)gt)[tid];
            gbox[tid] = bx;
            gpad[tid] = ((bx.x + bx.y + bx.z + bx.w) > 0.0f) ? 1 : 0;
        }
        __syncthreads();
        if (b == 0 && tid < 128) {
            long long v = ((const long long*)labels)[tid];   // first 1024B: in-bounds for both layouts
            if (v < 0 || v >= NCLS) atomicOr(&bad, 1);
        }
        int i = b * 256 + tid;
        if (i < NPRI) {
            count[i] = 0; firstgt[i] = NGT;
            float4 pr = ((const float4*)priors)[i];
            float px = pr.x, py = pr.y;
            int v = 0;
            for (int j = 0; j < NGT; ++j) {
                float4 bx = gbox[j];
                float m = fminf(fminf(px - bx.x, py - bx.y), fminf(bx.z - px, bx.w - py));
                if (m > 0.0f && gpad[j]) { v = 1; break; }
            }
            valid[i] = v;
        }
        if (b == 0) {
            __syncthreads();
            if (tid == 0) *flag = bad ? 0 : 1;   // 1 => int64 layout
        }
    } else if (useT) {
        __shared__ float tile[64][NCLS + 1];
        const int base_i = (blockIdx.x - PREP_BLKS) * 64;
        for (int k = tid; k < 64 * NCLS; k += 256) {
            int ip = k / NCLS, c = k - ip * NCLS;
            tile[ip][c] = scores[(size_t)(base_i + ip) * NCLS + c];
        }
        __syncthreads();
        for (int k = tid; k < 64 * NCLS; k += 256) {
            int c = k >> 6, ip = k & 63;
            scoresT[(size_t)c * NPRI + base_i + ip] = tile[ip][c];
        }
    }
}

// ---------- reduce helpers ----------
__device__ __forceinline__ float wave_min_f32(float v) {
    #pragma unroll
    for (int off = 32; off > 0; off >>= 1) v = fminf(v, __shfl_down(v, off, 64));
    return v;
}
__device__ __forceinline__ u64 wave_min_u64(u64 v) {
    #pragma unroll
    for (int off = 32; off > 0; off >>= 1) { u64 o = __shfl_down(v, off, 64); v = (o < v) ? o : v; }
    return v;
}
__device__ __forceinline__ u64 wave_max_u64(u64 v) {
    #pragma unroll
    for (int off = 32; off > 0; off >>= 1) { u64 o = __shfl_down(v, off, 64); v = (o > v) ? o : v; }
    return v;
}

// ---------- exact formulas (verbatim round-2: bit-identical selection) ----------
__device__ __forceinline__ float iou_exact(float4 pb, float areap, float gx1, float gy1,
                                           float gx2, float gy2, float areag) {
    float iw = fmaxf(fminf(pb.z, gx2) - fmaxf(pb.x, gx1), 0.0f);
    float ih = fmaxf(fminf(pb.w, gy2) - fmaxf(pb.y, gy1), 0.0f);
    float inter = iw * ih;
    return inter / fmaxf(areap + areag - inter, 1e-6f);
}
__device__ __forceinline__ float cost_exact(float4 pr, float gcx, float gcy,
                                            float l, float iou) {
    float dx = pr.x - gcx, dy = pr.y - gcy;
    float dist = sqrtf(dx * dx + dy * dy) / pr.z;
    float soft = exp2f((dist - 3.0f) * LOG2_10);
    float sig = 1.0f / (1.0f + expf(-l));
    float dd = iou - sig;
    float bce = fmaxf(l, 0.0f) - l * iou + log1pf(expf(-fabsf(l)));
    float iouc = -logf(iou + EPS_F) * 3.0f;
    return bce * (dd * dd) + iouc + soft;
}
// fast cost (filter only; all terms >=0, rel err ~2e-4 — covered by margin)
__device__ __forceinline__ float cost_fast(float4 pr, float gcx, float gcy,
                                           float l, float iou) {
    float dx = pr.x - gcx, dy = pr.y - gcy;
    float dist = __fdividef(__fsqrt_rn(dx * dx + dy * dy), pr.z);
    float soft = exp2f((dist - 3.0f) * LOG2_10);
    float sig = __fdividef(1.0f, 1.0f + __expf(-l));
    float dd = iou - sig;
    float bce = fmaxf(l, 0.0f) - l * iou + __logf(1.0f + __expf(-fabsf(l)));
    float iouc = -__logf(iou + EPS_F) * 3.0f;
    return bce * (dd * dd) + iouc + soft;
}

// One block (1024 thr) per GT: exact in-scan iou top-13 (values for ks),
// sampled-threshold filter for cost candidates, exact re-select; guarded fallback.
__global__ __launch_bounds__(SEL_T, 4) void k_select(
        const float* __restrict__ sc, int rs, int cs,
        const float* __restrict__ priors,
        const float* __restrict__ pboxes, const float* __restrict__ gt,
        const void* labels, const int* flag, const int* __restrict__ valid,
        int* count, int* firstgt) {
    const int tid = threadIdx.x;
    const int j = blockIdx.x;
    const int is64 = *flag;

    const float4 gb = ((const float4*)gt)[j];
    const float gx1 = gb.x, gy1 = gb.y, gx2 = gb.z, gy2 = gb.w;
    const float areag = (gx2 - gx1) * (gy2 - gy1);
    const float gcx = (gx1 + gx2) * 0.5f, gcy = (gy1 + gy2) * 0.5f;
    const int lab = get_label(labels, j, is64);
    const float* scol = sc + (size_t)lab * cs;   // element i at scol[i*rs]

    __shared__ int s_nc;
    __shared__ int candc[SCAP];
    __shared__ float redf[SEL_W];
    __shared__ u64 redu[SEL_W];
    __shared__ u64 csel[KTOP];
    __shared__ float tiou[KTOP];
    __shared__ int sks;
    const int wid = tid >> 6;

    if (tid == 0) s_nc = 0;

    // ---- Phase A: sampled fast-cost -> 13th-smallest threshold ----
    float ac = INF_F;
    {
        int si = tid * 32;   // 32736 max < NPRI
        float4 pb = ((const float4*)pboxes)[si];
        float areap = (pb.z - pb.x) * (pb.w - pb.y);
        float iw = fmaxf(fminf(pb.z, gx2) - fmaxf(pb.x, gx1), 0.0f);
        float ih = fmaxf(fminf(pb.w, gy2) - fmaxf(pb.y, gy1), 0.0f);
        float inter = iw * ih;
        float iou = inter / fmaxf(areap + areag - inter, 1e-6f);
        if (valid[si]) {
            float4 pr = ((const float4*)priors)[si];
            ac = cost_fast(pr, gcx, gcy, scol[(size_t)si * rs], iou);
        }
    }
    __syncthreads();
    float tauc = INF_F;
    {
        float cur = ac;
        for (int r = 0; r < KTOP; ++r) {
            float wm = wave_min_f32(cur);
            if ((tid & 63) == 0) redf[wid] = wm;
            __syncthreads();
            float bm = redf[0];
            #pragma unroll
            for (int q = 1; q < SEL_W; ++q) bm = fminf(bm, redf[q]);
            if (cur == bm) cur = __int_as_float(0x7f800000);   // eliminate (ties: looser, still valid)
            if (r == KTOP - 1) tauc = bm;
            __syncthreads();
        }
    }
    const float thrc = tauc * 1.004f + 4e-3f;
    // INF-ambiguity zone (reference's top-13 could contain invalid 1e8 entries) -> full scan
    const bool zone_bad = !(tauc < 9.0e7f);

    // ---- Phase B: scan. Exact iou top-13 values (u64 key, value-strict entry) + cost filter ----
    u64 li[KTOP];
    #pragma unroll
    for (int s = 0; s < KTOP; ++s) li[s] = 0ull;

    for (int i = tid; i < NPRI; i += SEL_T) {
        float4 pb = ((const float4*)pboxes)[i];
        float areap = (pb.z - pb.x) * (pb.w - pb.y);
        float iw = fmaxf(fminf(pb.z, gx2) - fmaxf(pb.x, gx1), 0.0f);
        float ih = fmaxf(fminf(pb.w, gy2) - fmaxf(pb.y, gy1), 0.0f);
        float inter = iw * ih;
        float iou = inter / fmaxf(areap + areag - inter, 1e-6f);   // exact (0 when inter==0)
        unsigned ib = __float_as_uint(iou);
        if (ib > (unsigned)(li[0] >> 32)) {                        // value-strict: zeros never enter
            li[0] = (((u64)ib) << 32) | (unsigned)i;
            #pragma unroll
            for (int s = 0; s < KTOP - 1; ++s)
                if (li[s] > li[s + 1]) { u64 t = li[s]; li[s] = li[s + 1]; li[s + 1] = t; }
        }
        if (!zone_bad && valid[i]) {
            float4 pr = ((const float4*)priors)[i];
            float af = cost_fast(pr, gcx, gcy, scol[(size_t)i * rs], iou);
            if (af <= thrc) {
                int p = atomicAdd(&s_nc, 1);
                if (p < SCAP) candc[p] = i;
            }
        }
    }
    __syncthreads();
    const int nc = s_nc;
    const bool full = zone_bad || (nc > SCAP);

    // ---- iou merge: 13 rounds, keys keep idx -> cross-thread duplicates preserved ----
    {
        int p = 0;
        for (int r = 0; r < KTOP; ++r) {
            u64 cur = 0ull;
            #pragma unroll
            for (int s = 0; s < KTOP; ++s) if (s == p) cur = li[KTOP - 1 - s];  // descending
            u64 wm = wave_max_u64(cur);
            if ((tid & 63) == 0) redu[wid] = wm;
            __syncthreads();
            u64 bm = redu[0];
            #pragma unroll
            for (int q = 1; q < SEL_W; ++q) bm = (redu[q] > bm) ? redu[q] : bm;
            if (cur == bm && bm != 0ull) p++;
            if (tid == 0) tiou[r] = __uint_as_float((unsigned)(bm >> 32));
            __syncthreads();
        }
    }

    // ---- Phase C: exact cost top-13 over survivors (or full exact scan) ----
    u64 lc[KTOP];
    #pragma unroll
    for (int s = 0; s < KTOP; ++s) lc[s] = ~0ull;

    if (!full) {
        for (int k = tid; k < nc; k += SEL_T) {
            int i = candc[k];                    // pushed only when valid
            float4 pb = ((const float4*)pboxes)[i];
            float areap = (pb.z - pb.x) * (pb.w - pb.y);
            float iou = iou_exact(pb, areap, gx1, gy1, gx2, gy2, areag);
            float4 pr = ((const float4*)priors)[i];
            float ec = cost_exact(pr, gcx, gcy, scol[(size_t)i * rs], iou);
            u64 ck = (((u64)__float_as_uint(ec)) << 32) | (unsigned)i;
            if (ck < lc[KTOP - 1]) {
                lc[KTOP - 1] = ck;
                #pragma unroll
                for (int s = KTOP - 1; s > 0; --s)
                    if (lc[s] < lc[s - 1]) { u64 t = lc[s]; lc[s] = lc[s - 1]; lc[s - 1] = t; }
            }
        }
    } else {
        for (int i = tid; i < NPRI; i += SEL_T) {
            float4 pb = ((const float4*)pboxes)[i];
            float areap = (pb.z - pb.x) * (pb.w - pb.y);
            float iou = iou_exact(pb, areap, gx1, gy1, gx2, gy2, areag);
            float ec = INF_F;
            if (valid[i]) {
                float4 pr = ((const float4*)priors)[i];
                ec = cost_exact(pr, gcx, gcy, scol[(size_t)i * rs], iou);
            }
            u64 ck = (((u64)__float_as_uint(ec)) << 32) | (unsigned)i;
            if (ck < lc[KTOP - 1]) {
                lc[KTOP - 1] = ck;
                #pragma unroll
                for (int s = KTOP - 1; s > 0; --s)
                    if (lc[s] < lc[s - 1]) { u64 t = lc[s]; lc[s] = lc[s - 1]; lc[s - 1] = t; }
            }
        }
    }

    // ---- cost merge: 13 rounds (min; smallest idx on ties = lax.top_k tie-break) ----
    {
        int p = 0;
        for (int r = 0; r < KTOP; ++r) {
            u64 cur = ~0ull;
            #pragma unroll
            for (int s = 0; s < KTOP; ++s) if (s == p) cur = lc[s];
            u64 wm = wave_min_u64(cur);
            if ((tid & 63) == 0) redu[wid] = wm;
            __syncthreads();
            u64 bm = redu[0];
            #pragma unroll
            for (int q = 1; q < SEL_W; ++q) bm = (redu[q] < bm) ? redu[q] : bm;
            if (cur == bm) p++;
            if (tid == 0) csel[r] = bm;
            __syncthreads();
        }
    }

    if (tid == 0) {
        float s = 0.0f;
        for (int r = 0; r < KTOP; ++r) s += tiou[r];  // descending-order sum (matches ref)
        int ks = (int)s;
        if (ks < 1) ks = 1;
        sks = ks;
    }
    __syncthreads();
    if (tid < KTOP && tid < sks) {
        u64 k = csel[tid];
        if (k != ~0ull) {
            int idx = (int)(unsigned)(k & 0xFFFFFFFFull);
            atomicAdd(&count[idx], 1);
            atomicMin(&firstgt[idx], j);
        }
    }
}

// ---------- per-prior finalize; multi-matched priors -> worklist ----------
__global__ __launch_bounds__(256) void k_assign(
        const float* __restrict__ pboxes, const float* __restrict__ gt,
        const void* labels, const int* flag, const int* __restrict__ valid,
        const int* __restrict__ count, const int* __restrict__ firstgt,
        int* nmulti, int* mlist, float* __restrict__ out) {
    __shared__ float4 gbox[NGT];
    __shared__ int glab[NGT];
    __shared__ float gareas[NGT];
    int tid = threadIdx.x;
    int is64 = *flag;
    {
        float4 b = ((const float4*)gt)[tid];
        gbox[tid] = b;
        glab[tid] = get_label(labels, tid, is64);
        gareas[tid] = (b.z - b.x) * (b.w - b.y);
    }
    __syncthreads();
    int i = blockIdx.x * 256 + tid;
    if (i >= NPRI) return;
    int v = valid[i];
    int c = count[i];
    float o0 = 0.0f, o1 = -INF_F, o2 = -1.0f;
    if (v && c == 1) {
        int j = firstgt[i];
        float4 pb = ((const float4*)pboxes)[i];
        float areap = (pb.z - pb.x) * (pb.w - pb.y);
        float4 g = gbox[j];
        float iw = fmaxf(fminf(pb.z, g.z) - fmaxf(pb.x, g.x), 0.0f);
        float ih = fmaxf(fminf(pb.w, g.w) - fmaxf(pb.y, g.y), 0.0f);
        float inter = iw * ih;
        float iou = inter / fmaxf(areap + gareas[j] - inter, 1e-6f);
        o0 = (float)(j + 1); o1 = iou; o2 = (float)glab[j];
    } else if (v && c > 1) {
        int pos = atomicAdd(nmulti, 1);
        mlist[pos] = i;
    }
    out[i] = o0;
    out[NPRI + i] = o1;
    out[2 * NPRI + i] = o2;
}

// ---------- one block per multi prior: block argmin over 256 GT costs ----------
__global__ __launch_bounds__(256) void k_multi(
        const float* __restrict__ sc, int rs, int cs,
        const float* __restrict__ priors,
        const float* __restrict__ pboxes, const float* __restrict__ gt,
        const void* labels, const int* flag,
        const int* __restrict__ nmulti, const int* __restrict__ mlist,
        float* __restrict__ out) {
    __shared__ float4 gbox[NGT];
    __shared__ int glab[NGT];
    __shared__ float gcxs[NGT], gcys[NGT], gareas[NGT];
    __shared__ u64 red4[4];
    const int tid = threadIdx.x;
    const int is64 = *flag;
    {
        float4 b = ((const float4*)gt)[tid];
        gbox[tid] = b;
        glab[tid] = get_label(labels, tid, is64);
        gcxs[tid] = (b.x + b.z) * 0.5f;
        gcys[tid] = (b.y + b.w) * 0.5f;
        gareas[tid] = (b.z - b.x) * (b.w - b.y);
    }
    __syncthreads();
    const int nm = *nmulti;
    const int j = tid;
    for (int m = blockIdx.x; m < nm; m += gridDim.x) {
        const int i = mlist[m];
        float4 pb = ((const float4*)pboxes)[i];
        float areap = (pb.z - pb.x) * (pb.w - pb.y);
        float4 pr = ((const float4*)priors)[i];

        float4 g = gbox[j];
        float iw = fmaxf(fminf(pb.z, g.z) - fmaxf(pb.x, g.x), 0.0f);
        float ih = fmaxf(fminf(pb.w, g.w) - fmaxf(pb.y, g.y), 0.0f);
        float inter = iw * ih;
        float iou = inter / fmaxf(areap + gareas[j] - inter, 1e-6f);
        float dx = pr.x - gcxs[j], dy = pr.y - gcys[j];
        float dist = sqrtf(dx * dx + dy * dy) / pr.z;
        float soft = exp2f((dist - 3.0f) * LOG2_10);
        float l = sc[(size_t)i * rs + (size_t)glab[j] * cs];
        float sig = 1.0f / (1.0f + expf(-l));
        float dd = iou - sig;
        float bce = fmaxf(l, 0.0f) - l * iou + log1pf(expf(-fabsf(l)));
        float cost = bce * (dd * dd) + (-logf(iou + EPS_F) * 3.0f) + soft;

        u64 key = (((u64)__float_as_uint(cost)) << 32) | (unsigned)j;
        u64 v = key;
        #pragma unroll
        for (int off = 32; off > 0; off >>= 1) {
            u64 o = __shfl_down(v, off, 64);
            v = (o < v) ? o : v;
        }
        if ((tid & 63) == 0) red4[tid >> 6] = v;
        __syncthreads();
        u64 best = red4[0];
        #pragma unroll
        for (int q = 1; q < 4; ++q) best = (red4[q] < best) ? red4[q] : best;
        if (key == best) {
            out[i] = (float)(j + 1);
            out[NPRI + i] = iou;
            out[2 * NPRI + i] = (float)glab[j];
        }
        __syncthreads();
    }
}

extern "C" void kernel_launch(void* const* d_in, const int* in_sizes, int n_in,
                              void* d_out, int out_size, void* d_ws, size_t ws_size,
                              hipStream_t stream) {
    const float* scores = (const float*)d_in[0];
    const float* priors = (const float*)d_in[1];
    const float* pboxes = (const float*)d_in[2];
    const float* gt     = (const float*)d_in[3];
    const void*  labels = d_in[4];
    float* out = (float*)d_out;

    char* ws = (char*)d_ws;
    int*   flag    = (int*)ws;
    int*   nmulti  = (int*)(ws + 64);
    int*   count   = (int*)(ws + 128);
    int*   firstgt = (int*)(ws + 128 + (size_t)NPRI * 4);
    int*   valid   = (int*)(ws + 128 + (size_t)NPRI * 8);
    int*   mlist   = (int*)(ws + 128 + (size_t)NPRI * 12);
    float* scoresT = (float*)(ws + 128 + (size_t)NPRI * 12 + 16384 + 192);
    const size_t need_T = 128 + (size_t)NPRI * 12 + 16384 + 192 + (size_t)NPRI * NCLS * 4;
    const int useT = (ws_size >= need_T) ? 1 : 0;

    hipLaunchKernelGGL(k_prep_tr, dim3(PREP_BLKS + (useT ? TR_BLKS : 0)), dim3(256), 0, stream,
                       priors, gt, labels, scores, scoresT, valid, count, firstgt, flag, nmulti, useT);

    const float* sc = scores; int rs = NCLS, cs = 1;
    if (useT) { sc = scoresT; rs = 1; cs = NPRI; }

    hipLaunchKernelGGL(k_select, dim3(NGT), dim3(SEL_T), 0, stream,
                       sc, rs, cs, priors, pboxes, gt, labels, flag, valid, count, firstgt);
    hipLaunchKernelGGL(k_assign, dim3((NPRI + 255) / 256), dim3(256), 0, stream,
                       pboxes, gt, labels, flag, valid, count, firstgt, nmulti, mlist, out);
    hipLaunchKernelGGL(k_multi, dim3(256), dim3(256), 0, stream,
                       sc, rs, cs, priors, pboxes, gt, labels, flag, nmulti, mlist, out);
}

// Round 5
// 258.522 us; speedup vs baseline: 1.4269x; 1.0895x over previous
//
#include <hip/hip_runtime.h>
#include <cstdint>

#define NPRI 33600
#define NGT  256
#define NCLS 80
#define KTOP 13
#define INF_F 1.0e8f
#define EPS_F 1e-7f
#define L10 3.3219280948873623f
#define SEL_T 512
#define NW (SEL_T / 64)
#define SCAP 2048
#define PREP_BLKS ((NPRI + 255) / 256)
#define TR_BLKS (NPRI / 64)

typedef unsigned long long u64;

__device__ __forceinline__ int get_label(const void* p, int j, int is64) {
    if (is64) return (int)((const long long*)p)[j];
    return ((const int*)p)[j];
}

// ---------- fused prep (detect+init+valid+pri2) and scores transpose ----------
__global__ __launch_bounds__(256) void k_prep_tr(
        const float* __restrict__ priors, const float* __restrict__ gt,
        const void* labels, const float* __restrict__ scores,
        float* __restrict__ scoresT, float4* __restrict__ pri2,
        int* count, int* firstgt, int* flag, int* nmulti, int useT) {
    const int tid = threadIdx.x;
    if (blockIdx.x < PREP_BLKS) {
        __shared__ float4 gbox[NGT];
        __shared__ int    gpad[NGT];
        __shared__ int    bad;
        const int b = blockIdx.x;
        if (b == 0 && tid == 0) { bad = 0; *nmulti = 0; }
        {
            float4 bx = ((const float4*)gt)[tid];
            gbox[tid] = bx;
            gpad[tid] = ((bx.x + bx.y + bx.z + bx.w) > 0.0f) ? 1 : 0;
        }
        __syncthreads();
        if (b == 0 && tid < 128) {
            long long v = ((const long long*)labels)[tid];   // first 1024B: in-bounds either layout
            if (v < 0 || v >= NCLS) atomicOr(&bad, 1);
        }
        int i = b * 256 + tid;
        if (i < NPRI) {
            count[i] = 0; firstgt[i] = NGT;
            float4 pr = ((const float4*)priors)[i];
            float px = pr.x, py = pr.y;
            int v = 0;
            for (int j = 0; j < NGT; ++j) {
                float4 bx = gbox[j];
                float m = fminf(fminf(px - bx.x, py - bx.y), fminf(bx.z - px, bx.w - py));
                if (m > 0.0f && gpad[j]) { v = 1; break; }
            }
            pri2[i] = make_float4(px, py, pr.z, v ? 1.0f : 0.0f);
        }
        if (b == 0) {
            __syncthreads();
            if (tid == 0) *flag = bad ? 0 : 1;   // 1 => int64 layout
        }
    } else if (useT) {
        __shared__ float tile[64][NCLS + 1];
        const int base_i = (blockIdx.x - PREP_BLKS) * 64;
        for (int k = tid; k < 64 * NCLS; k += 256) {
            int ip = k / NCLS, c = k - ip * NCLS;
            tile[ip][c] = scores[(size_t)(base_i + ip) * NCLS + c];
        }
        __syncthreads();
        for (int k = tid; k < 64 * NCLS; k += 256) {
            int c = k >> 6, ip = k & 63;
            scoresT[(size_t)c * NPRI + base_i + ip] = tile[ip][c];
        }
    }
}

// ---------- wave helpers (reduce + broadcast, convergent code only) ----------
__device__ __forceinline__ float wave_min_bc_f32(float v) {
    #pragma unroll
    for (int off = 32; off > 0; off >>= 1) v = fminf(v, __shfl_down(v, off, 64));
    return __int_as_float(__builtin_amdgcn_readfirstlane(__float_as_int(v)));
}
__device__ __forceinline__ u64 wave_max_bc_u64(u64 v) {
    #pragma unroll
    for (int off = 32; off > 0; off >>= 1) { u64 o = __shfl_down(v, off, 64); v = (o > v) ? o : v; }
    unsigned lo = (unsigned)__builtin_amdgcn_readfirstlane((int)(v & 0xffffffffull));
    unsigned hi = (unsigned)__builtin_amdgcn_readfirstlane((int)(v >> 32));
    return (((u64)hi) << 32) | lo;
}
__device__ __forceinline__ u64 wave_min_bc_u64(u64 v) {
    #pragma unroll
    for (int off = 32; off > 0; off >>= 1) { u64 o = __shfl_down(v, off, 64); v = (o < v) ? o : v; }
    unsigned lo = (unsigned)__builtin_amdgcn_readfirstlane((int)(v & 0xffffffffull));
    unsigned hi = (unsigned)__builtin_amdgcn_readfirstlane((int)(v >> 32));
    return (((u64)hi) << 32) | lo;
}

// per-wave top-13 (barrier-free): l ascending; consume descending (max) / ascending (min)
__device__ __forceinline__ void wave_merge_max13(u64 (&l)[KTOP], u64* dst, int lane) {
    int p = 0;
    for (int r = 0; r < KTOP; ++r) {
        u64 cur = 0ull;
        #pragma unroll
        for (int s = 0; s < KTOP; ++s) if (s == p) cur = l[KTOP - 1 - s];
        u64 bm = wave_max_bc_u64(cur);
        if (cur == bm && bm != 0ull) p++;
        if (lane == 0) dst[r] = bm;
    }
}
__device__ __forceinline__ void wave_merge_min13(u64 (&l)[KTOP], u64* dst, int lane) {
    int p = 0;
    for (int r = 0; r < KTOP; ++r) {
        u64 cur = ~0ull;
        #pragma unroll
        for (int s = 0; s < KTOP; ++s) if (s == p) cur = l[s];
        u64 bm = wave_min_bc_u64(cur);
        if (cur == bm && bm != ~0ull) p++;
        if (lane == 0) dst[r] = bm;
    }
}

// ---------- exact formulas (verbatim round-2: bit-identical selection) ----------
__device__ __forceinline__ float iou_exact(float4 pb, float areap, float gx1, float gy1,
                                           float gx2, float gy2, float areag) {
    float iw = fmaxf(fminf(pb.z, gx2) - fmaxf(pb.x, gx1), 0.0f);
    float ih = fmaxf(fminf(pb.w, gy2) - fmaxf(pb.y, gy1), 0.0f);
    float inter = iw * ih;
    return inter / fmaxf(areap + areag - inter, 1e-6f);
}
__device__ __forceinline__ float cost_exact(float4 p2, float gcx, float gcy,
                                            float l, float iou) {
    float dx = p2.x - gcx, dy = p2.y - gcy;
    float dist = sqrtf(dx * dx + dy * dy) / p2.z;
    float soft = exp2f((dist - 3.0f) * L10);
    float sig = 1.0f / (1.0f + expf(-l));
    float dd = iou - sig;
    float bce = fmaxf(l, 0.0f) - l * iou + log1pf(expf(-fabsf(l)));
    float iouc = -logf(iou + EPS_F) * 3.0f;
    return bce * (dd * dd) + iouc + soft;
}
// fast cost (Phase-A sampling only; error covered by margins)
__device__ __forceinline__ float cost_fast(float4 p2, float gcx, float gcy,
                                           float l, float iou) {
    float dx = p2.x - gcx, dy = p2.y - gcy;
    float dist = __fdividef(__fsqrt_rn(dx * dx + dy * dy), p2.z);
    float soft = exp2f((dist - 3.0f) * L10);
    float sig = __fdividef(1.0f, 1.0f + __expf(-l));
    float dd = iou - sig;
    float bce = fmaxf(l, 0.0f) - l * iou + __logf(1.0f + __expf(-fabsf(l)));
    float iouc = -__logf(iou + EPS_F) * 3.0f;
    return bce * (dd * dd) + iouc + soft;
}

// One block (512 thr) per GT.
__global__ __launch_bounds__(SEL_T) void k_select(
        const float* __restrict__ sc, int rs, int cs,
        const float4* __restrict__ pri2,
        const float* __restrict__ pboxes, const float* __restrict__ gt,
        const void* labels, const int* flag,
        int* count, int* firstgt) {
    const int tid = threadIdx.x, lane = tid & 63, wid = tid >> 6;
    const int j = blockIdx.x;
    const int is64 = *flag;

    const float4 gb = ((const float4*)gt)[j];
    const float gx1 = gb.x, gy1 = gb.y, gx2 = gb.z, gy2 = gb.w;
    const float areag = (gx2 - gx1) * (gy2 - gy1);
    const float gcx = (gx1 + gx2) * 0.5f, gcy = (gy1 + gy2) * 0.5f;
    const int lab = get_label(labels, j, is64);
    const float* scol = sc + (size_t)lab * cs;   // element i at scol[i*rs]

    __shared__ float wA[NW * KTOP];
    __shared__ float sA[1];
    __shared__ int s_nc;
    __shared__ int candc[SCAP];
    __shared__ u64 wiou[NW * KTOP];
    __shared__ u64 wcst[NW * KTOP];
    __shared__ u64 csel[KTOP];
    __shared__ float tiou[KTOP];
    __shared__ int sks;

    if (tid == 0) s_nc = 0;

    // ---- Phase A: 512 sampled fast costs -> 13th-smallest (distinct) = tauc ----
    float ac = INF_F;
    {
        int si = tid * 65;   // max 33215 < NPRI
        float4 pb = ((const float4*)pboxes)[si];
        float4 p2 = pri2[si];
        float areap = (pb.z - pb.x) * (pb.w - pb.y);
        float iw = fmaxf(fminf(pb.z, gx2) - fmaxf(pb.x, gx1), 0.0f);
        float ih = fmaxf(fminf(pb.w, gy2) - fmaxf(pb.y, gy1), 0.0f);
        float inter = iw * ih;
        float iou = __fdividef(inter, fmaxf(areap + areag - inter, 1e-6f));
        if (p2.w != 0.0f) ac = cost_fast(p2, gcx, gcy, scol[(size_t)si * rs], iou);
    }
    {   // per-wave 13-round distinct-min (barrier-free)
        float cur = ac;
        for (int r = 0; r < KTOP; ++r) {
            float m = wave_min_bc_f32(cur);
            if (cur == m) cur = __int_as_float(0x7f800000);
            if (lane == 0) wA[wid * KTOP + r] = m;
        }
    }
    __syncthreads();
    if (wid == 0) {   // 8-way cursor merge of per-wave lists
        int p = 0; float tl = INF_F;
        for (int r = 0; r < KTOP; ++r) {
            float cur = (lane < NW) ? wA[lane * KTOP + p] : __int_as_float(0x7f800000);
            float m = wave_min_bc_f32(cur);
            if (cur == m) p++;
            if (r == KTOP - 1) tl = m;
        }
        if (lane == 0) sA[0] = tl;
    }
    __syncthreads();
    const float tauc = sA[0];
    const float thrc = tauc * 1.004f + 4e-3f;
    const bool zone_bad = !(tauc < 9.0e7f);
    // distance filter: cost >= soft = 10^(dist-3); top-13 must satisfy dist <= log10(thrc)+3
    const float Dmax = zone_bad ? 0.0f
        : fmaxf(__log2f(thrc) * (1.0f / L10) + 3.0f + 0.01f, 0.0f);

    // ---- Phase B: scan. Exact iou top-13 (value-strict u64 lists) + distance filter ----
    u64 li[KTOP];
    #pragma unroll
    for (int s = 0; s < KTOP; ++s) li[s] = 0ull;

    for (int i = tid; i < NPRI; i += SEL_T) {
        float4 pb = ((const float4*)pboxes)[i];
        float4 p2 = pri2[i];
        float areap = (pb.z - pb.x) * (pb.w - pb.y);
        float iw = fmaxf(fminf(pb.z, gx2) - fmaxf(pb.x, gx1), 0.0f);
        float ih = fmaxf(fminf(pb.w, gy2) - fmaxf(pb.y, gy1), 0.0f);
        float inter = iw * ih;
        float iou = inter / fmaxf(areap + areag - inter, 1e-6f);   // exact
        unsigned ib = __float_as_uint(iou);
        if (ib > (unsigned)(li[0] >> 32)) {
            li[0] = (((u64)ib) << 32) | (unsigned)i;
            #pragma unroll
            for (int s = 0; s < KTOP - 1; ++s)
                if (li[s] > li[s + 1]) { u64 t = li[s]; li[s] = li[s + 1]; li[s + 1] = t; }
        }
        float dx = p2.x - gcx, dy = p2.y - gcy;
        float rad = p2.z * Dmax;
        if (!zone_bad && p2.w != 0.0f && dx * dx + dy * dy <= rad * rad) {
            int p = atomicAdd(&s_nc, 1);
            if (p < SCAP) candc[p] = i;
        }
    }
    __syncthreads();
    const int nc = s_nc;
    const bool full = zone_bad || (nc > SCAP);

    // ---- Phase C: exact cost top-13 over survivors (or full exact scan) ----
    u64 lc[KTOP];
    #pragma unroll
    for (int s = 0; s < KTOP; ++s) lc[s] = ~0ull;

    if (!full) {
        for (int k = tid; k < nc; k += SEL_T) {   // <=4 per thread
            int i = candc[k];
            float4 pb = ((const float4*)pboxes)[i];
            float4 p2 = pri2[i];
            float areap = (pb.z - pb.x) * (pb.w - pb.y);
            float iou = iou_exact(pb, areap, gx1, gy1, gx2, gy2, areag);
            float ec = cost_exact(p2, gcx, gcy, scol[(size_t)i * rs], iou);
            u64 ck = (((u64)__float_as_uint(ec)) << 32) | (unsigned)i;
            if (ck < lc[KTOP - 1]) {
                lc[KTOP - 1] = ck;
                #pragma unroll
                for (int s = KTOP - 1; s > 0; --s)
                    if (lc[s] < lc[s - 1]) { u64 t = lc[s]; lc[s] = lc[s - 1]; lc[s - 1] = t; }
            }
        }
    } else {
        for (int i = tid; i < NPRI; i += SEL_T) {
            float4 pb = ((const float4*)pboxes)[i];
            float4 p2 = pri2[i];
            float areap = (pb.z - pb.x) * (pb.w - pb.y);
            float iou = iou_exact(pb, areap, gx1, gy1, gx2, gy2, areag);
            float ec = INF_F;
            if (p2.w != 0.0f) ec = cost_exact(p2, gcx, gcy, scol[(size_t)i * rs], iou);
            u64 ck = (((u64)__float_as_uint(ec)) << 32) | (unsigned)i;
            if (ck < lc[KTOP - 1]) {
                lc[KTOP - 1] = ck;
                #pragma unroll
                for (int s = KTOP - 1; s > 0; --s)
                    if (lc[s] < lc[s - 1]) { u64 t = lc[s]; lc[s] = lc[s - 1]; lc[s - 1] = t; }
            }
        }
    }

    // ---- barrier-free per-wave merges, then 8-way finals on waves 0 and 1 ----
    wave_merge_max13(li, &wiou[wid * KTOP], lane);
    wave_merge_min13(lc, &wcst[wid * KTOP], lane);
    __syncthreads();
    if (wid == 0) {          // iou final (descending values)
        int p = 0;
        for (int r = 0; r < KTOP; ++r) {
            u64 cur = (lane < NW) ? wiou[lane * KTOP + p] : 0ull;
            u64 bm = wave_max_bc_u64(cur);
            if (cur == bm && bm != 0ull) p++;
            if (lane == 0) tiou[r] = __uint_as_float((unsigned)(bm >> 32));
        }
    } else if (wid == 1) {   // cost final (ascending; idx in key = lower-index tie-break)
        int p = 0;
        for (int r = 0; r < KTOP; ++r) {
            u64 cur = (lane < NW) ? wcst[lane * KTOP + p] : ~0ull;
            u64 bm = wave_min_bc_u64(cur);
            if (cur == bm && bm != ~0ull) p++;
            if (lane == 0) csel[r] = bm;
        }
    }
    __syncthreads();
    if (tid == 0) {
        float s = 0.0f;
        for (int r = 0; r < KTOP; ++r) s += tiou[r];  // descending-order sum (matches ref)
        int ks = (int)s;
        if (ks < 1) ks = 1;
        sks = ks;
    }
    __syncthreads();
    if (tid < KTOP && tid < sks) {
        u64 k = csel[tid];
        if (k != ~0ull) {
            int idx = (int)(unsigned)(k & 0xFFFFFFFFull);
            atomicAdd(&count[idx], 1);
            atomicMin(&firstgt[idx], j);
        }
    }
}

// ---------- per-prior finalize; multi-matched priors -> worklist ----------
__global__ __launch_bounds__(256) void k_assign(
        const float* __restrict__ pboxes, const float* __restrict__ gt,
        const void* labels, const int* flag, const float4* __restrict__ pri2,
        const int* __restrict__ count, const int* __restrict__ firstgt,
        int* nmulti, int* mlist, float* __restrict__ out) {
    __shared__ float4 gbox[NGT];
    __shared__ int glab[NGT];
    __shared__ float gareas[NGT];
    int tid = threadIdx.x;
    int is64 = *flag;
    {
        float4 b = ((const float4*)gt)[tid];
        gbox[tid] = b;
        glab[tid] = get_label(labels, tid, is64);
        gareas[tid] = (b.z - b.x) * (b.w - b.y);
    }
    __syncthreads();
    int i = blockIdx.x * 256 + tid;
    if (i >= NPRI) return;
    int v = (pri2[i].w != 0.0f) ? 1 : 0;
    int c = count[i];
    float o0 = 0.0f, o1 = -INF_F, o2 = -1.0f;
    if (v && c == 1) {
        int j = firstgt[i];
        float4 pb = ((const float4*)pboxes)[i];
        float areap = (pb.z - pb.x) * (pb.w - pb.y);
        float4 g = gbox[j];
        float iw = fmaxf(fminf(pb.z, g.z) - fmaxf(pb.x, g.x), 0.0f);
        float ih = fmaxf(fminf(pb.w, g.w) - fmaxf(pb.y, g.y), 0.0f);
        float inter = iw * ih;
        float iou = inter / fmaxf(areap + gareas[j] - inter, 1e-6f);
        o0 = (float)(j + 1); o1 = iou; o2 = (float)glab[j];
    } else if (v && c > 1) {
        int pos = atomicAdd(nmulti, 1);
        mlist[pos] = i;
    }
    out[i] = o0;
    out[NPRI + i] = o1;
    out[2 * NPRI + i] = o2;
}

// ---------- one block per multi prior: block argmin over 256 GT costs ----------
__global__ __launch_bounds__(256) void k_multi(
        const float* __restrict__ sc, int rs, int cs,
        const float4* __restrict__ pri2,
        const float* __restrict__ pboxes, const float* __restrict__ gt,
        const void* labels, const int* flag,
        const int* __restrict__ nmulti, const int* __restrict__ mlist,
        float* __restrict__ out) {
    __shared__ float4 gbox[NGT];
    __shared__ int glab[NGT];
    __shared__ float gcxs[NGT], gcys[NGT], gareas[NGT];
    __shared__ u64 red4[4];
    const int tid = threadIdx.x;
    const int is64 = *flag;
    {
        float4 b = ((const float4*)gt)[tid];
        gbox[tid] = b;
        glab[tid] = get_label(labels, tid, is64);
        gcxs[tid] = (b.x + b.z) * 0.5f;
        gcys[tid] = (b.y + b.w) * 0.5f;
        gareas[tid] = (b.z - b.x) * (b.w - b.y);
    }
    __syncthreads();
    const int nm = *nmulti;
    const int j = tid;
    for (int m = blockIdx.x; m < nm; m += gridDim.x) {
        const int i = mlist[m];
        float4 pb = ((const float4*)pboxes)[i];
        float areap = (pb.z - pb.x) * (pb.w - pb.y);
        float4 p2 = pri2[i];

        float4 g = gbox[j];
        float iw = fmaxf(fminf(pb.z, g.z) - fmaxf(pb.x, g.x), 0.0f);
        float ih = fmaxf(fminf(pb.w, g.w) - fmaxf(pb.y, g.y), 0.0f);
        float inter = iw * ih;
        float iou = inter / fmaxf(areap + gareas[j] - inter, 1e-6f);
        float dx = p2.x - gcxs[j], dy = p2.y - gcys[j];
        float dist = sqrtf(dx * dx + dy * dy) / p2.z;
        float soft = exp2f((dist - 3.0f) * L10);
        float l = sc[(size_t)i * rs + (size_t)glab[j] * cs];
        float sig = 1.0f / (1.0f + expf(-l));
        float dd = iou - sig;
        float bce = fmaxf(l, 0.0f) - l * iou + log1pf(expf(-fabsf(l)));
        float cost = bce * (dd * dd) + (-logf(iou + EPS_F) * 3.0f) + soft;

        u64 key = (((u64)__float_as_uint(cost)) << 32) | (unsigned)j;
        u64 v = key;
        #pragma unroll
        for (int off = 32; off > 0; off >>= 1) {
            u64 o = __shfl_down(v, off, 64);
            v = (o < v) ? o : v;
        }
        if ((tid & 63) == 0) red4[tid >> 6] = v;
        __syncthreads();
        u64 best = red4[0];
        #pragma unroll
        for (int q = 1; q < 4; ++q) best = (red4[q] < best) ? red4[q] : best;
        if (key == best) {
            out[i] = (float)(j + 1);
            out[NPRI + i] = iou;
            out[2 * NPRI + i] = (float)glab[j];
        }
        __syncthreads();
    }
}

extern "C" void kernel_launch(void* const* d_in, const int* in_sizes, int n_in,
                              void* d_out, int out_size, void* d_ws, size_t ws_size,
                              hipStream_t stream) {
    const float* scores = (const float*)d_in[0];
    const float* priors = (const float*)d_in[1];
    const float* pboxes = (const float*)d_in[2];
    const float* gt     = (const float*)d_in[3];
    const void*  labels = d_in[4];
    float* out = (float*)d_out;

    char* ws = (char*)d_ws;
    int*    flag    = (int*)ws;
    int*    nmulti  = (int*)(ws + 64);
    int*    count   = (int*)(ws + 128);
    int*    firstgt = (int*)(ws + 128 + (size_t)NPRI * 4);
    int*    mlist   = (int*)(ws + 128 + (size_t)NPRI * 8);          // 16 KiB
    float4* pri2    = (float4*)(ws + 128 + (size_t)NPRI * 8 + 16384);
    float*  scoresT = (float*)(ws + 128 + (size_t)NPRI * 8 + 16384 + (size_t)NPRI * 16);
    const size_t need_T = 128 + (size_t)NPRI * 8 + 16384 + (size_t)NPRI * 16
                        + (size_t)NPRI * NCLS * 4;
    const int useT = (ws_size >= need_T) ? 1 : 0;

    hipLaunchKernelGGL(k_prep_tr, dim3(PREP_BLKS + (useT ? TR_BLKS : 0)), dim3(256), 0, stream,
                       priors, gt, labels, scores, scoresT, pri2, count, firstgt, flag, nmulti, useT);

    const float* sc = scores; int rs = NCLS, cs = 1;
    if (useT) { sc = scoresT; rs = 1; cs = NPRI; }

    hipLaunchKernelGGL(k_select, dim3(NGT), dim3(SEL_T), 0, stream,
                       sc, rs, cs, pri2, pboxes, gt, labels, flag, count, firstgt);
    hipLaunchKernelGGL(k_assign, dim3((NPRI + 255) / 256), dim3(256), 0, stream,
                       pboxes, gt, labels, flag, pri2, count, firstgt, nmulti, mlist, out);
    hipLaunchKernelGGL(k_multi, dim3(256), dim3(256), 0, stream,
                       sc, rs, cs, pri2, pboxes, gt, labels, flag, nmulti, mlist, out);
}

// Round 6
// 247.849 us; speedup vs baseline: 1.4884x; 1.0431x over previous
//
#include <hip/hip_runtime.h>
#include <cstdint>

#define NPRI 33600
#define NGT  256
#define NCLS 80
#define KTOP 13
#define INF_F 1.0e8f
#define EPS_F 1e-7f
#define L10 3.3219280948873623f
#define SLC  4
#define SLEN (NPRI / SLC)          // 8400
#define SCN_T 512
#define NW8 (SCN_T / 64)
#define CAPI 1536
#define CAPC 1536
#define PREP_BLKS ((NPRI + 255) / 256)
#define TR_BLKS (NPRI / 64)

typedef unsigned long long u64;

__device__ __forceinline__ int get_label(const void* p, int j, int is64) {
    if (is64) return (int)((const long long*)p)[j];
    return ((const int*)p)[j];
}

// ---------- wave helpers (reduce + broadcast) ----------
__device__ __forceinline__ float wave_min_bc_f32(float v) {
    #pragma unroll
    for (int off = 32; off > 0; off >>= 1) v = fminf(v, __shfl_down(v, off, 64));
    return __int_as_float(__builtin_amdgcn_readfirstlane(__float_as_int(v)));
}
__device__ __forceinline__ u64 wave_max_bc_u64(u64 v) {
    #pragma unroll
    for (int off = 32; off > 0; off >>= 1) { u64 o = __shfl_down(v, off, 64); v = (o > v) ? o : v; }
    unsigned lo = (unsigned)__builtin_amdgcn_readfirstlane((int)(v & 0xffffffffull));
    unsigned hi = (unsigned)__builtin_amdgcn_readfirstlane((int)(v >> 32));
    return (((u64)hi) << 32) | lo;
}
__device__ __forceinline__ u64 wave_min_bc_u64(u64 v) {
    #pragma unroll
    for (int off = 32; off > 0; off >>= 1) { u64 o = __shfl_down(v, off, 64); v = (o < v) ? o : v; }
    unsigned lo = (unsigned)__builtin_amdgcn_readfirstlane((int)(v & 0xffffffffull));
    unsigned hi = (unsigned)__builtin_amdgcn_readfirstlane((int)(v >> 32));
    return (((u64)hi) << 32) | lo;
}
__device__ __forceinline__ void wave_merge_max13(u64 (&l)[KTOP], u64* dst, int lane) {
    int p = 0;
    for (int r = 0; r < KTOP; ++r) {
        u64 cur = 0ull;
        #pragma unroll
        for (int s = 0; s < KTOP; ++s) if (s == p) cur = l[KTOP - 1 - s];
        u64 bm = wave_max_bc_u64(cur);
        if (cur == bm && bm != 0ull) p++;
        if (lane == 0) dst[r] = bm;
    }
}
__device__ __forceinline__ void wave_merge_min13(u64 (&l)[KTOP], u64* dst, int lane) {
    int p = 0;
    for (int r = 0; r < KTOP; ++r) {
        u64 cur = ~0ull;
        #pragma unroll
        for (int s = 0; s < KTOP; ++s) if (s == p) cur = l[s];
        u64 bm = wave_min_bc_u64(cur);
        if (cur == bm && bm != ~0ull) p++;
        if (lane == 0) dst[r] = bm;
    }
}

// ---------- exact formulas (verbatim round-2: bit-identical selection) ----------
__device__ __forceinline__ float iou_exact(float4 pb, float areap, float gx1, float gy1,
                                           float gx2, float gy2, float areag) {
    float iw = fmaxf(fminf(pb.z, gx2) - fmaxf(pb.x, gx1), 0.0f);
    float ih = fmaxf(fminf(pb.w, gy2) - fmaxf(pb.y, gy1), 0.0f);
    float inter = iw * ih;
    return inter / fmaxf(areap + areag - inter, 1e-6f);
}
__device__ __forceinline__ float cost_exact(float4 p2, float gcx, float gcy,
                                            float l, float iou) {
    float dx = p2.x - gcx, dy = p2.y - gcy;
    float dist = sqrtf(dx * dx + dy * dy) / p2.z;
    float soft = exp2f((dist - 3.0f) * L10);
    float sig = 1.0f / (1.0f + expf(-l));
    float dd = iou - sig;
    float bce = fmaxf(l, 0.0f) - l * iou + log1pf(expf(-fabsf(l)));
    float iouc = -logf(iou + EPS_F) * 3.0f;
    return bce * (dd * dd) + iouc + soft;
}
__device__ __forceinline__ float cost_fast(float4 p2, float gcx, float gcy,
                                           float l, float iou) {
    float dx = p2.x - gcx, dy = p2.y - gcy;
    float dist = __fdividef(__fsqrt_rn(dx * dx + dy * dy), p2.z);
    float soft = exp2f((dist - 3.0f) * L10);
    float sig = __fdividef(1.0f, 1.0f + __expf(-l));
    float dd = iou - sig;
    float bce = fmaxf(l, 0.0f) - l * iou + __logf(1.0f + __expf(-fabsf(l)));
    float iouc = -__logf(iou + EPS_F) * 3.0f;
    return bce * (dd * dd) + iouc + soft;
}

// ---------- fused prep (detect+init+valid+pbp pack) and scores transpose ----------
__global__ __launch_bounds__(256) void k_prep_tr(
        const float* __restrict__ priors, const float* __restrict__ gt,
        const void* labels, const float* __restrict__ scores,
        const float* __restrict__ pboxes,
        float* __restrict__ scoresT, float4* __restrict__ pbp,
        int* count, int* firstgt, int* flag, int* nmulti, int useT) {
    const int tid = threadIdx.x;
    if (blockIdx.x < PREP_BLKS) {
        __shared__ float4 gbox[NGT];
        __shared__ int    gpad[NGT];
        __shared__ int    bad;
        const int b = blockIdx.x;
        if (b == 0 && tid == 0) { bad = 0; *nmulti = 0; }
        {
            float4 bx = ((const float4*)gt)[tid];
            gbox[tid] = bx;
            gpad[tid] = ((bx.x + bx.y + bx.z + bx.w) > 0.0f) ? 1 : 0;
        }
        __syncthreads();
        if (b == 0 && tid < 128) {
            long long v = ((const long long*)labels)[tid];
            if (v < 0 || v >= NCLS) atomicOr(&bad, 1);
        }
        int i = b * 256 + tid;
        if (i < NPRI) {
            count[i] = 0; firstgt[i] = NGT;
            float4 pr = ((const float4*)priors)[i];
            float px = pr.x, py = pr.y;
            int v = 0;
            for (int j = 0; j < NGT; ++j) {
                float4 bx = gbox[j];
                float m = fminf(fminf(px - bx.x, py - bx.y), fminf(bx.z - px, bx.w - py));
                if (m > 0.0f && gpad[j]) { v = 1; break; }
            }
            pbp[2 * i]     = ((const float4*)pboxes)[i];
            pbp[2 * i + 1] = make_float4(px, py, pr.z, v ? 1.0f : 0.0f);
        }
        if (b == 0) {
            __syncthreads();
            if (tid == 0) *flag = bad ? 0 : 1;
        }
    } else if (useT) {
        __shared__ float tile[64][NCLS + 1];
        const int base_i = (blockIdx.x - PREP_BLKS) * 64;
        for (int k = tid; k < 64 * NCLS; k += 256) {
            int ip = k / NCLS, c = k - ip * NCLS;
            tile[ip][c] = scores[(size_t)(base_i + ip) * NCLS + c];
        }
        __syncthreads();
        for (int k = tid; k < 64 * NCLS; k += 256) {
            int c = k >> 6, ip = k & 63;
            scoresT[(size_t)c * NPRI + base_i + ip] = tile[ip][c];
        }
    }
}

// ---------- per-GT sampled threshold -> Dmax/zbad ----------
__global__ __launch_bounds__(512) void k_thresh(
        const float* __restrict__ sc, int rs, int cs,
        const float4* __restrict__ pbp, const float* __restrict__ gt,
        const void* labels, const int* flag,
        float* __restrict__ dmaxA, int* __restrict__ zbadA) {
    const int tid = threadIdx.x, lane = tid & 63, wid = tid >> 6;
    const int j = blockIdx.x;
    const int is64 = *flag;
    const float4 gb = ((const float4*)gt)[j];
    const float gx1 = gb.x, gy1 = gb.y, gx2 = gb.z, gy2 = gb.w;
    const float areag = (gx2 - gx1) * (gy2 - gy1);
    const float gcx = (gx1 + gx2) * 0.5f, gcy = (gy1 + gy2) * 0.5f;
    const int lab = get_label(labels, j, is64);
    const float* scol = sc + (size_t)lab * cs;

    __shared__ float wA[NW8 * KTOP];
    float ac = INF_F;
    {
        int si = tid * 65;
        float4 pb = pbp[2 * si];
        float4 p2 = pbp[2 * si + 1];
        float areap = (pb.z - pb.x) * (pb.w - pb.y);
        float iw = fmaxf(fminf(pb.z, gx2) - fmaxf(pb.x, gx1), 0.0f);
        float ih = fmaxf(fminf(pb.w, gy2) - fmaxf(pb.y, gy1), 0.0f);
        float inter = iw * ih;
        float iou = __fdividef(inter, fmaxf(areap + areag - inter, 1e-6f));
        if (p2.w != 0.0f) ac = cost_fast(p2, gcx, gcy, scol[(size_t)si * rs], iou);
    }
    {
        float cur = ac;
        for (int r = 0; r < KTOP; ++r) {
            float m = wave_min_bc_f32(cur);
            if (cur == m) cur = __int_as_float(0x7f800000);
            if (lane == 0) wA[wid * KTOP + r] = m;
        }
    }
    __syncthreads();
    if (wid == 0) {
        int p = 0; float tauc = INF_F;
        for (int r = 0; r < KTOP; ++r) {
            float cur = (lane < NW8) ? wA[lane * KTOP + p] : __int_as_float(0x7f800000);
            float m = wave_min_bc_f32(cur);
            if (cur == m) p++;
            if (r == KTOP - 1) tauc = m;
        }
        if (lane == 0) {
            const float thrc = tauc * 1.004f + 4e-3f;
            const int zb = !(tauc < 9.0e7f);
            dmaxA[j] = zb ? 0.0f : fmaxf(__log2f(thrc) * (1.0f / L10) + 3.0f + 0.01f, 0.0f);
            zbadA[j] = zb;
        }
    }
}

// ---------- sliced scan: append-only candidates, exact per-slice top-13s ----------
__global__ __launch_bounds__(SCN_T) void k_scan(
        const float* __restrict__ sc, int rs, int cs,
        const float4* __restrict__ pbp, const float* __restrict__ gt,
        const void* labels, const int* flag,
        const float* __restrict__ dmaxA, const int* __restrict__ zbadA,
        u64* __restrict__ part_iou, u64* __restrict__ part_cost) {
    const int tid = threadIdx.x, lane = tid & 63, wid = tid >> 6;
    const int j = blockIdx.x, slice = blockIdx.y;
    const int base = slice * SLEN;
    const int is64 = *flag;

    const float4 gb = ((const float4*)gt)[j];
    const float gx1 = gb.x, gy1 = gb.y, gx2 = gb.z, gy2 = gb.w;
    const float areag = (gx2 - gx1) * (gy2 - gy1);
    const float gcx = (gx1 + gx2) * 0.5f, gcy = (gy1 + gy2) * 0.5f;
    const int lab = get_label(labels, j, is64);
    const float* scol = sc + (size_t)lab * cs;
    const float dmax = dmaxA[j];
    const int zbad = zbadA[j];

    __shared__ int s_ni, s_nc;
    __shared__ u64 liou[CAPI];
    __shared__ int lcost[CAPC];
    __shared__ u64 wio[NW8 * KTOP], wco[NW8 * KTOP];
    if (tid == 0) { s_ni = 0; s_nc = 0; }
    __syncthreads();

    for (int i = base + tid; i < base + SLEN; i += SCN_T) {
        float4 pb = pbp[2 * i];
        float4 p2 = pbp[2 * i + 1];
        float areap = (pb.z - pb.x) * (pb.w - pb.y);
        float iw = fmaxf(fminf(pb.z, gx2) - fmaxf(pb.x, gx1), 0.0f);
        float ih = fmaxf(fminf(pb.w, gy2) - fmaxf(pb.y, gy1), 0.0f);
        float inter = iw * ih;
        float iou = inter / fmaxf(areap + areag - inter, 1e-6f);
        if (iou > 0.0f) {
            int p = atomicAdd(&s_ni, 1);
            if (p < CAPI) liou[p] = (((u64)__float_as_uint(iou)) << 32) | (unsigned)i;
        }
        if (!zbad && p2.w != 0.0f) {
            float dx = p2.x - gcx, dy = p2.y - gcy;
            float rad = p2.z * dmax;
            if (dx * dx + dy * dy <= rad * rad) {
                int p = atomicAdd(&s_nc, 1);
                if (p < CAPC) lcost[p] = i;
            }
        }
    }
    __syncthreads();
    const int ni = s_ni, nc = s_nc;
    const bool fI = (ni > CAPI);
    const bool fC = zbad || (nc > CAPC);

    u64 li[KTOP], lc[KTOP];
    #pragma unroll
    for (int s = 0; s < KTOP; ++s) { li[s] = 0ull; lc[s] = ~0ull; }

    if (!fI) {
        for (int k = tid; k < ni; k += SCN_T) {
            u64 key = liou[k];
            if (key > li[0]) {
                li[0] = key;
                #pragma unroll
                for (int s = 0; s < KTOP - 1; ++s)
                    if (li[s] > li[s + 1]) { u64 t = li[s]; li[s] = li[s + 1]; li[s + 1] = t; }
            }
        }
    } else {
        for (int i = base + tid; i < base + SLEN; i += SCN_T) {
            float4 pb = pbp[2 * i];
            float areap = (pb.z - pb.x) * (pb.w - pb.y);
            float iou = iou_exact(pb, areap, gx1, gy1, gx2, gy2, areag);
            unsigned ib = __float_as_uint(iou);
            if (ib > (unsigned)(li[0] >> 32)) {
                li[0] = (((u64)ib) << 32) | (unsigned)i;
                #pragma unroll
                for (int s = 0; s < KTOP - 1; ++s)
                    if (li[s] > li[s + 1]) { u64 t = li[s]; li[s] = li[s + 1]; li[s + 1] = t; }
            }
        }
    }

    if (!fC) {
        for (int k = tid; k < nc; k += SCN_T) {
            int i = lcost[k];
            float4 pb = pbp[2 * i];
            float4 p2 = pbp[2 * i + 1];
            float areap = (pb.z - pb.x) * (pb.w - pb.y);
            float iou = iou_exact(pb, areap, gx1, gy1, gx2, gy2, areag);
            float ec = cost_exact(p2, gcx, gcy, scol[(size_t)i * rs], iou);
            u64 ck = (((u64)__float_as_uint(ec)) << 32) | (unsigned)i;
            if (ck < lc[KTOP - 1]) {
                lc[KTOP - 1] = ck;
                #pragma unroll
                for (int s = KTOP - 1; s > 0; --s)
                    if (lc[s] < lc[s - 1]) { u64 t = lc[s]; lc[s] = lc[s - 1]; lc[s - 1] = t; }
            }
        }
    } else {
        for (int i = base + tid; i < base + SLEN; i += SCN_T) {
            float4 pb = pbp[2 * i];
            float4 p2 = pbp[2 * i + 1];
            float areap = (pb.z - pb.x) * (pb.w - pb.y);
            float iou = iou_exact(pb, areap, gx1, gy1, gx2, gy2, areag);
            float ec = INF_F;
            if (p2.w != 0.0f) ec = cost_exact(p2, gcx, gcy, scol[(size_t)i * rs], iou);
            u64 ck = (((u64)__float_as_uint(ec)) << 32) | (unsigned)i;
            if (ck < lc[KTOP - 1]) {
                lc[KTOP - 1] = ck;
                #pragma unroll
                for (int s = KTOP - 1; s > 0; --s)
                    if (lc[s] < lc[s - 1]) { u64 t = lc[s]; lc[s] = lc[s - 1]; lc[s - 1] = t; }
            }
        }
    }

    wave_merge_max13(li, &wio[wid * KTOP], lane);
    wave_merge_min13(lc, &wco[wid * KTOP], lane);
    __syncthreads();
    if (wid == 0) {
        int p = 0;
        u64* dpi = part_iou + ((size_t)j * SLC + slice) * KTOP;
        for (int r = 0; r < KTOP; ++r) {
            u64 cur = (lane < NW8) ? wio[lane * KTOP + p] : 0ull;
            u64 bm = wave_max_bc_u64(cur);
            if (cur == bm && bm != 0ull) p++;
            if (lane == 0) dpi[r] = bm;
        }
    } else if (wid == 1) {
        int p = 0;
        u64* dpc = part_cost + ((size_t)j * SLC + slice) * KTOP;
        for (int r = 0; r < KTOP; ++r) {
            u64 cur = (lane < NW8) ? wco[lane * KTOP + p] : ~0ull;
            u64 bm = wave_min_bc_u64(cur);
            if (cur == bm && bm != ~0ull) p++;
            if (lane == 0) dpc[r] = bm;
        }
    }
}

// ---------- merge 4 slices per GT, compute ks, scatter ----------
__global__ __launch_bounds__(64) void k_merge(
        const u64* __restrict__ part_iou, const u64* __restrict__ part_cost,
        int* count, int* firstgt) {
    const int j = blockIdx.x;
    const int lane = threadIdx.x;
    u64 ki = (lane < SLC * KTOP) ? part_iou[(size_t)j * SLC * KTOP + lane] : 0ull;
    float tsum = 0.0f;
    for (int r = 0; r < KTOP; ++r) {
        u64 bm = wave_max_bc_u64(ki);
        if (ki == bm && bm != 0ull) ki = 0ull;
        tsum += __uint_as_float((unsigned)(bm >> 32));   // descending-order sum
    }
    int ks = (int)tsum;
    if (ks < 1) ks = 1;
    u64 kc = (lane < SLC * KTOP) ? part_cost[(size_t)j * SLC * KTOP + lane] : ~0ull;
    u64 mine = ~0ull;
    for (int r = 0; r < KTOP; ++r) {
        u64 bm = wave_min_bc_u64(kc);
        if (kc == bm && bm != ~0ull) kc = ~0ull;
        if (lane == r) mine = bm;
    }
    if (lane < KTOP && lane < ks && mine != ~0ull) {
        int idx = (int)(unsigned)(mine & 0xFFFFFFFFull);
        atomicAdd(&count[idx], 1);
        atomicMin(&firstgt[idx], j);
    }
}

// ---------- per-prior finalize; multi-matched priors -> worklist ----------
__global__ __launch_bounds__(256) void k_assign(
        const float4* __restrict__ pbp, const float* __restrict__ gt,
        const void* labels, const int* flag,
        const int* __restrict__ count, const int* __restrict__ firstgt,
        int* nmulti, int* mlist, float* __restrict__ out) {
    __shared__ float4 gbox[NGT];
    __shared__ int glab[NGT];
    __shared__ float gareas[NGT];
    int tid = threadIdx.x;
    int is64 = *flag;
    {
        float4 b = ((const float4*)gt)[tid];
        gbox[tid] = b;
        glab[tid] = get_label(labels, tid, is64);
        gareas[tid] = (b.z - b.x) * (b.w - b.y);
    }
    __syncthreads();
    int i = blockIdx.x * 256 + tid;
    if (i >= NPRI) return;
    float4 p2 = pbp[2 * i + 1];
    int v = (p2.w != 0.0f) ? 1 : 0;
    int c = count[i];
    float o0 = 0.0f, o1 = -INF_F, o2 = -1.0f;
    if (v && c == 1) {
        int j = firstgt[i];
        float4 pb = pbp[2 * i];
        float areap = (pb.z - pb.x) * (pb.w - pb.y);
        float4 g = gbox[j];
        float iw = fmaxf(fminf(pb.z, g.z) - fmaxf(pb.x, g.x), 0.0f);
        float ih = fmaxf(fminf(pb.w, g.w) - fmaxf(pb.y, g.y), 0.0f);
        float inter = iw * ih;
        float iou = inter / fmaxf(areap + gareas[j] - inter, 1e-6f);
        o0 = (float)(j + 1); o1 = iou; o2 = (float)glab[j];
    } else if (v && c > 1) {
        int pos = atomicAdd(nmulti, 1);
        mlist[pos] = i;
    }
    out[i] = o0;
    out[NPRI + i] = o1;
    out[2 * NPRI + i] = o2;
}

// ---------- one block per multi prior: block argmin over 256 GT costs ----------
__global__ __launch_bounds__(256) void k_multi(
        const float* __restrict__ sc, int rs, int cs,
        const float4* __restrict__ pbp, const float* __restrict__ gt,
        const void* labels, const int* flag,
        const int* __restrict__ nmulti, const int* __restrict__ mlist,
        float* __restrict__ out) {
    __shared__ float4 gbox[NGT];
    __shared__ int glab[NGT];
    __shared__ float gcxs[NGT], gcys[NGT], gareas[NGT];
    __shared__ u64 red4[4];
    const int tid = threadIdx.x;
    const int is64 = *flag;
    {
        float4 b = ((const float4*)gt)[tid];
        gbox[tid] = b;
        glab[tid] = get_label(labels, tid, is64);
        gcxs[tid] = (b.x + b.z) * 0.5f;
        gcys[tid] = (b.y + b.w) * 0.5f;
        gareas[tid] = (b.z - b.x) * (b.w - b.y);
    }
    __syncthreads();
    const int nm = *nmulti;
    const int j = tid;
    for (int m = blockIdx.x; m < nm; m += gridDim.x) {
        const int i = mlist[m];
        float4 pb = pbp[2 * i];
        float4 p2 = pbp[2 * i + 1];
        float areap = (pb.z - pb.x) * (pb.w - pb.y);

        float4 g = gbox[j];
        float iw = fmaxf(fminf(pb.z, g.z) - fmaxf(pb.x, g.x), 0.0f);
        float ih = fmaxf(fminf(pb.w, g.w) - fmaxf(pb.y, g.y), 0.0f);
        float inter = iw * ih;
        float iou = inter / fmaxf(areap + gareas[j] - inter, 1e-6f);
        float dx = p2.x - gcxs[j], dy = p2.y - gcys[j];
        float dist = sqrtf(dx * dx + dy * dy) / p2.z;
        float soft = exp2f((dist - 3.0f) * L10);
        float l = sc[(size_t)i * rs + (size_t)glab[j] * cs];
        float sig = 1.0f / (1.0f + expf(-l));
        float dd = iou - sig;
        float bce = fmaxf(l, 0.0f) - l * iou + log1pf(expf(-fabsf(l)));
        float cost = bce * (dd * dd) + (-logf(iou + EPS_F) * 3.0f) + soft;

        u64 key = (((u64)__float_as_uint(cost)) << 32) | (unsigned)j;
        u64 v = key;
        #pragma unroll
        for (int off = 32; off > 0; off >>= 1) {
            u64 o = __shfl_down(v, off, 64);
            v = (o < v) ? o : v;
        }
        if ((tid & 63) == 0) red4[tid >> 6] = v;
        __syncthreads();
        u64 best = red4[0];
        #pragma unroll
        for (int q = 1; q < 4; ++q) best = (red4[q] < best) ? red4[q] : best;
        if (key == best) {
            out[i] = (float)(j + 1);
            out[NPRI + i] = iou;
            out[2 * NPRI + i] = (float)glab[j];
        }
        __syncthreads();
    }
}

extern "C" void kernel_launch(void* const* d_in, const int* in_sizes, int n_in,
                              void* d_out, int out_size, void* d_ws, size_t ws_size,
                              hipStream_t stream) {
    const float* scores = (const float*)d_in[0];
    const float* priors = (const float*)d_in[1];
    const float* pboxes = (const float*)d_in[2];
    const float* gt     = (const float*)d_in[3];
    const void*  labels = d_in[4];
    float* out = (float*)d_out;

    char* ws = (char*)d_ws;
    size_t off = 0;
    auto alloc = [&](size_t bytes) { size_t o = off; off = (off + bytes + 255) & ~(size_t)255; return o; };
    int*    flag     = (int*)(ws + alloc(4));
    int*    nmulti   = (int*)(ws + alloc(4));
    int*    count    = (int*)(ws + alloc((size_t)NPRI * 4));
    int*    firstgt  = (int*)(ws + alloc((size_t)NPRI * 4));
    int*    mlist    = (int*)(ws + alloc((size_t)NPRI * 4));
    float*  dmaxA    = (float*)(ws + alloc(NGT * 4));
    int*    zbadA    = (int*)(ws + alloc(NGT * 4));
    u64*    part_iou = (u64*)(ws + alloc((size_t)NGT * SLC * KTOP * 8));
    u64*    part_cost= (u64*)(ws + alloc((size_t)NGT * SLC * KTOP * 8));
    float4* pbp      = (float4*)(ws + alloc((size_t)NPRI * 32));
    float*  scoresT  = (float*)(ws + alloc((size_t)NPRI * NCLS * 4));
    const int useT = (ws_size >= off) ? 1 : 0;

    hipLaunchKernelGGL(k_prep_tr, dim3(PREP_BLKS + (useT ? TR_BLKS : 0)), dim3(256), 0, stream,
                       priors, gt, labels, scores, pboxes, scoresT, pbp,
                       count, firstgt, flag, nmulti, useT);

    const float* scb = scores; int rs = NCLS, cs = 1;
    if (useT) { scb = scoresT; rs = 1; cs = NPRI; }

    hipLaunchKernelGGL(k_thresh, dim3(NGT), dim3(512), 0, stream,
                       scb, rs, cs, pbp, gt, labels, flag, dmaxA, zbadA);
    hipLaunchKernelGGL(k_scan, dim3(NGT, SLC), dim3(SCN_T), 0, stream,
                       scb, rs, cs, pbp, gt, labels, flag, dmaxA, zbadA, part_iou, part_cost);
    hipLaunchKernelGGL(k_merge, dim3(NGT), dim3(64), 0, stream,
                       part_iou, part_cost, count, firstgt);
    hipLaunchKernelGGL(k_assign, dim3((NPRI + 255) / 256), dim3(256), 0, stream,
                       pbp, gt, labels, flag, count, firstgt, nmulti, mlist, out);
    hipLaunchKernelGGL(k_multi, dim3(256), dim3(256), 0, stream,
                       scb, rs, cs, pbp, gt, labels, flag, nmulti, mlist, out);
}

// Round 7
// 229.835 us; speedup vs baseline: 1.6050x; 1.0784x over previous
//
#include <hip/hip_runtime.h>
#include <cstdint>

#define NPRI 33600
#define NGT  256
#define NCLS 80
#define KTOP 13
#define INF_F 1.0e8f
#define EPS_F 1e-7f
#define L10 3.3219280948873623f
#define SLC  4
#define SLEN (NPRI / SLC)          // 8400
#define SCN_T 512
#define NW8 (SCN_T / 64)
#define CAPI 1536                  // per-slice iou candidates (3/thread)
#define CAPC 512                   // per-slice cost candidates (1/thread)
#define CAPT 1024                  // per-GT threshold candidates (2/thread)
#define PREP_BLKS ((NPRI + 255) / 256)

typedef unsigned long long u64;

__device__ __forceinline__ int get_label(const void* p, int j, int is64) {
    if (is64) return (int)((const long long*)p)[j];
    return ((const int*)p)[j];
}

// ---------- wave helpers (reduce + broadcast) ----------
__device__ __forceinline__ float wave_min_bc_f32(float v) {
    #pragma unroll
    for (int off = 32; off > 0; off >>= 1) v = fminf(v, __shfl_down(v, off, 64));
    return __int_as_float(__builtin_amdgcn_readfirstlane(__float_as_int(v)));
}
__device__ __forceinline__ int wave_sum_i32(int v) {
    #pragma unroll
    for (int off = 32; off > 0; off >>= 1) v += __shfl_down(v, off, 64);
    return v;
}
__device__ __forceinline__ u64 wave_max_bc_u64(u64 v) {
    #pragma unroll
    for (int off = 32; off > 0; off >>= 1) { u64 o = __shfl_down(v, off, 64); v = (o > v) ? o : v; }
    unsigned lo = (unsigned)__builtin_amdgcn_readfirstlane((int)(v & 0xffffffffull));
    unsigned hi = (unsigned)__builtin_amdgcn_readfirstlane((int)(v >> 32));
    return (((u64)hi) << 32) | lo;
}
__device__ __forceinline__ u64 wave_min_bc_u64(u64 v) {
    #pragma unroll
    for (int off = 32; off > 0; off >>= 1) { u64 o = __shfl_down(v, off, 64); v = (o < v) ? o : v; }
    unsigned lo = (unsigned)__builtin_amdgcn_readfirstlane((int)(v & 0xffffffffull));
    unsigned hi = (unsigned)__builtin_amdgcn_readfirstlane((int)(v >> 32));
    return (((u64)hi) << 32) | lo;
}
// per-wave top-13 from per-thread NSL-slot ascending lists (keys idx-distinct -> exact)
template<int NSL>
__device__ __forceinline__ void wave_merge_maxN(u64 (&l)[NSL], u64* dst, int lane) {
    int p = 0;
    for (int r = 0; r < KTOP; ++r) {
        u64 cur = 0ull;
        #pragma unroll
        for (int s = 0; s < NSL; ++s) if (s == p) cur = l[NSL - 1 - s];
        u64 bm = wave_max_bc_u64(cur);
        if (cur == bm && bm != 0ull) p++;
        if (lane == 0) dst[r] = bm;
    }
}
template<int NSL>
__device__ __forceinline__ void wave_merge_minN(u64 (&l)[NSL], u64* dst, int lane) {
    int p = 0;
    for (int r = 0; r < KTOP; ++r) {
        u64 cur = ~0ull;
        #pragma unroll
        for (int s = 0; s < NSL; ++s) if (s == p) cur = l[s];
        u64 bm = wave_min_bc_u64(cur);
        if (cur == bm && bm != ~0ull) p++;
        if (lane == 0) dst[r] = bm;
    }
}

// ---------- exact formulas (verbatim round-2: bit-identical selection) ----------
__device__ __forceinline__ float iou_exact(float4 pb, float areap, float gx1, float gy1,
                                           float gx2, float gy2, float areag) {
    float iw = fmaxf(fminf(pb.z, gx2) - fmaxf(pb.x, gx1), 0.0f);
    float ih = fmaxf(fminf(pb.w, gy2) - fmaxf(pb.y, gy1), 0.0f);
    float inter = iw * ih;
    return inter / fmaxf(areap + areag - inter, 1e-6f);
}
__device__ __forceinline__ float cost_exact(float4 p2, float gcx, float gcy,
                                            float l, float iou) {
    float dx = p2.x - gcx, dy = p2.y - gcy;
    float dist = sqrtf(dx * dx + dy * dy) / p2.z;
    float soft = exp2f((dist - 3.0f) * L10);
    float sig = 1.0f / (1.0f + expf(-l));
    float dd = iou - sig;
    float bce = fmaxf(l, 0.0f) - l * iou + log1pf(expf(-fabsf(l)));
    float iouc = -logf(iou + EPS_F) * 3.0f;
    return bce * (dd * dd) + iouc + soft;
}

// ---------- prep: detect int64 + init + valid mask + packed arrays ----------
__global__ __launch_bounds__(256) void k_prep(
        const float* __restrict__ priors, const float* __restrict__ gt,
        const void* labels, const float* __restrict__ pboxes,
        float4* __restrict__ pbp, float4* __restrict__ p2c,
        int* count, int* firstgt, int* flag, int* nmulti) {
    __shared__ float4 gbox[NGT];
    __shared__ int    gpad[NGT];
    __shared__ int    bad;
    const int tid = threadIdx.x;
    const int b = blockIdx.x;
    if (b == 0 && tid == 0) { bad = 0; *nmulti = 0; }
    {
        float4 bx = ((const float4*)gt)[tid];
        gbox[tid] = bx;
        gpad[tid] = ((bx.x + bx.y + bx.z + bx.w) > 0.0f) ? 1 : 0;
    }
    __syncthreads();
    if (b == 0 && tid < 128) {
        long long v = ((const long long*)labels)[tid];   // first 1024B: in-bounds either layout
        if (v < 0 || v >= NCLS) atomicOr(&bad, 1);
    }
    int i = b * 256 + tid;
    if (i < NPRI) {
        count[i] = 0; firstgt[i] = NGT;
        float4 pr = ((const float4*)priors)[i];
        float px = pr.x, py = pr.y;
        int v = 0;
        for (int j = 0; j < NGT; ++j) {
            float4 bx = gbox[j];
            float m = fminf(fminf(px - bx.x, py - bx.y), fminf(bx.z - px, bx.w - py));
            if (m > 0.0f && gpad[j]) { v = 1; break; }
        }
        float4 p2 = make_float4(px, py, pr.z, v ? 1.0f : 0.0f);
        pbp[2 * i]     = ((const float4*)pboxes)[i];
        pbp[2 * i + 1] = p2;
        p2c[i] = p2;
    }
    if (b == 0) {
        __syncthreads();
        if (tid == 0) *flag = bad ? 0 : 1;   // 1 => int64 layout
    }
}

// ---------- per-GT deterministic threshold: ladder count -> collect -> exact tau -> Dmax ----------
__global__ __launch_bounds__(512) void k_thresh(
        const float* __restrict__ scores,
        const float4* __restrict__ pbp, const float4* __restrict__ p2c,
        const float* __restrict__ gt, const void* labels, const int* flag,
        float* __restrict__ dmaxA, int* __restrict__ zbadA) {
    const int tid = threadIdx.x, lane = tid & 63, wid = tid >> 6;
    const int j = blockIdx.x;
    const int is64 = *flag;
    const float4 gb = ((const float4*)gt)[j];
    const float gx1 = gb.x, gy1 = gb.y, gx2 = gb.z, gy2 = gb.w;
    const float areag = (gx2 - gx1) * (gy2 - gy1);
    const float gcx = (gx1 + gx2) * 0.5f, gcy = (gy1 + gy2) * 0.5f;
    const int lab = get_label(labels, j, is64);

    const float R0 = 1.5f, R1 = 2.5f, R2 = 4.0f, R3 = 7.0f, R4 = 12.0f, R5 = 24.0f;
    int c0 = 0, c1 = 0, c2 = 0, c3 = 0, c4 = 0, c5 = 0, c6 = 0;
    for (int i = tid; i < NPRI; i += 512) {
        float4 p2 = p2c[i];
        if (p2.w != 0.0f) {
            float dx = p2.x - gcx, dy = p2.y - gcy;
            float dxx = dx * dx + dy * dy;
            float z = p2.z;
            c0 += (dxx <= (z * R0) * (z * R0));
            c1 += (dxx <= (z * R1) * (z * R1));
            c2 += (dxx <= (z * R2) * (z * R2));
            c3 += (dxx <= (z * R3) * (z * R3));
            c4 += (dxx <= (z * R4) * (z * R4));
            c5 += (dxx <= (z * R5) * (z * R5));
            c6++;
        }
    }
    __shared__ int scnt[7];
    if (tid < 7) scnt[tid] = 0;
    __syncthreads();
    {
        int v;
        v = wave_sum_i32(c0); if (lane == 0) atomicAdd(&scnt[0], v);
        v = wave_sum_i32(c1); if (lane == 0) atomicAdd(&scnt[1], v);
        v = wave_sum_i32(c2); if (lane == 0) atomicAdd(&scnt[2], v);
        v = wave_sum_i32(c3); if (lane == 0) atomicAdd(&scnt[3], v);
        v = wave_sum_i32(c4); if (lane == 0) atomicAdd(&scnt[4], v);
        v = wave_sum_i32(c5); if (lane == 0) atomicAdd(&scnt[5], v);
        v = wave_sum_i32(c6); if (lane == 0) atomicAdd(&scnt[6], v);
    }
    __syncthreads();
    float rsel = -1.0f;
    if      (scnt[0] >= KTOP) rsel = R0;
    else if (scnt[1] >= KTOP) rsel = R1;
    else if (scnt[2] >= KTOP) rsel = R2;
    else if (scnt[3] >= KTOP) rsel = R3;
    else if (scnt[4] >= KTOP) rsel = R4;
    else if (scnt[5] >= KTOP) rsel = R5;
    bool zb = (rsel < 0.0f);   // <13 valid within 192px (or anywhere) -> exact fallback

    __shared__ int s_n;
    __shared__ int cand[CAPT];
    if (tid == 0) s_n = 0;
    __syncthreads();
    if (!zb) {
        for (int i = tid; i < NPRI; i += 512) {
            float4 p2 = p2c[i];
            if (p2.w != 0.0f) {
                float dx = p2.x - gcx, dy = p2.y - gcy;
                float rad = p2.z * rsel;
                if (dx * dx + dy * dy <= rad * rad) {
                    int p = atomicAdd(&s_n, 1);
                    if (p < CAPT) cand[p] = i;
                }
            }
        }
    }
    __syncthreads();
    int n = s_n;
    if (n > CAPT) zb = true;

    // exact costs of candidates; block 13th-smallest value (dup-collapse only loosens tau)
    const float FINF = __int_as_float(0x7f800000);
    float s0 = FINF, s1 = FINF;   // ascending 2-slot
    if (!zb) {
        for (int k = tid; k < n; k += 512) {   // <=2 iters
            int i = cand[k];
            float4 pb = pbp[2 * i];
            float4 p2 = pbp[2 * i + 1];
            float areap = (pb.z - pb.x) * (pb.w - pb.y);
            float iou = iou_exact(pb, areap, gx1, gy1, gx2, gy2, areag);
            float l = scores[(size_t)i * NCLS + lab];
            float c = cost_exact(p2, gcx, gcy, l, iou);
            if (c < s1) { s1 = c; if (s1 < s0) { float t = s0; s0 = s1; s1 = t; } }
        }
    }
    __shared__ float wA[NW8 * KTOP];
    {
        int p = 0;
        for (int r = 0; r < KTOP; ++r) {
            float cur = (p == 0) ? s0 : ((p == 1) ? s1 : FINF);
            float m = wave_min_bc_f32(cur);
            if (cur == m && m < FINF) p++;
            if (lane == 0) wA[wid * KTOP + r] = m;
        }
    }
    __syncthreads();
    if (wid == 0) {
        int p = 0; float tau = FINF;
        for (int r = 0; r < KTOP; ++r) {
            float cur = (lane < NW8 && p < KTOP) ? wA[lane * KTOP + p] : FINF;
            float m = wave_min_bc_f32(cur);
            if (cur == m && m < FINF) p++;
            if (r == KTOP - 1) tau = m;
        }
        if (lane == 0) {
            int zb2 = zb || !(tau < 9.0e7f);
            // any true top-13 member: soft <= cost <= tau  =>  dist <= 3 + log10(tau)
            dmaxA[j] = zb2 ? 0.0f
                : (3.0f + __log2f(tau + 1e-5f) * (1.0f / L10) + 4e-3f);
            zbadA[j] = zb2;
        }
    }
}

// ---------- sliced scan: append-only candidates, exact top-13s ----------
__global__ __launch_bounds__(SCN_T) void k_scan(
        const float* __restrict__ scores,
        const float4* __restrict__ pbp, const float* __restrict__ gt,
        const void* labels, const int* flag,
        const float* __restrict__ dmaxA, const int* __restrict__ zbadA,
        u64* __restrict__ part_iou, u64* __restrict__ part_cost) {
    const int tid = threadIdx.x, lane = tid & 63, wid = tid >> 6;
    const int j = blockIdx.x, slice = blockIdx.y;
    const int base = slice * SLEN;
    const int is64 = *flag;

    const float4 gb = ((const float4*)gt)[j];
    const float gx1 = gb.x, gy1 = gb.y, gx2 = gb.z, gy2 = gb.w;
    const float areag = (gx2 - gx1) * (gy2 - gy1);
    const float gcx = (gx1 + gx2) * 0.5f, gcy = (gy1 + gy2) * 0.5f;
    const int lab = get_label(labels, j, is64);
    const float dmax = dmaxA[j];
    const int zbad = zbadA[j];

    __shared__ int s_ni, s_nc;
    __shared__ u64 liou[CAPI];
    __shared__ int lcost[CAPC];
    __shared__ u64 wio[NW8 * KTOP], wco[NW8 * KTOP];
    if (tid == 0) { s_ni = 0; s_nc = 0; }
    __syncthreads();

    for (int i = base + tid; i < base + SLEN; i += SCN_T) {
        float4 pb = pbp[2 * i];
        float4 p2 = pbp[2 * i + 1];
        float areap = (pb.z - pb.x) * (pb.w - pb.y);
        float iw = fmaxf(fminf(pb.z, gx2) - fmaxf(pb.x, gx1), 0.0f);
        float ih = fmaxf(fminf(pb.w, gy2) - fmaxf(pb.y, gy1), 0.0f);
        float inter = iw * ih;
        float iou = inter / fmaxf(areap + areag - inter, 1e-6f);   // exact
        if (iou > 0.0f) {
            int p = atomicAdd(&s_ni, 1);
            if (p < CAPI) liou[p] = (((u64)__float_as_uint(iou)) << 32) | (unsigned)i;
        }
        if (!zbad && p2.w != 0.0f) {
            float dx = p2.x - gcx, dy = p2.y - gcy;
            float rad = p2.z * dmax;
            if (dx * dx + dy * dy <= rad * rad * (1.0f + 1e-5f)) {
                int p = atomicAdd(&s_nc, 1);
                if (p < CAPC) lcost[p] = i;
            }
        }
    }
    __syncthreads();
    const int ni = s_ni, nc = s_nc;
    const bool fI = (ni > CAPI);
    const bool fC = zbad || (nc > CAPC);

    // ---- iou top-13 ----
    if (!fI) {
        u64 l3[3] = {0ull, 0ull, 0ull};
        for (int k = tid; k < ni; k += SCN_T) {   // <=3 iters
            u64 key = liou[k];
            if (key > l3[0]) {
                l3[0] = key;
                if (l3[0] > l3[1]) { u64 t = l3[0]; l3[0] = l3[1]; l3[1] = t; }
                if (l3[1] > l3[2]) { u64 t = l3[1]; l3[1] = l3[2]; l3[2] = t; }
            }
        }
        wave_merge_maxN<3>(l3, &wio[wid * KTOP], lane);
    } else {
        u64 lf[KTOP];
        #pragma unroll
        for (int s = 0; s < KTOP; ++s) lf[s] = 0ull;
        for (int i = base + tid; i < base + SLEN; i += SCN_T) {
            float4 pb = pbp[2 * i];
            float areap = (pb.z - pb.x) * (pb.w - pb.y);
            float iou = iou_exact(pb, areap, gx1, gy1, gx2, gy2, areag);
            unsigned ib = __float_as_uint(iou);
            if (ib > (unsigned)(lf[0] >> 32)) {
                lf[0] = (((u64)ib) << 32) | (unsigned)i;
                #pragma unroll
                for (int s = 0; s < KTOP - 1; ++s)
                    if (lf[s] > lf[s + 1]) { u64 t = lf[s]; lf[s] = lf[s + 1]; lf[s + 1] = t; }
            }
        }
        wave_merge_maxN<KTOP>(lf, &wio[wid * KTOP], lane);
    }

    // ---- cost top-13 ----
    if (!fC) {
        u64 ck[1] = {~0ull};
        if (tid < nc) {   // nc <= 512 == SCN_T
            int i = lcost[tid];
            float4 pb = pbp[2 * i];
            float4 p2 = pbp[2 * i + 1];
            float areap = (pb.z - pb.x) * (pb.w - pb.y);
            float iou = iou_exact(pb, areap, gx1, gy1, gx2, gy2, areag);
            float ec = cost_exact(p2, gcx, gcy, scores[(size_t)i * NCLS + lab], iou);
            ck[0] = (((u64)__float_as_uint(ec)) << 32) | (unsigned)i;
        }
        wave_merge_minN<1>(ck, &wco[wid * KTOP], lane);
    } else {
        u64 lf[KTOP];
        #pragma unroll
        for (int s = 0; s < KTOP; ++s) lf[s] = ~0ull;
        for (int i = base + tid; i < base + SLEN; i += SCN_T) {
            float4 pb = pbp[2 * i];
            float4 p2 = pbp[2 * i + 1];
            float areap = (pb.z - pb.x) * (pb.w - pb.y);
            float iou = iou_exact(pb, areap, gx1, gy1, gx2, gy2, areag);
            float ec = INF_F;
            if (p2.w != 0.0f) ec = cost_exact(p2, gcx, gcy, scores[(size_t)i * NCLS + lab], iou);
            u64 k2 = (((u64)__float_as_uint(ec)) << 32) | (unsigned)i;
            if (k2 < lf[KTOP - 1]) {
                lf[KTOP - 1] = k2;
                #pragma unroll
                for (int s = KTOP - 1; s > 0; --s)
                    if (lf[s] < lf[s - 1]) { u64 t = lf[s]; lf[s] = lf[s - 1]; lf[s - 1] = t; }
            }
        }
        wave_merge_minN<KTOP>(lf, &wco[wid * KTOP], lane);
    }

    __syncthreads();
    if (wid == 0) {
        int p = 0;
        u64* dpi = part_iou + ((size_t)j * SLC + slice) * KTOP;
        for (int r = 0; r < KTOP; ++r) {
            u64 cur = (lane < NW8 && p < KTOP) ? wio[lane * KTOP + p] : 0ull;
            u64 bm = wave_max_bc_u64(cur);
            if (cur == bm && bm != 0ull) p++;
            if (lane == 0) dpi[r] = bm;
        }
    } else if (wid == 1) {
        int p = 0;
        u64* dpc = part_cost + ((size_t)j * SLC + slice) * KTOP;
        for (int r = 0; r < KTOP; ++r) {
            u64 cur = (lane < NW8 && p < KTOP) ? wco[lane * KTOP + p] : ~0ull;
            u64 bm = wave_min_bc_u64(cur);
            if (cur == bm && bm != ~0ull) p++;
            if (lane == 0) dpc[r] = bm;
        }
    }
}

// ---------- merge 4 slices per GT, compute ks, scatter ----------
__global__ __launch_bounds__(64) void k_merge(
        const u64* __restrict__ part_iou, const u64* __restrict__ part_cost,
        int* count, int* firstgt) {
    const int j = blockIdx.x;
    const int lane = threadIdx.x;
    u64 ki = (lane < SLC * KTOP) ? part_iou[(size_t)j * SLC * KTOP + lane] : 0ull;
    float tsum = 0.0f;
    for (int r = 0; r < KTOP; ++r) {
        u64 bm = wave_max_bc_u64(ki);
        if (ki == bm && bm != 0ull) ki = 0ull;
        tsum += __uint_as_float((unsigned)(bm >> 32));   // descending-order sum
    }
    int ks = (int)tsum;
    if (ks < 1) ks = 1;
    u64 kc = (lane < SLC * KTOP) ? part_cost[(size_t)j * SLC * KTOP + lane] : ~0ull;
    u64 mine = ~0ull;
    for (int r = 0; r < KTOP; ++r) {
        u64 bm = wave_min_bc_u64(kc);
        if (kc == bm && bm != ~0ull) kc = ~0ull;
        if (lane == r) mine = bm;
    }
    if (lane < KTOP && lane < ks && mine != ~0ull) {
        int idx = (int)(unsigned)(mine & 0xFFFFFFFFull);
        atomicAdd(&count[idx], 1);
        atomicMin(&firstgt[idx], j);
    }
}

// ---------- per-prior finalize; multi-matched priors -> worklist ----------
__global__ __launch_bounds__(256) void k_assign(
        const float4* __restrict__ pbp, const float* __restrict__ gt,
        const void* labels, const int* flag,
        const int* __restrict__ count, const int* __restrict__ firstgt,
        int* nmulti, int* mlist, float* __restrict__ out) {
    __shared__ float4 gbox[NGT];
    __shared__ int glab[NGT];
    __shared__ float gareas[NGT];
    int tid = threadIdx.x;
    int is64 = *flag;
    {
        float4 b = ((const float4*)gt)[tid];
        gbox[tid] = b;
        glab[tid] = get_label(labels, tid, is64);
        gareas[tid] = (b.z - b.x) * (b.w - b.y);
    }
    __syncthreads();
    int i = blockIdx.x * 256 + tid;
    if (i >= NPRI) return;
    float4 p2 = pbp[2 * i + 1];
    int v = (p2.w != 0.0f) ? 1 : 0;
    int c = count[i];
    float o0 = 0.0f, o1 = -INF_F, o2 = -1.0f;
    if (v && c == 1) {
        int j = firstgt[i];
        float4 pb = pbp[2 * i];
        float areap = (pb.z - pb.x) * (pb.w - pb.y);
        float4 g = gbox[j];
        float iw = fmaxf(fminf(pb.z, g.z) - fmaxf(pb.x, g.x), 0.0f);
        float ih = fmaxf(fminf(pb.w, g.w) - fmaxf(pb.y, g.y), 0.0f);
        float inter = iw * ih;
        float iou = inter / fmaxf(areap + gareas[j] - inter, 1e-6f);
        o0 = (float)(j + 1); o1 = iou; o2 = (float)glab[j];
    } else if (v && c > 1) {
        int pos = atomicAdd(nmulti, 1);
        mlist[pos] = i;
    }
    out[i] = o0;
    out[NPRI + i] = o1;
    out[2 * NPRI + i] = o2;
}

// ---------- one block per multi prior: block argmin over 256 GT costs ----------
__global__ __launch_bounds__(256) void k_multi(
        const float* __restrict__ scores,
        const float4* __restrict__ pbp, const float* __restrict__ gt,
        const void* labels, const int* flag,
        const int* __restrict__ nmulti, const int* __restrict__ mlist,
        float* __restrict__ out) {
    __shared__ float4 gbox[NGT];
    __shared__ int glab[NGT];
    __shared__ float gcxs[NGT], gcys[NGT], gareas[NGT];
    __shared__ u64 red4[4];
    const int tid = threadIdx.x;
    const int is64 = *flag;
    {
        float4 b = ((const float4*)gt)[tid];
        gbox[tid] = b;
        glab[tid] = get_label(labels, tid, is64);
        gcxs[tid] = (b.x + b.z) * 0.5f;
        gcys[tid] = (b.y + b.w) * 0.5f;
        gareas[tid] = (b.z - b.x) * (b.w - b.y);
    }
    __syncthreads();
    const int nm = *nmulti;
    const int j = tid;
    for (int m = blockIdx.x; m < nm; m += gridDim.x) {
        const int i = mlist[m];
        float4 pb = pbp[2 * i];
        float4 p2 = pbp[2 * i + 1];
        float areap = (pb.z - pb.x) * (pb.w - pb.y);

        float4 g = gbox[j];
        float iw = fmaxf(fminf(pb.z, g.z) - fmaxf(pb.x, g.x), 0.0f);
        float ih = fmaxf(fminf(pb.w, g.w) - fmaxf(pb.y, g.y), 0.0f);
        float inter = iw * ih;
        float iou = inter / fmaxf(areap + gareas[j] - inter, 1e-6f);
        float dx = p2.x - gcxs[j], dy = p2.y - gcys[j];
        float dist = sqrtf(dx * dx + dy * dy) / p2.z;
        float soft = exp2f((dist - 3.0f) * L10);
        float l = scores[(size_t)i * NCLS + glab[j]];
        float sig = 1.0f / (1.0f + expf(-l));
        float dd = iou - sig;
        float bce = fmaxf(l, 0.0f) - l * iou + log1pf(expf(-fabsf(l)));
        float cost = bce * (dd * dd) + (-logf(iou + EPS_F) * 3.0f) + soft;

        u64 key = (((u64)__float_as_uint(cost)) << 32) | (unsigned)j;
        u64 v = key;
        #pragma unroll
        for (int off = 32; off > 0; off >>= 1) {
            u64 o = __shfl_down(v, off, 64);
            v = (o < v) ? o : v;
        }
        if ((tid & 63) == 0) red4[tid >> 6] = v;
        __syncthreads();
        u64 best = red4[0];
        #pragma unroll
        for (int q = 1; q < 4; ++q) best = (red4[q] < best) ? red4[q] : best;
        if (key == best) {
            out[i] = (float)(j + 1);
            out[NPRI + i] = iou;
            out[2 * NPRI + i] = (float)glab[j];
        }
        __syncthreads();
    }
}

extern "C" void kernel_launch(void* const* d_in, const int* in_sizes, int n_in,
                              void* d_out, int out_size, void* d_ws, size_t ws_size,
                              hipStream_t stream) {
    const float* scores = (const float*)d_in[0];
    const float* priors = (const float*)d_in[1];
    const float* pboxes = (const float*)d_in[2];
    const float* gt     = (const float*)d_in[3];
    const void*  labels = d_in[4];
    float* out = (float*)d_out;

    char* ws = (char*)d_ws;
    size_t off = 0;
    auto alloc = [&](size_t bytes) { size_t o = off; off = (off + bytes + 255) & ~(size_t)255; return o; };
    int*    flag     = (int*)(ws + alloc(4));
    int*    nmulti   = (int*)(ws + alloc(4));
    int*    count    = (int*)(ws + alloc((size_t)NPRI * 4));
    int*    firstgt  = (int*)(ws + alloc((size_t)NPRI * 4));
    int*    mlist    = (int*)(ws + alloc((size_t)NPRI * 4));
    float*  dmaxA    = (float*)(ws + alloc(NGT * 4));
    int*    zbadA    = (int*)(ws + alloc(NGT * 4));
    u64*    part_iou = (u64*)(ws + alloc((size_t)NGT * SLC * KTOP * 8));
    u64*    part_cost= (u64*)(ws + alloc((size_t)NGT * SLC * KTOP * 8));
    float4* pbp      = (float4*)(ws + alloc((size_t)NPRI * 32));
    float4* p2c      = (float4*)(ws + alloc((size_t)NPRI * 16));
    (void)ws_size;

    hipLaunchKernelGGL(k_prep, dim3(PREP_BLKS), dim3(256), 0, stream,
                       priors, gt, labels, pboxes, pbp, p2c, count, firstgt, flag, nmulti);
    hipLaunchKernelGGL(k_thresh, dim3(NGT), dim3(512), 0, stream,
                       scores, pbp, p2c, gt, labels, flag, dmaxA, zbadA);
    hipLaunchKernelGGL(k_scan, dim3(NGT, SLC), dim3(SCN_T), 0, stream,
                       scores, pbp, gt, labels, flag, dmaxA, zbadA, part_iou, part_cost);
    hipLaunchKernelGGL(k_merge, dim3(NGT), dim3(64), 0, stream,
                       part_iou, part_cost, count, firstgt);
    hipLaunchKernelGGL(k_assign, dim3((NPRI + 255) / 256), dim3(256), 0, stream,
                       pbp, gt, labels, flag, count, firstgt, nmulti, mlist, out);
    hipLaunchKernelGGL(k_multi, dim3(256), dim3(256), 0, stream,
                       scores, pbp, gt, labels, flag, nmulti, mlist, out);
}

// Round 10
// 206.925 us; speedup vs baseline: 1.7827x; 1.1107x over previous
//
#include <hip/hip_runtime.h>
#include <cstdint>

#define NPRI 33600
#define NGT  256
#define NCLS 80
#define KTOP 13
#define INF_F 1.0e8f
#define EPS_F 1e-7f
#define L10 3.3219280948873623f
#define SLC  4
#define SLEN (NPRI / SLC)          // 8400
#define SCN_T 512
#define NW8 (SCN_T / 64)
#define CAPI 1536                  // per-slice iou candidates (3/thread)
#define CAPC 512                   // per-slice cost candidates (1/thread)
#define PREP_BLKS ((NPRI + 255) / 256)

typedef unsigned long long u64;

__device__ __forceinline__ int get_label(const void* p, int j, int is64) {
    if (is64) return (int)((const long long*)p)[j];
    return ((const int*)p)[j];
}

// ---------- wave helpers (reduce + broadcast) ----------
__device__ __forceinline__ u64 wave_max_bc_u64(u64 v) {
    #pragma unroll
    for (int off = 32; off > 0; off >>= 1) { u64 o = __shfl_down(v, off, 64); v = (o > v) ? o : v; }
    unsigned lo = (unsigned)__builtin_amdgcn_readfirstlane((int)(v & 0xffffffffull));
    unsigned hi = (unsigned)__builtin_amdgcn_readfirstlane((int)(v >> 32));
    return (((u64)hi) << 32) | lo;
}
__device__ __forceinline__ u64 wave_min_bc_u64(u64 v) {
    #pragma unroll
    for (int off = 32; off > 0; off >>= 1) { u64 o = __shfl_down(v, off, 64); v = (o < v) ? o : v; }
    unsigned lo = (unsigned)__builtin_amdgcn_readfirstlane((int)(v & 0xffffffffull));
    unsigned hi = (unsigned)__builtin_amdgcn_readfirstlane((int)(v >> 32));
    return (((u64)hi) << 32) | lo;
}
// per-wave top-13 from per-thread NSL-slot ascending lists (keys idx-distinct -> exact)
template<int NSL>
__device__ __forceinline__ void wave_merge_maxN(u64 (&l)[NSL], u64* dst, int lane) {
    int p = 0;
    for (int r = 0; r < KTOP; ++r) {
        u64 cur = 0ull;
        #pragma unroll
        for (int s = 0; s < NSL; ++s) if (s == p) cur = l[NSL - 1 - s];
        u64 bm = wave_max_bc_u64(cur);
        if (cur == bm && bm != 0ull) p++;
        if (lane == 0) dst[r] = bm;
    }
}
template<int NSL>
__device__ __forceinline__ void wave_merge_minN(u64 (&l)[NSL], u64* dst, int lane) {
    int p = 0;
    for (int r = 0; r < KTOP; ++r) {
        u64 cur = ~0ull;
        #pragma unroll
        for (int s = 0; s < NSL; ++s) if (s == p) cur = l[s];
        u64 bm = wave_min_bc_u64(cur);
        if (cur == bm && bm != ~0ull) p++;
        if (lane == 0) dst[r] = bm;
    }
}

// ---------- exact formulas (verbatim round-2: bit-identical selection) ----------
__device__ __forceinline__ float iou_exact(float4 pb, float areap, float gx1, float gy1,
                                           float gx2, float gy2, float areag) {
    float iw = fmaxf(fminf(pb.z, gx2) - fmaxf(pb.x, gx1), 0.0f);
    float ih = fmaxf(fminf(pb.w, gy2) - fmaxf(pb.y, gy1), 0.0f);
    float inter = iw * ih;
    return inter / fmaxf(areap + areag - inter, 1e-6f);
}
__device__ __forceinline__ float cost_exact(float4 p2, float gcx, float gcy,
                                            float l, float iou) {
    float dx = p2.x - gcx, dy = p2.y - gcy;
    float dist = sqrtf(dx * dx + dy * dy) / p2.z;
    float soft = exp2f((dist - 3.0f) * L10);
    float sig = 1.0f / (1.0f + expf(-l));
    float dd = iou - sig;
    float bce = fmaxf(l, 0.0f) - l * iou + log1pf(expf(-fabsf(l)));
    float iouc = -logf(iou + EPS_F) * 3.0f;
    return bce * (dd * dd) + iouc + soft;
}

// ---------- prep: detect int64 + init + valid mask + packed arrays ----------
__global__ __launch_bounds__(256) void k_prep(
        const float* __restrict__ priors, const float* __restrict__ gt,
        const void* labels, const float* __restrict__ pboxes,
        float4* __restrict__ pbp, float4* __restrict__ p2c,
        int* count, int* firstgt, int* flag, int* nmulti) {
    __shared__ float4 gbox[NGT];
    __shared__ int    gpad[NGT];
    __shared__ int    bad;
    const int tid = threadIdx.x;
    const int b = blockIdx.x;
    if (b == 0 && tid == 0) { bad = 0; *nmulti = 0; }
    {
        float4 bx = ((const float4*)gt)[tid];
        gbox[tid] = bx;
        gpad[tid] = ((bx.x + bx.y + bx.z + bx.w) > 0.0f) ? 1 : 0;
    }
    __syncthreads();
    if (b == 0 && tid < 128) {
        long long v = ((const long long*)labels)[tid];   // first 1024B: in-bounds either layout
        if (v < 0 || v >= NCLS) atomicOr(&bad, 1);
    }
    int i = b * 256 + tid;
    if (i < NPRI) {
        count[i] = 0; firstgt[i] = NGT;
        float4 pr = ((const float4*)priors)[i];
        float px = pr.x, py = pr.y;
        int v = 0;
        for (int j = 0; j < NGT; ++j) {
            float4 bx = gbox[j];
            float m = fminf(fminf(px - bx.x, py - bx.y), fminf(bx.z - px, bx.w - py));
            if (m > 0.0f && gpad[j]) { v = 1; break; }
        }
        float4 p2 = make_float4(px, py, pr.z, v ? 1.0f : 0.0f);
        pbp[2 * i]     = ((const float4*)pboxes)[i];
        pbp[2 * i + 1] = p2;
        p2c[i] = p2;
    }
    if (b == 0) {
        __syncthreads();
        if (tid == 0) *flag = bad ? 0 : 1;   // 1 => int64 layout
    }
}

// ---------- fused sliced scan: in-block tau (13 nearest -> exact costs) -> filter -> exact top-13s ----------
__global__ __launch_bounds__(SCN_T) void k_scan(
        const float* __restrict__ scores,
        const float4* __restrict__ pbp, const float4* __restrict__ p2c,
        const float* __restrict__ gt, const void* labels, const int* flag,
        u64* __restrict__ part_iou, u64* __restrict__ part_cost) {
    const int tid = threadIdx.x, lane = tid & 63, wid = tid >> 6;
    const int j = blockIdx.x, slice = blockIdx.y;
    const int base = slice * SLEN;
    const int is64 = *flag;

    const float4 gb = ((const float4*)gt)[j];
    const float gx1 = gb.x, gy1 = gb.y, gx2 = gb.z, gy2 = gb.w;
    const float areag = (gx2 - gx1) * (gy2 - gy1);
    const float gcx = (gx1 + gx2) * 0.5f, gcy = (gy1 + gy2) * 0.5f;
    const int lab = get_label(labels, j, is64);

    __shared__ int s_ni, s_nc, s_zbad;
    __shared__ float s_dmax;
    __shared__ u64 liou[CAPI];
    __shared__ int lcost[CAPC];
    __shared__ u64 wio[NW8 * KTOP], wco[NW8 * KTOP], wnr[NW8 * KTOP];
    __shared__ u64 snear[KTOP];
    __shared__ float scost[KTOP];
    if (tid == 0) { s_ni = 0; s_nc = 0; }

    // ---- Phase 0: per-thread nearest valid prior in slice (approx key = d^2/z^2; selection-only) ----
    u64 nk = ~0ull;
    for (int i = base + tid; i < base + SLEN; i += SCN_T) {
        float4 p2 = p2c[i];
        if (p2.w != 0.0f) {
            float dx = p2.x - gcx, dy = p2.y - gcy;
            float dn = __fdividef(dx * dx + dy * dy, p2.z * p2.z);
            u64 k = (((u64)__float_as_uint(dn)) << 32) | (unsigned)i;
            nk = (k < nk) ? k : nk;
        }
    }
    {
        u64 n1[1] = {nk};
        wave_merge_minN<1>(n1, &wnr[wid * KTOP], lane);
    }
    __syncthreads();
    if (wid == 0) {
        int p = 0;
        for (int r = 0; r < KTOP; ++r) {
            u64 cur = (lane < NW8 && p < KTOP) ? wnr[lane * KTOP + p] : ~0ull;
            u64 bm = wave_min_bc_u64(cur);
            if (cur == bm && bm != ~0ull) p++;
            if (lane == 0) snear[r] = bm;
        }
    }
    __syncthreads();
    // ---- Phase 0b: exact costs of the 13 slice-nearest -> tau -> Dmax (sound upper bound) ----
    const float FINF = __int_as_float(0x7f800000);
    if (tid < KTOP) {
        u64 k = snear[tid];
        float c = FINF;
        if (k != ~0ull) {
            int i = (int)(unsigned)(k & 0xffffffffull);
            float4 pb = pbp[2 * i];
            float4 p2 = pbp[2 * i + 1];
            float areap = (pb.z - pb.x) * (pb.w - pb.y);
            float iou = iou_exact(pb, areap, gx1, gy1, gx2, gy2, areag);
            c = cost_exact(p2, gcx, gcy, scores[(size_t)i * NCLS + lab], iou);
        }
        scost[tid] = c;
    }
    __syncthreads();
    if (tid == 0) {
        float tau = 0.0f; int zb = 0;
        for (int r = 0; r < KTOP; ++r) {
            if (snear[r] == ~0ull) zb = 1;
            else tau = fmaxf(tau, scost[r]);
        }
        if (!(tau < 9.0e7f)) zb = 1;   // INF-ambiguity zone -> exact fallback
        // any true top-13 member: soft <= cost <= global13th <= tau  =>  dist <= 3 + log10(tau)
        s_dmax = zb ? 0.0f : (3.0f + __log2f(tau + 1e-5f) * (1.0f / L10) + 4e-3f);
        s_zbad = zb;
    }
    __syncthreads();
    const float dmax = s_dmax;
    const int zbad = s_zbad;

    // ---- Phase 1: append-only scan over slice ----
    for (int i = base + tid; i < base + SLEN; i += SCN_T) {
        float4 pb = pbp[2 * i];
        float4 p2 = pbp[2 * i + 1];
        float areap = (pb.z - pb.x) * (pb.w - pb.y);
        float iw = fmaxf(fminf(pb.z, gx2) - fmaxf(pb.x, gx1), 0.0f);
        float ih = fmaxf(fminf(pb.w, gy2) - fmaxf(pb.y, gy1), 0.0f);
        float inter = iw * ih;
        float iou = inter / fmaxf(areap + areag - inter, 1e-6f);   // exact
        if (iou > 0.0f) {
            int p = atomicAdd(&s_ni, 1);
            if (p < CAPI) liou[p] = (((u64)__float_as_uint(iou)) << 32) | (unsigned)i;
        }
        if (!zbad && p2.w != 0.0f) {
            float dx = p2.x - gcx, dy = p2.y - gcy;
            float rad = p2.z * dmax;
            if (dx * dx + dy * dy <= rad * rad * (1.0f + 1e-5f)) {
                int p = atomicAdd(&s_nc, 1);
                if (p < CAPC) lcost[p] = i;
            }
        }
    }
    __syncthreads();
    const int ni = s_ni, nc = s_nc;
    const bool fI = (ni > CAPI);
    const bool fC = zbad || (nc > CAPC);

    // ---- Phase 2a: iou top-13 ----
    if (!fI) {
        u64 l3[3] = {0ull, 0ull, 0ull};
        for (int k = tid; k < ni; k += SCN_T) {   // <=3 iters
            u64 key = liou[k];
            if (key > l3[0]) {
                l3[0] = key;
                if (l3[0] > l3[1]) { u64 t = l3[0]; l3[0] = l3[1]; l3[1] = t; }
                if (l3[1] > l3[2]) { u64 t = l3[1]; l3[1] = l3[2]; l3[2] = t; }
            }
        }
        wave_merge_maxN<3>(l3, &wio[wid * KTOP], lane);
    } else {
        u64 lf[KTOP];
        #pragma unroll
        for (int s = 0; s < KTOP; ++s) lf[s] = 0ull;
        for (int i = base + tid; i < base + SLEN; i += SCN_T) {
            float4 pb = pbp[2 * i];
            float areap = (pb.z - pb.x) * (pb.w - pb.y);
            float iou = iou_exact(pb, areap, gx1, gy1, gx2, gy2, areag);
            unsigned ib = __float_as_uint(iou);
            if (ib > (unsigned)(lf[0] >> 32)) {
                lf[0] = (((u64)ib) << 32) | (unsigned)i;
                #pragma unroll
                for (int s = 0; s < KTOP - 1; ++s)
                    if (lf[s] > lf[s + 1]) { u64 t = lf[s]; lf[s] = lf[s + 1]; lf[s + 1] = t; }
            }
        }
        wave_merge_maxN<KTOP>(lf, &wio[wid * KTOP], lane);
    }

    // ---- Phase 2b: cost top-13 ----
    if (!fC) {
        u64 ck[1] = {~0ull};
        if (tid < nc) {   // nc <= CAPC == SCN_T
            int i = lcost[tid];
            float4 pb = pbp[2 * i];
            float4 p2 = pbp[2 * i + 1];
            float areap = (pb.z - pb.x) * (pb.w - pb.y);
            float iou = iou_exact(pb, areap, gx1, gy1, gx2, gy2, areag);
            float ec = cost_exact(p2, gcx, gcy, scores[(size_t)i * NCLS + lab], iou);
            ck[0] = (((u64)__float_as_uint(ec)) << 32) | (unsigned)i;
        }
        wave_merge_minN<1>(ck, &wco[wid * KTOP], lane);
    } else {
        u64 lf[KTOP];
        #pragma unroll
        for (int s = 0; s < KTOP; ++s) lf[s] = ~0ull;
        for (int i = base + tid; i < base + SLEN; i += SCN_T) {
            float4 pb = pbp[2 * i];
            float4 p2 = pbp[2 * i + 1];
            float areap = (pb.z - pb.x) * (pb.w - pb.y);
            float iou = iou_exact(pb, areap, gx1, gy1, gx2, gy2, areag);
            float ec = INF_F;
            if (p2.w != 0.0f) ec = cost_exact(p2, gcx, gcy, scores[(size_t)i * NCLS + lab], iou);
            u64 k2 = (((u64)__float_as_uint(ec)) << 32) | (unsigned)i;
            if (k2 < lf[KTOP - 1]) {
                lf[KTOP - 1] = k2;
                #pragma unroll
                for (int s = KTOP - 1; s > 0; --s)
                    if (lf[s] < lf[s - 1]) { u64 t = lf[s]; lf[s] = lf[s - 1]; lf[s - 1] = t; }
            }
        }
        wave_merge_minN<KTOP>(lf, &wco[wid * KTOP], lane);
    }

    __syncthreads();
    if (wid == 0) {
        int p = 0;
        u64* dpi = part_iou + ((size_t)j * SLC + slice) * KTOP;
        for (int r = 0; r < KTOP; ++r) {
            u64 cur = (lane < NW8 && p < KTOP) ? wio[lane * KTOP + p] : 0ull;
            u64 bm = wave_max_bc_u64(cur);
            if (cur == bm && bm != 0ull) p++;
            if (lane == 0) dpi[r] = bm;
        }
    } else if (wid == 1) {
        int p = 0;
        u64* dpc = part_cost + ((size_t)j * SLC + slice) * KTOP;
        for (int r = 0; r < KTOP; ++r) {
            u64 cur = (lane < NW8 && p < KTOP) ? wco[lane * KTOP + p] : ~0ull;
            u64 bm = wave_min_bc_u64(cur);
            if (cur == bm && bm != ~0ull) p++;
            if (lane == 0) dpc[r] = bm;
        }
    }
}

// ---------- merge 4 slices per GT, compute ks, scatter ----------
__global__ __launch_bounds__(64) void k_merge(
        const u64* __restrict__ part_iou, const u64* __restrict__ part_cost,
        int* count, int* firstgt) {
    const int j = blockIdx.x;
    const int lane = threadIdx.x;
    u64 ki = (lane < SLC * KTOP) ? part_iou[(size_t)j * SLC * KTOP + lane] : 0ull;
    float tsum = 0.0f;
    for (int r = 0; r < KTOP; ++r) {
        u64 bm = wave_max_bc_u64(ki);
        if (ki == bm && bm != 0ull) ki = 0ull;
        tsum += __uint_as_float((unsigned)(bm >> 32));   // descending-order sum
    }
    int ks = (int)tsum;
    if (ks < 1) ks = 1;
    u64 kc = (lane < SLC * KTOP) ? part_cost[(size_t)j * SLC * KTOP + lane] : ~0ull;
    u64 mine = ~0ull;
    for (int r = 0; r < KTOP; ++r) {
        u64 bm = wave_min_bc_u64(kc);
        if (kc == bm && bm != ~0ull) kc = ~0ull;
        if (lane == r) mine = bm;
    }
    if (lane < KTOP && lane < ks && mine != ~0ull) {
        int idx = (int)(unsigned)(mine & 0xFFFFFFFFull);
        atomicAdd(&count[idx], 1);
        atomicMin(&firstgt[idx], j);
    }
}

// ---------- per-prior finalize; multi-matched priors -> worklist ----------
__global__ __launch_bounds__(256) void k_assign(
        const float4* __restrict__ pbp, const float* __restrict__ gt,
        const void* labels, const int* flag,
        const int* __restrict__ count, const int* __restrict__ firstgt,
        int* nmulti, int* mlist, float* __restrict__ out) {
    __shared__ float4 gbox[NGT];
    __shared__ int glab[NGT];
    __shared__ float gareas[NGT];
    int tid = threadIdx.x;
    int is64 = *flag;
    {
        float4 b = ((const float4*)gt)[tid];
        gbox[tid] = b;
        glab[tid] = get_label(labels, tid, is64);
        gareas[tid] = (b.z - b.x) * (b.w - b.y);
    }
    __syncthreads();
    int i = blockIdx.x * 256 + tid;
    if (i >= NPRI) return;
    float4 p2 = pbp[2 * i + 1];
    int v = (p2.w != 0.0f) ? 1 : 0;
    int c = count[i];
    float o0 = 0.0f, o1 = -INF_F, o2 = -1.0f;
    if (v && c == 1) {
        int j = firstgt[i];
        float4 pb = pbp[2 * i];
        float areap = (pb.z - pb.x) * (pb.w - pb.y);
        float4 g = gbox[j];
        float iw = fmaxf(fminf(pb.z, g.z) - fmaxf(pb.x, g.x), 0.0f);
        float ih = fmaxf(fminf(pb.w, g.w) - fmaxf(pb.y, g.y), 0.0f);
        float inter = iw * ih;
        float iou = inter / fmaxf(areap + gareas[j] - inter, 1e-6f);
        o0 = (float)(j + 1); o1 = iou; o2 = (float)glab[j];
    } else if (v && c > 1) {
        int pos = atomicAdd(nmulti, 1);
        mlist[pos] = i;
    }
    out[i] = o0;
    out[NPRI + i] = o1;
    out[2 * NPRI + i] = o2;
}

// ---------- one block per multi prior: block argmin over 256 GT costs ----------
__global__ __launch_bounds__(256) void k_multi(
        const float* __restrict__ scores,
        const float4* __restrict__ pbp, const float* __restrict__ gt,
        const void* labels, const int* flag,
        const int* __restrict__ nmulti, const int* __restrict__ mlist,
        float* __restrict__ out) {
    __shared__ float4 gbox[NGT];
    __shared__ int glab[NGT];
    __shared__ float gcxs[NGT], gcys[NGT], gareas[NGT];
    __shared__ u64 red4[4];
    const int tid = threadIdx.x;
    const int is64 = *flag;
    {
        float4 b = ((const float4*)gt)[tid];
        gbox[tid] = b;
        glab[tid] = get_label(labels, tid, is64);
        gcxs[tid] = (b.x + b.z) * 0.5f;
        gcys[tid] = (b.y + b.w) * 0.5f;
        gareas[tid] = (b.z - b.x) * (b.w - b.y);
    }
    __syncthreads();
    const int nm = *nmulti;
    const int j = tid;
    for (int m = blockIdx.x; m < nm; m += gridDim.x) {
        const int i = mlist[m];
        float4 pb = pbp[2 * i];
        float4 p2 = pbp[2 * i + 1];
        float areap = (pb.z - pb.x) * (pb.w - pb.y);

        float4 g = gbox[j];
        float iw = fmaxf(fminf(pb.z, g.z) - fmaxf(pb.x, g.x), 0.0f);
        float ih = fmaxf(fminf(pb.w, g.w) - fmaxf(pb.y, g.y), 0.0f);
        float inter = iw * ih;
        float iou = inter / fmaxf(areap + gareas[j] - inter, 1e-6f);
        float dx = p2.x - gcxs[j], dy = p2.y - gcys[j];
        float dist = sqrtf(dx * dx + dy * dy) / p2.z;
        float soft = exp2f((dist - 3.0f) * L10);
        float l = scores[(size_t)i * NCLS + glab[j]];
        float sig = 1.0f / (1.0f + expf(-l));
        float dd = iou - sig;
        float bce = fmaxf(l, 0.0f) - l * iou + log1pf(expf(-fabsf(l)));
        float cost = bce * (dd * dd) + (-logf(iou + EPS_F) * 3.0f) + soft;

        u64 key = (((u64)__float_as_uint(cost)) << 32) | (unsigned)j;
        u64 v = key;
        #pragma unroll
        for (int off = 32; off > 0; off >>= 1) {
            u64 o = __shfl_down(v, off, 64);
            v = (o < v) ? o : v;
        }
        if ((tid & 63) == 0) red4[tid >> 6] = v;
        __syncthreads();
        u64 best = red4[0];
        #pragma unroll
        for (int q = 1; q < 4; ++q) best = (red4[q] < best) ? red4[q] : best;
        if (key == best) {
            out[i] = (float)(j + 1);
            out[NPRI + i] = iou;
            out[2 * NPRI + i] = (float)glab[j];
        }
        __syncthreads();
    }
}

extern "C" void kernel_launch(void* const* d_in, const int* in_sizes, int n_in,
                              void* d_out, int out_size, void* d_ws, size_t ws_size,
                              hipStream_t stream) {
    const float* scores = (const float*)d_in[0];
    const float* priors = (const float*)d_in[1];
    const float* pboxes = (const float*)d_in[2];
    const float* gt     = (const float*)d_in[3];
    const void*  labels = d_in[4];
    float* out = (float*)d_out;

    char* ws = (char*)d_ws;
    size_t off = 0;
    auto alloc = [&](size_t bytes) { size_t o = off; off = (off + bytes + 255) & ~(size_t)255; return o; };
    int*    flag     = (int*)(ws + alloc(4));
    int*    nmulti   = (int*)(ws + alloc(4));
    int*    count    = (int*)(ws + alloc((size_t)NPRI * 4));
    int*    firstgt  = (int*)(ws + alloc((size_t)NPRI * 4));
    int*    mlist    = (int*)(ws + alloc((size_t)NPRI * 4));
    u64*    part_iou = (u64*)(ws + alloc((size_t)NGT * SLC * KTOP * 8));
    u64*    part_cost= (u64*)(ws + alloc((size_t)NGT * SLC * KTOP * 8));
    float4* pbp      = (float4*)(ws + alloc((size_t)NPRI * 32));
    float4* p2c      = (float4*)(ws + alloc((size_t)NPRI * 16));
    (void)ws_size;

    hipLaunchKernelGGL(k_prep, dim3(PREP_BLKS), dim3(256), 0, stream,
                       priors, gt, labels, pboxes, pbp, p2c, count, firstgt, flag, nmulti);
    hipLaunchKernelGGL(k_scan, dim3(NGT, SLC), dim3(SCN_T), 0, stream,
                       scores, pbp, p2c, gt, labels, flag, part_iou, part_cost);
    hipLaunchKernelGGL(k_merge, dim3(NGT), dim3(64), 0, stream,
                       part_iou, part_cost, count, firstgt);
    hipLaunchKernelGGL(k_assign, dim3((NPRI + 255) / 256), dim3(256), 0, stream,
                       pbp, gt, labels, flag, count, firstgt, nmulti, mlist, out);
    hipLaunchKernelGGL(k_multi, dim3(256), dim3(256), 0, stream,
                       scores, pbp, gt, labels, flag, nmulti, mlist, out);
}

// Round 11
// 192.513 us; speedup vs baseline: 1.9162x; 1.0749x over previous
//
#include <hip/hip_runtime.h>
#include <cstdint>

#define NPRI 33600
#define NGT  256
#define NCLS 80
#define KTOP 13
#define INF_F 1.0e8f
#define EPS_F 1e-7f
#define L10 3.3219280948873623f
#define SLC  4
#define SLEN (NPRI / SLC)          // 8400
#define SCN_T 512
#define NW8 (SCN_T / 64)
#define CAPI 1536                  // per-slice iou candidates (3/thread)
#define CAPC 512                   // per-slice cost candidates (1/thread)
#define RFIX 5.5f                  // fixed collect radius (strides); Dmax typically ~4.7
#define PREP_BLKS ((NPRI + 255) / 256)

typedef unsigned long long u64;

__device__ __forceinline__ int get_label(const void* p, int j, int is64) {
    if (is64) return (int)((const long long*)p)[j];
    return ((const int*)p)[j];
}

// ---------- wave helpers (reduce + broadcast) ----------
__device__ __forceinline__ u64 wave_max_bc_u64(u64 v) {
    #pragma unroll
    for (int off = 32; off > 0; off >>= 1) { u64 o = __shfl_down(v, off, 64); v = (o > v) ? o : v; }
    unsigned lo = (unsigned)__builtin_amdgcn_readfirstlane((int)(v & 0xffffffffull));
    unsigned hi = (unsigned)__builtin_amdgcn_readfirstlane((int)(v >> 32));
    return (((u64)hi) << 32) | lo;
}
__device__ __forceinline__ u64 wave_min_bc_u64(u64 v) {
    #pragma unroll
    for (int off = 32; off > 0; off >>= 1) { u64 o = __shfl_down(v, off, 64); v = (o < v) ? o : v; }
    unsigned lo = (unsigned)__builtin_amdgcn_readfirstlane((int)(v & 0xffffffffull));
    unsigned hi = (unsigned)__builtin_amdgcn_readfirstlane((int)(v >> 32));
    return (((u64)hi) << 32) | lo;
}
// per-wave top-13 from per-thread NSL-slot ascending lists (keys idx-distinct -> exact)
template<int NSL>
__device__ __forceinline__ void wave_merge_maxN(u64 (&l)[NSL], u64* dst, int lane) {
    int p = 0;
    for (int r = 0; r < KTOP; ++r) {
        u64 cur = 0ull;
        #pragma unroll
        for (int s = 0; s < NSL; ++s) if (s == p) cur = l[NSL - 1 - s];
        u64 bm = wave_max_bc_u64(cur);
        if (cur == bm && bm != 0ull) p++;
        if (lane == 0) dst[r] = bm;
    }
}
template<int NSL>
__device__ __forceinline__ void wave_merge_minN(u64 (&l)[NSL], u64* dst, int lane) {
    int p = 0;
    for (int r = 0; r < KTOP; ++r) {
        u64 cur = ~0ull;
        #pragma unroll
        for (int s = 0; s < NSL; ++s) if (s == p) cur = l[s];
        u64 bm = wave_min_bc_u64(cur);
        if (cur == bm && bm != ~0ull) p++;
        if (lane == 0) dst[r] = bm;
    }
}

// ---------- exact formulas (verbatim round-2: bit-identical selection) ----------
__device__ __forceinline__ float iou_exact(float4 pb, float areap, float gx1, float gy1,
                                           float gx2, float gy2, float areag) {
    float iw = fmaxf(fminf(pb.z, gx2) - fmaxf(pb.x, gx1), 0.0f);
    float ih = fmaxf(fminf(pb.w, gy2) - fmaxf(pb.y, gy1), 0.0f);
    float inter = iw * ih;
    return inter / fmaxf(areap + areag - inter, 1e-6f);
}
__device__ __forceinline__ float cost_exact(float4 p2, float gcx, float gcy,
                                            float l, float iou) {
    float dx = p2.x - gcx, dy = p2.y - gcy;
    float dist = sqrtf(dx * dx + dy * dy) / p2.z;
    float soft = exp2f((dist - 3.0f) * L10);
    float sig = 1.0f / (1.0f + expf(-l));
    float dd = iou - sig;
    float bce = fmaxf(l, 0.0f) - l * iou + log1pf(expf(-fabsf(l)));
    float iouc = -logf(iou + EPS_F) * 3.0f;
    return bce * (dd * dd) + iouc + soft;
}

// ---------- prep: detect int64 + init + valid mask + packed array ----------
__global__ __launch_bounds__(256) void k_prep(
        const float* __restrict__ priors, const float* __restrict__ gt,
        const void* labels, const float* __restrict__ pboxes,
        float4* __restrict__ pbp,
        int* count, int* firstgt, int* flag, int* nmulti) {
    __shared__ float4 gbox[NGT];
    __shared__ int    gpad[NGT];
    __shared__ int    bad;
    const int tid = threadIdx.x;
    const int b = blockIdx.x;
    if (b == 0 && tid == 0) { bad = 0; *nmulti = 0; }
    {
        float4 bx = ((const float4*)gt)[tid];
        gbox[tid] = bx;
        gpad[tid] = ((bx.x + bx.y + bx.z + bx.w) > 0.0f) ? 1 : 0;
    }
    __syncthreads();
    if (b == 0 && tid < 128) {
        long long v = ((const long long*)labels)[tid];   // first 1024B: in-bounds either layout
        if (v < 0 || v >= NCLS) atomicOr(&bad, 1);
    }
    int i = b * 256 + tid;
    if (i < NPRI) {
        count[i] = 0; firstgt[i] = NGT;
        float4 pr = ((const float4*)priors)[i];
        float px = pr.x, py = pr.y;
        int v = 0;
        for (int j = 0; j < NGT; ++j) {
            float4 bx = gbox[j];
            float m = fminf(fminf(px - bx.x, py - bx.y), fminf(bx.z - px, bx.w - py));
            if (m > 0.0f && gpad[j]) { v = 1; break; }
        }
        pbp[2 * i]     = ((const float4*)pboxes)[i];
        pbp[2 * i + 1] = make_float4(px, py, pr.z, v ? 1.0f : 0.0f);
    }
    if (b == 0) {
        __syncthreads();
        if (tid == 0) *flag = bad ? 0 : 1;   // 1 => int64 layout
    }
}

// ---------- single-pass sliced scan: collect (iou>0, fixed-radius cost cands, nearest)
// ---------- then tau -> Dmax, exact top-13s; guarded fallbacks ----------
__global__ __launch_bounds__(SCN_T) void k_scan(
        const float* __restrict__ scores,
        const float4* __restrict__ pbp,
        const float* __restrict__ gt, const void* labels, const int* flag,
        u64* __restrict__ part_iou, u64* __restrict__ part_cost) {
    const int tid = threadIdx.x, lane = tid & 63, wid = tid >> 6;
    const int j = blockIdx.x, slice = blockIdx.y;
    const int base = slice * SLEN;
    const int is64 = *flag;

    const float4 gb = ((const float4*)gt)[j];
    const float gx1 = gb.x, gy1 = gb.y, gx2 = gb.z, gy2 = gb.w;
    const float areag = (gx2 - gx1) * (gy2 - gy1);
    const float gcx = (gx1 + gx2) * 0.5f, gcy = (gy1 + gy2) * 0.5f;
    const int lab = get_label(labels, j, is64);

    __shared__ int s_ni, s_nc, s_zbad, s_need2;
    __shared__ float s_dmax;
    __shared__ u64 liou[CAPI];
    __shared__ int lcost[CAPC];
    __shared__ u64 wio[NW8 * KTOP], wco[NW8 * KTOP], wnr[NW8 * KTOP];
    __shared__ u64 snear[KTOP];
    __shared__ float scost[KTOP];
    if (tid == 0) { s_ni = 0; s_nc = 0; }
    __syncthreads();

    // ---- single pass: iou>0 append + nearest-valid track + fixed-radius cost append ----
    u64 nk = ~0ull;
    for (int i = base + tid; i < base + SLEN; i += SCN_T) {
        float4 pb = pbp[2 * i];
        float4 p2 = pbp[2 * i + 1];
        float areap = (pb.z - pb.x) * (pb.w - pb.y);
        float iw = fmaxf(fminf(pb.z, gx2) - fmaxf(pb.x, gx1), 0.0f);
        float ih = fmaxf(fminf(pb.w, gy2) - fmaxf(pb.y, gy1), 0.0f);
        float inter = iw * ih;
        float iou = inter / fmaxf(areap + areag - inter, 1e-6f);   // exact
        if (iou > 0.0f) {
            int p = atomicAdd(&s_ni, 1);
            if (p < CAPI) liou[p] = (((u64)__float_as_uint(iou)) << 32) | (unsigned)i;
        }
        if (p2.w != 0.0f) {
            float dx = p2.x - gcx, dy = p2.y - gcy;
            float d2 = dx * dx + dy * dy;
            float z = p2.z;
            float dn = __fdividef(d2, z * z);
            u64 k = (((u64)__float_as_uint(dn)) << 32) | (unsigned)i;
            nk = (k < nk) ? k : nk;
            float rad = z * RFIX;
            if (d2 <= rad * rad * (1.0f + 1e-5f)) {
                int p = atomicAdd(&s_nc, 1);
                if (p < CAPC) lcost[p] = i;
            }
        }
    }
    // ---- nearest-13 merge (per-wave then 8-way) ----
    {
        u64 n1[1] = {nk};
        wave_merge_minN<1>(n1, &wnr[wid * KTOP], lane);
    }
    __syncthreads();
    if (wid == 0) {
        int p = 0;
        for (int r = 0; r < KTOP; ++r) {
            u64 cur = (lane < NW8 && p < KTOP) ? wnr[lane * KTOP + p] : ~0ull;
            u64 bm = wave_min_bc_u64(cur);
            if (cur == bm && bm != ~0ull) p++;
            if (lane == 0) snear[r] = bm;
        }
    }
    __syncthreads();
    // ---- exact costs of the 13 nearest -> tau -> Dmax (sound upper bound) ----
    const float FINF = __int_as_float(0x7f800000);
    if (tid < KTOP) {
        u64 k = snear[tid];
        float c = FINF;
        if (k != ~0ull) {
            int i = (int)(unsigned)(k & 0xffffffffull);
            float4 pb = pbp[2 * i];
            float4 p2 = pbp[2 * i + 1];
            float areap = (pb.z - pb.x) * (pb.w - pb.y);
            float iou = iou_exact(pb, areap, gx1, gy1, gx2, gy2, areag);
            c = cost_exact(p2, gcx, gcy, scores[(size_t)i * NCLS + lab], iou);
        }
        scost[tid] = c;
    }
    __syncthreads();
    if (tid == 0) {
        float tau = 0.0f; int zb = 0;
        for (int r = 0; r < KTOP; ++r) {
            if (snear[r] == ~0ull) zb = 1;
            else tau = fmaxf(tau, scost[r]);
        }
        if (!(tau < 9.0e7f)) zb = 1;   // INF-ambiguity zone -> exact fallback
        // any true top-13 member: soft <= cost <= global13th <= tau  =>  dist <= 3 + log10(tau)
        float dmax = 3.0f + __log2f(tau + 1e-5f) * (1.0f / L10) + 4e-3f;
        s_dmax = zb ? 0.0f : dmax;
        s_zbad = zb;
        s_need2 = (!zb && dmax > RFIX) ? 1 : 0;   // fixed-radius superset insufficient (rare)
    }
    __syncthreads();
    const float dmax = s_dmax;
    const int zbad = s_zbad;
    const int need2 = s_need2;

    // ---- rare second filtered pass when Dmax > RFIX ----
    if (need2) {
        if (tid == 0) s_nc = 0;
        __syncthreads();
        for (int i = base + tid; i < base + SLEN; i += SCN_T) {
            float4 p2 = pbp[2 * i + 1];
            if (p2.w != 0.0f) {
                float dx = p2.x - gcx, dy = p2.y - gcy;
                float rad = p2.z * dmax;
                if (dx * dx + dy * dy <= rad * rad * (1.0f + 1e-5f)) {
                    int p = atomicAdd(&s_nc, 1);
                    if (p < CAPC) lcost[p] = i;
                }
            }
        }
        __syncthreads();
    }
    const int ni = s_ni, nc = s_nc;
    const bool fI = (ni > CAPI);
    const bool fC = zbad || (nc > CAPC);

    // ---- iou top-13 ----
    if (!fI) {
        u64 l3[3] = {0ull, 0ull, 0ull};
        for (int k = tid; k < ni; k += SCN_T) {   // <=3 iters
            u64 key = liou[k];
            if (key > l3[0]) {
                l3[0] = key;
                if (l3[0] > l3[1]) { u64 t = l3[0]; l3[0] = l3[1]; l3[1] = t; }
                if (l3[1] > l3[2]) { u64 t = l3[1]; l3[1] = l3[2]; l3[2] = t; }
            }
        }
        wave_merge_maxN<3>(l3, &wio[wid * KTOP], lane);
    } else {
        u64 lf[KTOP];
        #pragma unroll
        for (int s = 0; s < KTOP; ++s) lf[s] = 0ull;
        for (int i = base + tid; i < base + SLEN; i += SCN_T) {
            float4 pb = pbp[2 * i];
            float areap = (pb.z - pb.x) * (pb.w - pb.y);
            float iou = iou_exact(pb, areap, gx1, gy1, gx2, gy2, areag);
            unsigned ib = __float_as_uint(iou);
            if (ib > (unsigned)(lf[0] >> 32)) {
                lf[0] = (((u64)ib) << 32) | (unsigned)i;
                #pragma unroll
                for (int s = 0; s < KTOP - 1; ++s)
                    if (lf[s] > lf[s + 1]) { u64 t = lf[s]; lf[s] = lf[s + 1]; lf[s + 1] = t; }
            }
        }
        wave_merge_maxN<KTOP>(lf, &wio[wid * KTOP], lane);
    }

    // ---- cost top-13 (superset evaluation is exact) ----
    if (!fC) {
        u64 ck[1] = {~0ull};
        if (tid < nc) {   // nc <= CAPC == SCN_T
            int i = lcost[tid];
            float4 pb = pbp[2 * i];
            float4 p2 = pbp[2 * i + 1];
            float areap = (pb.z - pb.x) * (pb.w - pb.y);
            float iou = iou_exact(pb, areap, gx1, gy1, gx2, gy2, areag);
            float ec = cost_exact(p2, gcx, gcy, scores[(size_t)i * NCLS + lab], iou);
            ck[0] = (((u64)__float_as_uint(ec)) << 32) | (unsigned)i;
        }
        wave_merge_minN<1>(ck, &wco[wid * KTOP], lane);
    } else {
        u64 lf[KTOP];
        #pragma unroll
        for (int s = 0; s < KTOP; ++s) lf[s] = ~0ull;
        for (int i = base + tid; i < base + SLEN; i += SCN_T) {
            float4 pb = pbp[2 * i];
            float4 p2 = pbp[2 * i + 1];
            float areap = (pb.z - pb.x) * (pb.w - pb.y);
            float iou = iou_exact(pb, areap, gx1, gy1, gx2, gy2, areag);
            float ec = INF_F;
            if (p2.w != 0.0f) ec = cost_exact(p2, gcx, gcy, scores[(size_t)i * NCLS + lab], iou);
            u64 k2 = (((u64)__float_as_uint(ec)) << 32) | (unsigned)i;
            if (k2 < lf[KTOP - 1]) {
                lf[KTOP - 1] = k2;
                #pragma unroll
                for (int s = KTOP - 1; s > 0; --s)
                    if (lf[s] < lf[s - 1]) { u64 t = lf[s]; lf[s] = lf[s - 1]; lf[s - 1] = t; }
            }
        }
        wave_merge_minN<KTOP>(lf, &wco[wid * KTOP], lane);
    }

    __syncthreads();
    if (wid == 0) {
        int p = 0;
        u64* dpi = part_iou + ((size_t)j * SLC + slice) * KTOP;
        for (int r = 0; r < KTOP; ++r) {
            u64 cur = (lane < NW8 && p < KTOP) ? wio[lane * KTOP + p] : 0ull;
            u64 bm = wave_max_bc_u64(cur);
            if (cur == bm && bm != 0ull) p++;
            if (lane == 0) dpi[r] = bm;
        }
    } else if (wid == 1) {
        int p = 0;
        u64* dpc = part_cost + ((size_t)j * SLC + slice) * KTOP;
        for (int r = 0; r < KTOP; ++r) {
            u64 cur = (lane < NW8 && p < KTOP) ? wco[lane * KTOP + p] : ~0ull;
            u64 bm = wave_min_bc_u64(cur);
            if (cur == bm && bm != ~0ull) p++;
            if (lane == 0) dpc[r] = bm;
        }
    }
}

// ---------- merge 4 slices per GT, compute ks, scatter ----------
__global__ __launch_bounds__(64) void k_merge(
        const u64* __restrict__ part_iou, const u64* __restrict__ part_cost,
        int* count, int* firstgt) {
    const int j = blockIdx.x;
    const int lane = threadIdx.x;
    u64 ki = (lane < SLC * KTOP) ? part_iou[(size_t)j * SLC * KTOP + lane] : 0ull;
    float tsum = 0.0f;
    for (int r = 0; r < KTOP; ++r) {
        u64 bm = wave_max_bc_u64(ki);
        if (ki == bm && bm != 0ull) ki = 0ull;
        tsum += __uint_as_float((unsigned)(bm >> 32));   // descending-order sum
    }
    int ks = (int)tsum;
    if (ks < 1) ks = 1;
    u64 kc = (lane < SLC * KTOP) ? part_cost[(size_t)j * SLC * KTOP + lane] : ~0ull;
    u64 mine = ~0ull;
    for (int r = 0; r < KTOP; ++r) {
        u64 bm = wave_min_bc_u64(kc);
        if (kc == bm && bm != ~0ull) kc = ~0ull;
        if (lane == r) mine = bm;
    }
    if (lane < KTOP && lane < ks && mine != ~0ull) {
        int idx = (int)(unsigned)(mine & 0xFFFFFFFFull);
        atomicAdd(&count[idx], 1);
        atomicMin(&firstgt[idx], j);
    }
}

// ---------- per-prior finalize; multi-matched priors -> worklist ----------
__global__ __launch_bounds__(256) void k_assign(
        const float4* __restrict__ pbp, const float* __restrict__ gt,
        const void* labels, const int* flag,
        const int* __restrict__ count, const int* __restrict__ firstgt,
        int* nmulti, int* mlist, float* __restrict__ out) {
    __shared__ float4 gbox[NGT];
    __shared__ int glab[NGT];
    __shared__ float gareas[NGT];
    int tid = threadIdx.x;
    int is64 = *flag;
    {
        float4 b = ((const float4*)gt)[tid];
        gbox[tid] = b;
        glab[tid] = get_label(labels, tid, is64);
        gareas[tid] = (b.z - b.x) * (b.w - b.y);
    }
    __syncthreads();
    int i = blockIdx.x * 256 + tid;
    if (i >= NPRI) return;
    float4 p2 = pbp[2 * i + 1];
    int v = (p2.w != 0.0f) ? 1 : 0;
    int c = count[i];
    float o0 = 0.0f, o1 = -INF_F, o2 = -1.0f;
    if (v && c == 1) {
        int j = firstgt[i];
        float4 pb = pbp[2 * i];
        float areap = (pb.z - pb.x) * (pb.w - pb.y);
        float4 g = gbox[j];
        float iw = fmaxf(fminf(pb.z, g.z) - fmaxf(pb.x, g.x), 0.0f);
        float ih = fmaxf(fminf(pb.w, g.w) - fmaxf(pb.y, g.y), 0.0f);
        float inter = iw * ih;
        float iou = inter / fmaxf(areap + gareas[j] - inter, 1e-6f);
        o0 = (float)(j + 1); o1 = iou; o2 = (float)glab[j];
    } else if (v && c > 1) {
        int pos = atomicAdd(nmulti, 1);
        mlist[pos] = i;
    }
    out[i] = o0;
    out[NPRI + i] = o1;
    out[2 * NPRI + i] = o2;
}

// ---------- one block per multi prior: block argmin over 256 GT costs ----------
__global__ __launch_bounds__(256) void k_multi(
        const float* __restrict__ scores,
        const float4* __restrict__ pbp, const float* __restrict__ gt,
        const void* labels, const int* flag,
        const int* __restrict__ nmulti, const int* __restrict__ mlist,
        float* __restrict__ out) {
    __shared__ float4 gbox[NGT];
    __shared__ int glab[NGT];
    __shared__ float gcxs[NGT], gcys[NGT], gareas[NGT];
    __shared__ u64 red4[4];
    const int tid = threadIdx.x;
    const int is64 = *flag;
    {
        float4 b = ((const float4*)gt)[tid];
        gbox[tid] = b;
        glab[tid] = get_label(labels, tid, is64);
        gcxs[tid] = (b.x + b.z) * 0.5f;
        gcys[tid] = (b.y + b.w) * 0.5f;
        gareas[tid] = (b.z - b.x) * (b.w - b.y);
    }
    __syncthreads();
    const int nm = *nmulti;
    const int j = tid;
    for (int m = blockIdx.x; m < nm; m += gridDim.x) {
        const int i = mlist[m];
        float4 pb = pbp[2 * i];
        float4 p2 = pbp[2 * i + 1];
        float areap = (pb.z - pb.x) * (pb.w - pb.y);

        float4 g = gbox[j];
        float iw = fmaxf(fminf(pb.z, g.z) - fmaxf(pb.x, g.x), 0.0f);
        float ih = fmaxf(fminf(pb.w, g.w) - fmaxf(pb.y, g.y), 0.0f);
        float inter = iw * ih;
        float iou = inter / fmaxf(areap + gareas[j] - inter, 1e-6f);
        float dx = p2.x - gcxs[j], dy = p2.y - gcys[j];
        float dist = sqrtf(dx * dx + dy * dy) / p2.z;
        float soft = exp2f((dist - 3.0f) * L10);
        float l = scores[(size_t)i * NCLS + glab[j]];
        float sig = 1.0f / (1.0f + expf(-l));
        float dd = iou - sig;
        float bce = fmaxf(l, 0.0f) - l * iou + log1pf(expf(-fabsf(l)));
        float cost = bce * (dd * dd) + (-logf(iou + EPS_F) * 3.0f) + soft;

        u64 key = (((u64)__float_as_uint(cost)) << 32) | (unsigned)j;
        u64 v = key;
        #pragma unroll
        for (int off = 32; off > 0; off >>= 1) {
            u64 o = __shfl_down(v, off, 64);
            v = (o < v) ? o : v;
        }
        if ((tid & 63) == 0) red4[tid >> 6] = v;
        __syncthreads();
        u64 best = red4[0];
        #pragma unroll
        for (int q = 1; q < 4; ++q) best = (red4[q] < best) ? red4[q] : best;
        if (key == best) {
            out[i] = (float)(j + 1);
            out[NPRI + i] = iou;
            out[2 * NPRI + i] = (float)glab[j];
        }
        __syncthreads();
    }
}

extern "C" void kernel_launch(void* const* d_in, const int* in_sizes, int n_in,
                              void* d_out, int out_size, void* d_ws, size_t ws_size,
                              hipStream_t stream) {
    const float* scores = (const float*)d_in[0];
    const float* priors = (const float*)d_in[1];
    const float* pboxes = (const float*)d_in[2];
    const float* gt     = (const float*)d_in[3];
    const void*  labels = d_in[4];
    float* out = (float*)d_out;

    char* ws = (char*)d_ws;
    size_t off = 0;
    auto alloc = [&](size_t bytes) { size_t o = off; off = (off + bytes + 255) & ~(size_t)255; return o; };
    int*    flag     = (int*)(ws + alloc(4));
    int*    nmulti   = (int*)(ws + alloc(4));
    int*    count    = (int*)(ws + alloc((size_t)NPRI * 4));
    int*    firstgt  = (int*)(ws + alloc((size_t)NPRI * 4));
    int*    mlist    = (int*)(ws + alloc((size_t)NPRI * 4));
    u64*    part_iou = (u64*)(ws + alloc((size_t)NGT * SLC * KTOP * 8));
    u64*    part_cost= (u64*)(ws + alloc((size_t)NGT * SLC * KTOP * 8));
    float4* pbp      = (float4*)(ws + alloc((size_t)NPRI * 32));
    (void)ws_size;

    hipLaunchKernelGGL(k_prep, dim3(PREP_BLKS), dim3(256), 0, stream,
                       priors, gt, labels, pboxes, pbp, count, firstgt, flag, nmulti);
    hipLaunchKernelGGL(k_scan, dim3(NGT, SLC), dim3(SCN_T), 0, stream,
                       scores, pbp, gt, labels, flag, part_iou, part_cost);
    hipLaunchKernelGGL(k_merge, dim3(NGT), dim3(64), 0, stream,
                       part_iou, part_cost, count, firstgt);
    hipLaunchKernelGGL(k_assign, dim3((NPRI + 255) / 256), dim3(256), 0, stream,
                       pbp, gt, labels, flag, count, firstgt, nmulti, mlist, out);
    hipLaunchKernelGGL(k_multi, dim3(256), dim3(256), 0, stream,
                       scores, pbp, gt, labels, flag, nmulti, mlist, out);
}

// Round 13
// 164.175 us; speedup vs baseline: 2.2469x; 1.1726x over previous
//
#include <hip/hip_runtime.h>
#include <cstdint>

#define NPRI 33600
#define NGT  256
#define NCLS 80
#define KTOP 13
#define INF_F 1.0e8f
#define EPS_F 1e-7f
#define L10 3.3219280948873623f
#define SLC  4
#define SLEN (NPRI / SLC)          // 8400
#define SCN_T 512
#define NW8 (SCN_T / 64)
#define CAPI 1536                  // per-slice iou values (3/thread)
#define CAPC 512                   // per-slice cost candidates (1/thread)
#define RFIX 5.5f                  // fixed collect radius (strides); Dmax typically ~4.7
#define PREP_BLKS ((NPRI + 255) / 256)
#define NEGINF __int_as_float(0xff800000)

typedef unsigned long long u64;

__device__ __forceinline__ int get_label(const void* p, int j, int is64) {
    if (is64) return (int)((const long long*)p)[j];
    return ((const int*)p)[j];
}

// ---------- wave helpers (reduce + broadcast) ----------
__device__ __forceinline__ float wave_max_bc_f32(float v) {
    #pragma unroll
    for (int off = 32; off > 0; off >>= 1) v = fmaxf(v, __shfl_down(v, off, 64));
    return __int_as_float(__builtin_amdgcn_readfirstlane(__float_as_int(v)));
}
__device__ __forceinline__ u64 wave_min_bc_u64(u64 v) {
    #pragma unroll
    for (int off = 32; off > 0; off >>= 1) { u64 o = __shfl_down(v, off, 64); v = (o < v) ? o : v; }
    unsigned lo = (unsigned)__builtin_amdgcn_readfirstlane((int)(v & 0xffffffffull));
    unsigned hi = (unsigned)__builtin_amdgcn_readfirstlane((int)(v >> 32));
    return (((u64)hi) << 32) | lo;
}
// f32 multiset per-wave top-13: ballot single-lane elimination preserves duplicates
template<int NSL>
__device__ __forceinline__ void wave_merge_max13_f32(float (&l)[NSL], float* dst, int lane) {
    int p = 0;
    for (int r = 0; r < KTOP; ++r) {
        float cur = NEGINF;
        #pragma unroll
        for (int s = 0; s < NSL; ++s) if (s == p) cur = l[NSL - 1 - s];
        float bm = wave_max_bc_f32(cur);
        u64 m = __ballot(cur == bm && bm != NEGINF);
        int first = __ffsll(m) - 1;
        if (lane == first) p++;
        if (lane == 0) dst[r] = bm;
    }
}
// u64 per-wave top-13 min (keys idx-distinct -> single match per round)
template<int NSL>
__device__ __forceinline__ void wave_merge_minN(u64 (&l)[NSL], u64* dst, int lane) {
    int p = 0;
    for (int r = 0; r < KTOP; ++r) {
        u64 cur = ~0ull;
        #pragma unroll
        for (int s = 0; s < NSL; ++s) if (s == p) cur = l[s];
        u64 bm = wave_min_bc_u64(cur);
        if (cur == bm && bm != ~0ull) p++;
        if (lane == 0) dst[r] = bm;
    }
}

// ---------- exact formulas (verbatim round-2: bit-identical selection) ----------
__device__ __forceinline__ float iou_exact(float4 pb, float areap, float gx1, float gy1,
                                           float gx2, float gy2, float areag) {
    float iw = fmaxf(fminf(pb.z, gx2) - fmaxf(pb.x, gx1), 0.0f);
    float ih = fmaxf(fminf(pb.w, gy2) - fmaxf(pb.y, gy1), 0.0f);
    float inter = iw * ih;
    return inter / fmaxf(areap + areag - inter, 1e-6f);
}
__device__ __forceinline__ float cost_exact(float4 p2, float gcx, float gcy,
                                            float l, float iou) {
    float dx = p2.x - gcx, dy = p2.y - gcy;
    float dist = sqrtf(dx * dx + dy * dy) / p2.z;
    float soft = exp2f((dist - 3.0f) * L10);
    float sig = 1.0f / (1.0f + expf(-l));
    float dd = iou - sig;
    float bce = fmaxf(l, 0.0f) - l * iou + log1pf(expf(-fabsf(l)));
    float iouc = -logf(iou + EPS_F) * 3.0f;
    return bce * (dd * dd) + iouc + soft;
}

// ---------- prep: detect int64 + init + valid mask + packed array ----------
__global__ __launch_bounds__(256) void k_prep(
        const float* __restrict__ priors, const float* __restrict__ gt,
        const void* labels, const float* __restrict__ pboxes,
        float4* __restrict__ pbp,
        int* count, int* firstgt, int* flag, int* nmulti) {
    __shared__ float4 gbox[NGT];
    __shared__ int    gpad[NGT];
    __shared__ int    bad;
    const int tid = threadIdx.x;
    const int b = blockIdx.x;
    if (b == 0 && tid == 0) { bad = 0; *nmulti = 0; }
    {
        float4 bx = ((const float4*)gt)[tid];
        gbox[tid] = bx;
        gpad[tid] = ((bx.x + bx.y + bx.z + bx.w) > 0.0f) ? 1 : 0;
    }
    __syncthreads();
    if (b == 0 && tid < 128) {
        long long v = ((const long long*)labels)[tid];   // first 1024B: in-bounds either layout
        if (v < 0 || v >= NCLS) atomicOr(&bad, 1);
    }
    int i = b * 256 + tid;
    if (i < NPRI) {
        count[i] = 0; firstgt[i] = NGT;
        float4 pr = ((const float4*)priors)[i];
        float px = pr.x, py = pr.y;
        int v = 0;
        for (int j = 0; j < NGT; ++j) {
            float4 bx = gbox[j];
            float m = fminf(fminf(px - bx.x, py - bx.y), fminf(bx.z - px, bx.w - py));
            if (m > 0.0f && gpad[j]) { v = 1; break; }
        }
        pbp[2 * i]     = ((const float4*)pboxes)[i];
        pbp[2 * i + 1] = make_float4(px, py, pr.z, v ? 1.0f : 0.0f);
    }
    if (b == 0) {
        __syncthreads();
        if (tid == 0) *flag = bad ? 0 : 1;   // 1 => int64 layout
    }
}

// ---------- single-pass sliced scan; tau from candidates' own costs; validated ----------
__global__ __launch_bounds__(SCN_T) void k_scan(
        const float* __restrict__ scores,
        const float4* __restrict__ pbp,
        const float* __restrict__ gt, const void* labels, const int* flag,
        float* __restrict__ part_iou, u64* __restrict__ part_cost) {
    const int tid = threadIdx.x, lane = tid & 63, wid = tid >> 6;
    const int j = blockIdx.x, slice = blockIdx.y;
    const int base = slice * SLEN;
    const int is64 = *flag;

    const float4 gb = ((const float4*)gt)[j];
    const float gx1 = gb.x, gy1 = gb.y, gx2 = gb.z, gy2 = gb.w;
    const float areag = (gx2 - gx1) * (gy2 - gy1);
    const float gcx = (gx1 + gx2) * 0.5f, gcy = (gy1 + gy2) * 0.5f;
    const int lab = get_label(labels, j, is64);

    __shared__ int s_ni, s_nc, s_mode;
    __shared__ float s_dmax;
    __shared__ float liou[CAPI];
    __shared__ int lcost[CAPC];
    __shared__ float wiof[NW8 * KTOP];
    __shared__ u64 wco[NW8 * KTOP];
    __shared__ u64 csel[KTOP];
    __shared__ u64 s_tauk;
    if (tid == 0) { s_ni = 0; s_nc = 0; }
    __syncthreads();

    // ---- single pass: iou>0 value append + fixed-radius candidate append ----
    for (int i = base + tid; i < base + SLEN; i += SCN_T) {
        float4 pb = pbp[2 * i];
        float4 p2 = pbp[2 * i + 1];
        float areap = (pb.z - pb.x) * (pb.w - pb.y);
        float iw = fmaxf(fminf(pb.z, gx2) - fmaxf(pb.x, gx1), 0.0f);
        float ih = fmaxf(fminf(pb.w, gy2) - fmaxf(pb.y, gy1), 0.0f);
        float inter = iw * ih;
        float iou = inter / fmaxf(areap + areag - inter, 1e-6f);   // exact
        if (iou > 0.0f) {
            int p = atomicAdd(&s_ni, 1);
            if (p < CAPI) liou[p] = iou;
        }
        if (p2.w != 0.0f) {
            float dx = p2.x - gcx, dy = p2.y - gcy;
            float rad = p2.z * RFIX;
            if (dx * dx + dy * dy <= rad * rad * (1.0f + 1e-5f)) {
                int p = atomicAdd(&s_nc, 1);
                if (p < CAPC) lcost[p] = i;
            }
        }
    }
    __syncthreads();
    const int ni = s_ni, nc = s_nc;
    const int ncc = (nc < CAPC) ? nc : CAPC;
    const bool fI = (ni > CAPI);

    // ---- candidate preload (issue gathers early for ILP with iou scan) ----
    const bool part = (tid < ncc);
    int ci = 0; float4 cpb, cp2; float lv = 0.0f;
    if (part) {
        ci = lcost[tid];
        cpb = pbp[2 * ci];
        cp2 = pbp[2 * ci + 1];
        lv = scores[(size_t)ci * NCLS + lab];
    }

    // ---- iou top-13 values (multiset) ----
    if (!fI) {
        float l3[3] = {NEGINF, NEGINF, NEGINF};
        for (int k = tid; k < ni; k += SCN_T) {   // <=3 iters
            float v = liou[k];
            if (v > l3[0]) {
                l3[0] = v;
                if (l3[0] > l3[1]) { float t = l3[0]; l3[0] = l3[1]; l3[1] = t; }
                if (l3[1] > l3[2]) { float t = l3[1]; l3[1] = l3[2]; l3[2] = t; }
            }
        }
        wave_merge_max13_f32<3>(l3, &wiof[wid * KTOP], lane);
    } else {
        float lf[KTOP];
        #pragma unroll
        for (int s = 0; s < KTOP; ++s) lf[s] = NEGINF;
        for (int i = base + tid; i < base + SLEN; i += SCN_T) {
            float4 pb = pbp[2 * i];
            float areap = (pb.z - pb.x) * (pb.w - pb.y);
            float iou = iou_exact(pb, areap, gx1, gy1, gx2, gy2, areag);
            if (iou > lf[0]) {
                lf[0] = iou;
                #pragma unroll
                for (int s = 0; s < KTOP - 1; ++s)
                    if (lf[s] > lf[s + 1]) { float t = lf[s]; lf[s] = lf[s + 1]; lf[s + 1] = t; }
            }
        }
        wave_merge_max13_f32<KTOP>(lf, &wiof[wid * KTOP], lane);
    }

    // ---- exact cost keys for candidates ----
    {
        u64 ck[1] = {~0ull};
        if (part) {
            float areap = (cpb.z - cpb.x) * (cpb.w - cpb.y);
            float iou = iou_exact(cpb, areap, gx1, gy1, gx2, gy2, areag);
            float ec = cost_exact(cp2, gcx, gcy, lv, iou);
            ck[0] = (((u64)__float_as_uint(ec)) << 32) | (unsigned)ci;
        }
        wave_merge_minN<1>(ck, &wco[wid * KTOP], lane);
    }
    __syncthreads();

    if (wid == 0) {          // iou 8-way final -> global f32 values (no revalidation needed)
        float* dpi = part_iou + ((size_t)j * SLC + slice) * KTOP;
        int p = 0;
        for (int r = 0; r < KTOP; ++r) {
            float cur = (lane < NW8 && p < KTOP) ? wiof[lane * KTOP + p] : NEGINF;
            float bm = wave_max_bc_f32(cur);
            u64 m = __ballot(cur == bm && bm != NEGINF);
            int first = __ffsll(m) - 1;
            if (lane == first) p++;
            if (lane == 0) dpi[r] = bm;
        }
    } else if (wid == 1) {   // cost 8-way final -> csel + tau'
        int p = 0;
        for (int r = 0; r < KTOP; ++r) {
            u64 cur = (lane < NW8 && p < KTOP) ? wco[lane * KTOP + p] : ~0ull;
            u64 bm = wave_min_bc_u64(cur);
            if (cur == bm && bm != ~0ull) p++;
            if (lane == 0) { csel[r] = bm; if (r == KTOP - 1) s_tauk = bm; }
        }
    }
    __syncthreads();
    // ---- validation: tau' -> Dmax'; mode 0=OK 1=REDO 2=FULL ----
    if (tid == 0) {
        u64 tk = s_tauk;
        int mode; float dmax = 0.0f;
        if (tk == ~0ull) mode = 2;               // <13 candidates in RFIX ball
        else {
            float tau = __uint_as_float((unsigned)(tk >> 32));
            if (!(tau < 9.0e7f)) mode = 2;       // INF-ambiguity zone
            else {
                dmax = 3.0f + __log2f(tau + 1e-5f) * (1.0f / L10) + 4e-3f;
                mode = (dmax > RFIX || nc > CAPC) ? 1 : 0;
            }
        }
        s_mode = mode; s_dmax = dmax;
    }
    __syncthreads();
    int mode = s_mode;

    if (mode == 1) {   // re-collect at the sound radius Dmax' (rare)
        const float dmax = s_dmax;
        if (tid == 0) s_nc = 0;
        __syncthreads();
        for (int i = base + tid; i < base + SLEN; i += SCN_T) {
            float4 p2 = pbp[2 * i + 1];
            if (p2.w != 0.0f) {
                float dx = p2.x - gcx, dy = p2.y - gcy;
                float rad = p2.z * dmax;
                if (dx * dx + dy * dy <= rad * rad * (1.0f + 1e-5f)) {
                    int p = atomicAdd(&s_nc, 1);
                    if (p < CAPC) lcost[p] = i;
                }
            }
        }
        __syncthreads();
        int nc2 = s_nc;
        if (nc2 > CAPC) {
            mode = 2;
        } else {
            u64 ck[1] = {~0ull};
            if (tid < nc2) {
                int i = lcost[tid];
                float4 pb = pbp[2 * i];
                float4 p2 = pbp[2 * i + 1];
                float areap = (pb.z - pb.x) * (pb.w - pb.y);
                float iou = iou_exact(pb, areap, gx1, gy1, gx2, gy2, areag);
                float ec = cost_exact(p2, gcx, gcy, scores[(size_t)i * NCLS + lab], iou);
                ck[0] = (((u64)__float_as_uint(ec)) << 32) | (unsigned)i;
            }
            wave_merge_minN<1>(ck, &wco[wid * KTOP], lane);
            __syncthreads();
            if (wid == 0) {
                int p = 0;
                for (int r = 0; r < KTOP; ++r) {
                    u64 cur = (lane < NW8 && p < KTOP) ? wco[lane * KTOP + p] : ~0ull;
                    u64 bm = wave_min_bc_u64(cur);
                    if (cur == bm && bm != ~0ull) p++;
                    if (lane == 0) csel[r] = bm;
                }
            }
            __syncthreads();
        }
    }
    if (mode == 2) {   // exact full slice scan (round-2 semantics; correctness net)
        u64 lf[KTOP];
        #pragma unroll
        for (int s = 0; s < KTOP; ++s) lf[s] = ~0ull;
        for (int i = base + tid; i < base + SLEN; i += SCN_T) {
            float4 pb = pbp[2 * i];
            float4 p2 = pbp[2 * i + 1];
            float areap = (pb.z - pb.x) * (pb.w - pb.y);
            float iou = iou_exact(pb, areap, gx1, gy1, gx2, gy2, areag);
            float ec = INF_F;
            if (p2.w != 0.0f) ec = cost_exact(p2, gcx, gcy, scores[(size_t)i * NCLS + lab], iou);
            u64 k2 = (((u64)__float_as_uint(ec)) << 32) | (unsigned)i;
            if (k2 < lf[KTOP - 1]) {
                lf[KTOP - 1] = k2;
                #pragma unroll
                for (int s = KTOP - 1; s > 0; --s)
                    if (lf[s] < lf[s - 1]) { u64 t = lf[s]; lf[s] = lf[s - 1]; lf[s - 1] = t; }
            }
        }
        wave_merge_minN<KTOP>(lf, &wco[wid * KTOP], lane);
        __syncthreads();
        if (wid == 0) {
            int p = 0;
            for (int r = 0; r < KTOP; ++r) {
                u64 cur = (lane < NW8 && p < KTOP) ? wco[lane * KTOP + p] : ~0ull;
                u64 bm = wave_min_bc_u64(cur);
                if (cur == bm && bm != ~0ull) p++;
                if (lane == 0) csel[r] = bm;
            }
        }
        __syncthreads();
    }
    if (tid < KTOP) {
        u64* dpc = part_cost + ((size_t)j * SLC + slice) * KTOP;
        dpc[tid] = csel[tid];
    }
}

// ---------- merge 4 slices per GT, compute ks, scatter ----------
__global__ __launch_bounds__(64) void k_merge(
        const float* __restrict__ part_iou, const u64* __restrict__ part_cost,
        int* count, int* firstgt) {
    const int j = blockIdx.x;
    const int lane = threadIdx.x;
    float vi = (lane < SLC * KTOP) ? part_iou[(size_t)j * SLC * KTOP + lane] : NEGINF;
    float tsum = 0.0f;
    for (int r = 0; r < KTOP; ++r) {
        float bm = wave_max_bc_f32(vi);
        u64 m = __ballot(vi == bm && bm != NEGINF);
        int first = __ffsll(m) - 1;
        if (lane == first) vi = NEGINF;
        tsum += (bm == NEGINF) ? 0.0f : bm;   // descending-order sum (missing = 0, as ref)
    }
    int ks = (int)tsum;
    if (ks < 1) ks = 1;
    u64 kc = (lane < SLC * KTOP) ? part_cost[(size_t)j * SLC * KTOP + lane] : ~0ull;
    u64 mine = ~0ull;
    for (int r = 0; r < KTOP; ++r) {
        u64 bm = wave_min_bc_u64(kc);
        if (kc == bm && bm != ~0ull) kc = ~0ull;
        if (lane == r) mine = bm;
    }
    if (lane < KTOP && lane < ks && mine != ~0ull) {
        int idx = (int)(unsigned)(mine & 0xFFFFFFFFull);
        atomicAdd(&count[idx], 1);
        atomicMin(&firstgt[idx], j);
    }
}

// ---------- per-prior finalize; multi-matched priors -> worklist ----------
__global__ __launch_bounds__(256) void k_assign(
        const float4* __restrict__ pbp, const float* __restrict__ gt,
        const void* labels, const int* flag,
        const int* __restrict__ count, const int* __restrict__ firstgt,
        int* nmulti, int* mlist, float* __restrict__ out) {
    __shared__ float4 gbox[NGT];
    __shared__ int glab[NGT];
    __shared__ float gareas[NGT];
    int tid = threadIdx.x;
    int is64 = *flag;
    {
        float4 b = ((const float4*)gt)[tid];
        gbox[tid] = b;
        glab[tid] = get_label(labels, tid, is64);
        gareas[tid] = (b.z - b.x) * (b.w - b.y);
    }
    __syncthreads();
    int i = blockIdx.x * 256 + tid;
    if (i >= NPRI) return;
    float4 p2 = pbp[2 * i + 1];
    int v = (p2.w != 0.0f) ? 1 : 0;
    int c = count[i];
    float o0 = 0.0f, o1 = -INF_F, o2 = -1.0f;
    if (v && c == 1) {
        int j = firstgt[i];
        float4 pb = pbp[2 * i];
        float areap = (pb.z - pb.x) * (pb.w - pb.y);
        float4 g = gbox[j];
        float iw = fmaxf(fminf(pb.z, g.z) - fmaxf(pb.x, g.x), 0.0f);
        float ih = fmaxf(fminf(pb.w, g.w) - fmaxf(pb.y, g.y), 0.0f);
        float inter = iw * ih;
        float iou = inter / fmaxf(areap + gareas[j] - inter, 1e-6f);
        o0 = (float)(j + 1); o1 = iou; o2 = (float)glab[j];
    } else if (v && c > 1) {
        int pos = atomicAdd(nmulti, 1);
        mlist[pos] = i;
    }
    out[i] = o0;
    out[NPRI + i] = o1;
    out[2 * NPRI + i] = o2;
}

// ---------- one block per multi prior: block argmin over 256 GT costs ----------
__global__ __launch_bounds__(256) void k_multi(
        const float* __restrict__ scores,
        const float4* __restrict__ pbp, const float* __restrict__ gt,
        const void* labels, const int* flag,
        const int* __restrict__ nmulti, const int* __restrict__ mlist,
        float* __restrict__ out) {
    __shared__ float4 gbox[NGT];
    __shared__ int glab[NGT];
    __shared__ float gcxs[NGT], gcys[NGT], gareas[NGT];
    __shared__ u64 red4[4];
    const int tid = threadIdx.x;
    const int is64 = *flag;
    {
        float4 b = ((const float4*)gt)[tid];
        gbox[tid] = b;
        glab[tid] = get_label(labels, tid, is64);
        gcxs[tid] = (b.x + b.z) * 0.5f;
        gcys[tid] = (b.y + b.w) * 0.5f;
        gareas[tid] = (b.z - b.x) * (b.w - b.y);
    }
    __syncthreads();
    const int nm = *nmulti;
    const int j = tid;
    for (int m = blockIdx.x; m < nm; m += gridDim.x) {
        const int i = mlist[m];
        float4 pb = pbp[2 * i];
        float4 p2 = pbp[2 * i + 1];
        float areap = (pb.z - pb.x) * (pb.w - pb.y);

        float4 g = gbox[j];
        float iw = fmaxf(fminf(pb.z, g.z) - fmaxf(pb.x, g.x), 0.0f);
        float ih = fmaxf(fminf(pb.w, g.w) - fmaxf(pb.y, g.y), 0.0f);
        float inter = iw * ih;
        float iou = inter / fmaxf(areap + gareas[j] - inter, 1e-6f);
        float dx = p2.x - gcxs[j], dy = p2.y - gcys[j];
        float dist = sqrtf(dx * dx + dy * dy) / p2.z;
        float soft = exp2f((dist - 3.0f) * L10);
        float l = scores[(size_t)i * NCLS + glab[j]];
        float sig = 1.0f / (1.0f + expf(-l));
        float dd = iou - sig;
        float bce = fmaxf(l, 0.0f) - l * iou + log1pf(expf(-fabsf(l)));
        float cost = bce * (dd * dd) + (-logf(iou + EPS_F) * 3.0f) + soft;

        u64 key = (((u64)__float_as_uint(cost)) << 32) | (unsigned)j;
        u64 v = key;
        #pragma unroll
        for (int off = 32; off > 0; off >>= 1) {
            u64 o = __shfl_down(v, off, 64);
            v = (o < v) ? o : v;
        }
        if ((tid & 63) == 0) red4[tid >> 6] = v;
        __syncthreads();
        u64 best = red4[0];
        #pragma unroll
        for (int q = 1; q < 4; ++q) best = (red4[q] < best) ? red4[q] : best;
        if (key == best) {
            out[i] = (float)(j + 1);
            out[NPRI + i] = iou;
            out[2 * NPRI + i] = (float)glab[j];
        }
        __syncthreads();
    }
}

extern "C" void kernel_launch(void* const* d_in, const int* in_sizes, int n_in,
                              void* d_out, int out_size, void* d_ws, size_t ws_size,
                              hipStream_t stream) {
    const float* scores = (const float*)d_in[0];
    const float* priors = (const float*)d_in[1];
    const float* pboxes = (const float*)d_in[2];
    const float* gt     = (const float*)d_in[3];
    const void*  labels = d_in[4];
    float* out = (float*)d_out;

    char* ws = (char*)d_ws;
    size_t off = 0;
    auto alloc = [&](size_t bytes) { size_t o = off; off = (off + bytes + 255) & ~(size_t)255; return o; };
    int*    flag     = (int*)(ws + alloc(4));
    int*    nmulti   = (int*)(ws + alloc(4));
    int*    count    = (int*)(ws + alloc((size_t)NPRI * 4));
    int*    firstgt  = (int*)(ws + alloc((size_t)NPRI * 4));
    int*    mlist    = (int*)(ws + alloc((size_t)NPRI * 4));
    float*  part_iou = (float*)(ws + alloc((size_t)NGT * SLC * KTOP * 4));
    u64*    part_cost= (u64*)(ws + alloc((size_t)NGT * SLC * KTOP * 8));
    float4* pbp      = (float4*)(ws + alloc((size_t)NPRI * 32));
    (void)ws_size;

    hipLaunchKernelGGL(k_prep, dim3(PREP_BLKS), dim3(256), 0, stream,
                       priors, gt, labels, pboxes, pbp, count, firstgt, flag, nmulti);
    hipLaunchKernelGGL(k_scan, dim3(NGT, SLC), dim3(SCN_T), 0, stream,
                       scores, pbp, gt, labels, flag, part_iou, part_cost);
    hipLaunchKernelGGL(k_merge, dim3(NGT), dim3(64), 0, stream,
                       part_iou, part_cost, count, firstgt);
    hipLaunchKernelGGL(k_assign, dim3((NPRI + 255) / 256), dim3(256), 0, stream,
                       pbp, gt, labels, flag, count, firstgt, nmulti, mlist, out);
    hipLaunchKernelGGL(k_multi, dim3(256), dim3(256), 0, stream,
                       scores, pbp, gt, labels, flag, nmulti, mlist, out);
}

// Round 15
// 160.151 us; speedup vs baseline: 2.3034x; 1.0251x over previous
//
#include <hip/hip_runtime.h>
#include <cstdint>

#define NPRI 33600
#define NGT  256
#define NCLS 80
#define KTOP 13
#define INF_F 1.0e8f
#define EPS_F 1e-7f
#define L10 3.3219280948873623f
#define SLC  4
#define SLEN (NPRI / SLC)          // 8400
#define SCN_T 512
#define NW8 (SCN_T / 64)
#define NIT  ((SLEN + SCN_T - 1) / SCN_T)   // 17, uniform padded trip count
#define CAPI 1536                  // per-slice iou values
#define CAPC 512                   // per-slice cost candidates
#define RFIX 5.5f                  // fixed collect radius (strides); Dmax typically ~4.7
#define PREP_BLKS ((NPRI + 255) / 256)
#define NEGINF __int_as_float(0xff800000)

typedef unsigned long long u64;

__device__ __forceinline__ int get_label(const void* p, int j, int is64) {
    if (is64) return (int)((const long long*)p)[j];
    return ((const int*)p)[j];
}

// ---------- wave helpers (reduce + broadcast) ----------
__device__ __forceinline__ float wave_max_bc_f32(float v) {
    #pragma unroll
    for (int off = 32; off > 0; off >>= 1) v = fmaxf(v, __shfl_down(v, off, 64));
    return __int_as_float(__builtin_amdgcn_readfirstlane(__float_as_int(v)));
}
__device__ __forceinline__ u64 wave_min_bc_u64(u64 v) {
    #pragma unroll
    for (int off = 32; off > 0; off >>= 1) { u64 o = __shfl_down(v, off, 64); v = (o < v) ? o : v; }
    unsigned lo = (unsigned)__builtin_amdgcn_readfirstlane((int)(v & 0xffffffffull));
    unsigned hi = (unsigned)__builtin_amdgcn_readfirstlane((int)(v >> 32));
    return (((u64)hi) << 32) | lo;
}
// f32 multiset per-wave top-13: ballot single-lane elimination preserves duplicates
template<int NSL>
__device__ __forceinline__ void wave_merge_max13_f32(float (&l)[NSL], float* dst, int lane) {
    int p = 0;
    for (int r = 0; r < KTOP; ++r) {
        float cur = NEGINF;
        #pragma unroll
        for (int s = 0; s < NSL; ++s) if (s == p) cur = l[NSL - 1 - s];
        float bm = wave_max_bc_f32(cur);
        u64 m = __ballot(cur == bm && bm != NEGINF);
        int first = __ffsll(m) - 1;
        if (lane == first) p++;
        if (lane == 0) dst[r] = bm;
    }
}
// u64 per-wave top-13 min (keys idx-distinct -> single match per round)
template<int NSL>
__device__ __forceinline__ void wave_merge_minN(u64 (&l)[NSL], u64* dst, int lane) {
    int p = 0;
    for (int r = 0; r < KTOP; ++r) {
        u64 cur = ~0ull;
        #pragma unroll
        for (int s = 0; s < NSL; ++s) if (s == p) cur = l[s];
        u64 bm = wave_min_bc_u64(cur);
        if (cur == bm && bm != ~0ull) p++;
        if (lane == 0) dst[r] = bm;
    }
}

// ---------- exact formulas (verbatim round-2: bit-identical selection) ----------
__device__ __forceinline__ float iou_exact(float4 pb, float areap, float gx1, float gy1,
                                           float gx2, float gy2, float areag) {
    float iw = fmaxf(fminf(pb.z, gx2) - fmaxf(pb.x, gx1), 0.0f);
    float ih = fmaxf(fminf(pb.w, gy2) - fmaxf(pb.y, gy1), 0.0f);
    float inter = iw * ih;
    return inter / fmaxf(areap + areag - inter, 1e-6f);
}
__device__ __forceinline__ float cost_exact(float4 p2, float gcx, float gcy,
                                            float l, float iou) {
    float dx = p2.x - gcx, dy = p2.y - gcy;
    float dist = sqrtf(dx * dx + dy * dy) / p2.z;
    float soft = exp2f((dist - 3.0f) * L10);
    float sig = 1.0f / (1.0f + expf(-l));
    float dd = iou - sig;
    float bce = fmaxf(l, 0.0f) - l * iou + log1pf(expf(-fabsf(l)));
    float iouc = -logf(iou + EPS_F) * 3.0f;
    return bce * (dd * dd) + iouc + soft;
}

// ---------- prep: detect int64 + init + valid mask + packed array ----------
__global__ __launch_bounds__(256) void k_prep(
        const float* __restrict__ priors, const float* __restrict__ gt,
        const void* labels, const float* __restrict__ pboxes,
        float4* __restrict__ pbp,
        int* count, int* firstgt, int* flag, int* nmulti) {
    __shared__ float4 gbox[NGT];
    __shared__ int    gpad[NGT];
    __shared__ int    bad;
    const int tid = threadIdx.x;
    const int b = blockIdx.x;
    if (b == 0 && tid == 0) { bad = 0; *nmulti = 0; }
    {
        float4 bx = ((const float4*)gt)[tid];
        gbox[tid] = bx;
        gpad[tid] = ((bx.x + bx.y + bx.z + bx.w) > 0.0f) ? 1 : 0;
    }
    __syncthreads();
    if (b == 0 && tid < 128) {
        long long v = ((const long long*)labels)[tid];   // first 1024B: in-bounds either layout
        if (v < 0 || v >= NCLS) atomicOr(&bad, 1);
    }
    int i = b * 256 + tid;
    if (i < NPRI) {
        count[i] = 0; firstgt[i] = NGT;
        float4 pr = ((const float4*)priors)[i];
        float px = pr.x, py = pr.y;
        int v = 0;
        for (int j = 0; j < NGT; ++j) {
            float4 bx = gbox[j];
            float m = fminf(fminf(px - bx.x, py - bx.y), fminf(bx.z - px, bx.w - py));
            if (m > 0.0f && gpad[j]) { v = 1; break; }
        }
        pbp[2 * i]     = ((const float4*)pboxes)[i];
        pbp[2 * i + 1] = make_float4(px, py, pr.z, v ? 1.0f : 0.0f);
    }
    if (b == 0) {
        __syncthreads();
        if (tid == 0) *flag = bad ? 0 : 1;   // 1 => int64 layout
    }
}

// ---------- single-pass sliced scan; single-wave merges; wave-aggregated appends ----------
__global__ __launch_bounds__(SCN_T) void k_scan(
        const float* __restrict__ scores,
        const float4* __restrict__ pbp,
        const float* __restrict__ gt, const void* labels, const int* flag,
        float* __restrict__ part_iou, u64* __restrict__ part_cost) {
    const int tid = threadIdx.x, lane = tid & 63, wid = tid >> 6;
    const int j = blockIdx.x, slice = blockIdx.y;
    const int base = slice * SLEN;
    const int is64 = *flag;

    const float4 gb = ((const float4*)gt)[j];
    const float gx1 = gb.x, gy1 = gb.y, gx2 = gb.z, gy2 = gb.w;
    const float areag = (gx2 - gx1) * (gy2 - gy1);
    const float gcx = (gx1 + gx2) * 0.5f, gcy = (gy1 + gy2) * 0.5f;
    const int lab = get_label(labels, j, is64);

    __shared__ int s_ni, s_nc, s_mode;
    __shared__ float s_dmax;
    __shared__ float liou[CAPI];
    __shared__ int lcost[CAPC];
    __shared__ float wiof[NW8 * KTOP];   // fI fallback only
    __shared__ u64 wco[NW8 * KTOP];      // mode-2 fallback only
    __shared__ u64 csel[KTOP];
    if (tid == 0) { s_ni = 0; s_nc = 0; }
    __syncthreads();

    // ---- single pass, uniform 17-iter trip (convergent ballots), wave-agg appends ----
    for (int it = 0; it < NIT; ++it) {
        int i = base + tid + it * SCN_T;
        bool inb = (i < base + SLEN);
        float iou = 0.0f;
        bool pc = false;
        if (inb) {
            float4 pb = pbp[2 * i];
            float4 p2 = pbp[2 * i + 1];
            float areap = (pb.z - pb.x) * (pb.w - pb.y);
            float iw = fmaxf(fminf(pb.z, gx2) - fmaxf(pb.x, gx1), 0.0f);
            float ih = fmaxf(fminf(pb.w, gy2) - fmaxf(pb.y, gy1), 0.0f);
            float inter = iw * ih;
            iou = inter / fmaxf(areap + areag - inter, 1e-6f);   // exact
            if (p2.w != 0.0f) {
                float dx = p2.x - gcx, dy = p2.y - gcy;
                float rad = p2.z * RFIX;
                pc = (dx * dx + dy * dy <= rad * rad * (1.0f + 1e-5f));
            }
        }
        bool pi = inb && (iou > 0.0f);
        u64 mi = __ballot(pi);
        if (mi) {
            int lead = __ffsll(mi) - 1;
            int cnt = __popcll(mi);
            int bs = 0;
            if (lane == lead) bs = atomicAdd(&s_ni, cnt);
            bs = __shfl(bs, lead, 64);
            if (pi) {
                int p = bs + __popcll(mi & ((1ull << lane) - 1ull));
                if (p < CAPI) liou[p] = iou;
            }
        }
        u64 mc = __ballot(pc);
        if (mc) {
            int lead = __ffsll(mc) - 1;
            int cnt = __popcll(mc);
            int bs = 0;
            if (lane == lead) bs = atomicAdd(&s_nc, cnt);
            bs = __shfl(bs, lead, 64);
            if (pc) {
                int p = bs + __popcll(mc & ((1ull << lane) - 1ull));
                if (p < CAPC) lcost[p] = i;
            }
        }
    }
    __syncthreads();
    const int ni = s_ni, nc = s_nc;
    const int ncc = (nc < CAPC) ? nc : CAPC;
    const bool fI = (ni > CAPI);

    // ---- parallel single-wave merges: wave 0 = cost, wave 1 = iou ----
    if (wid == 0) {
        u64 lf[KTOP];
        #pragma unroll
        for (int s = 0; s < KTOP; ++s) lf[s] = ~0ull;
        for (int k = lane; k < ncc; k += 64) {   // <=8 per lane; 13-deep list complete
            int i = lcost[k];
            float4 pb = pbp[2 * i];
            float4 p2 = pbp[2 * i + 1];
            float areap = (pb.z - pb.x) * (pb.w - pb.y);
            float iou = iou_exact(pb, areap, gx1, gy1, gx2, gy2, areag);
            float ec = cost_exact(p2, gcx, gcy, scores[(size_t)i * NCLS + lab], iou);
            u64 ck = (((u64)__float_as_uint(ec)) << 32) | (unsigned)i;
            if (ck < lf[KTOP - 1]) {
                lf[KTOP - 1] = ck;
                #pragma unroll
                for (int s = KTOP - 1; s > 0; --s)
                    if (lf[s] < lf[s - 1]) { u64 t = lf[s]; lf[s] = lf[s - 1]; lf[s - 1] = t; }
            }
        }
        wave_merge_minN<KTOP>(lf, csel, lane);
        if (lane == 0) {
            u64 tk = csel[KTOP - 1];
            int mode; float dmax = 0.0f;
            if (tk == ~0ull) mode = 2;               // <13 candidates in RFIX ball
            else {
                float tau = __uint_as_float((unsigned)(tk >> 32));
                if (!(tau < 9.0e7f)) mode = 2;       // INF-ambiguity zone
                else {
                    dmax = 3.0f + __log2f(tau + 1e-5f) * (1.0f / L10) + 4e-3f;
                    mode = (dmax > RFIX || nc > CAPC) ? 1 : 0;
                }
            }
            s_mode = mode; s_dmax = dmax;
        }
    } else if (wid == 1 && !fI) {
        float lf[KTOP];
        #pragma unroll
        for (int s = 0; s < KTOP; ++s) lf[s] = NEGINF;
        int nn = (ni < CAPI) ? ni : CAPI;
        for (int k = lane; k < nn; k += 64) {    // <=24 per lane; 13-deep retains any lane's top-13
            float v = liou[k];
            if (v > lf[0]) {
                lf[0] = v;
                #pragma unroll
                for (int s = 0; s < KTOP - 1; ++s)
                    if (lf[s] > lf[s + 1]) { float t = lf[s]; lf[s] = lf[s + 1]; lf[s + 1] = t; }
            }
        }
        wave_merge_max13_f32<KTOP>(lf, part_iou + ((size_t)j * SLC + slice) * KTOP, lane);
    }
    __syncthreads();

    if (fI) {   // rare: iou list overflowed -> exact full-slice scan (two-stage merge)
        float lf[KTOP];
        #pragma unroll
        for (int s = 0; s < KTOP; ++s) lf[s] = NEGINF;
        for (int i = base + tid; i < base + SLEN; i += SCN_T) {
            float4 pb = pbp[2 * i];
            float areap = (pb.z - pb.x) * (pb.w - pb.y);
            float iou = iou_exact(pb, areap, gx1, gy1, gx2, gy2, areag);
            if (iou > lf[0]) {
                lf[0] = iou;
                #pragma unroll
                for (int s = 0; s < KTOP - 1; ++s)
                    if (lf[s] > lf[s + 1]) { float t = lf[s]; lf[s] = lf[s + 1]; lf[s + 1] = t; }
            }
        }
        wave_merge_max13_f32<KTOP>(lf, &wiof[wid * KTOP], lane);
        __syncthreads();
        if (wid == 0) {
            float* dpi = part_iou + ((size_t)j * SLC + slice) * KTOP;
            int p = 0;
            for (int r = 0; r < KTOP; ++r) {
                float cur = (lane < NW8 && p < KTOP) ? wiof[lane * KTOP + p] : NEGINF;
                float bm = wave_max_bc_f32(cur);
                u64 m = __ballot(cur == bm && bm != NEGINF);
                int first = __ffsll(m) - 1;
                if (lane == first) p++;
                if (lane == 0) dpi[r] = bm;
            }
        }
        __syncthreads();
    }

    int mode = s_mode;
    if (mode == 1) {   // re-collect at the sound radius Dmax' (rare)
        const float dmax = s_dmax;
        if (tid == 0) s_nc = 0;
        __syncthreads();
        for (int i = base + tid; i < base + SLEN; i += SCN_T) {
            float4 p2 = pbp[2 * i + 1];
            if (p2.w != 0.0f) {
                float dx = p2.x - gcx, dy = p2.y - gcy;
                float rad = p2.z * dmax;
                if (dx * dx + dy * dy <= rad * rad * (1.0f + 1e-5f)) {
                    int p = atomicAdd(&s_nc, 1);
                    if (p < CAPC) lcost[p] = i;
                }
            }
        }
        __syncthreads();
        int nc2 = s_nc;
        if (nc2 <= CAPC) {
            if (wid == 0) {
                u64 lf[KTOP];
                #pragma unroll
                for (int s = 0; s < KTOP; ++s) lf[s] = ~0ull;
                for (int k = lane; k < nc2; k += 64) {
                    int i = lcost[k];
                    float4 pb = pbp[2 * i];
                    float4 p2 = pbp[2 * i + 1];
                    float areap = (pb.z - pb.x) * (pb.w - pb.y);
                    float iou = iou_exact(pb, areap, gx1, gy1, gx2, gy2, areag);
                    float ec = cost_exact(p2, gcx, gcy, scores[(size_t)i * NCLS + lab], iou);
                    u64 ck = (((u64)__float_as_uint(ec)) << 32) | (unsigned)i;
                    if (ck < lf[KTOP - 1]) {
                        lf[KTOP - 1] = ck;
                        #pragma unroll
                        for (int s = KTOP - 1; s > 0; --s)
                            if (lf[s] < lf[s - 1]) { u64 t = lf[s]; lf[s] = lf[s - 1]; lf[s - 1] = t; }
                    }
                }
                wave_merge_minN<KTOP>(lf, csel, lane);
            }
        } else {
            mode = 2;   // uniform (s_nc shared)
        }
        __syncthreads();
    }
    if (mode == 2) {   // exact full slice scan (round-2 semantics; correctness net)
        u64 lf[KTOP];
        #pragma unroll
        for (int s = 0; s < KTOP; ++s) lf[s] = ~0ull;
        for (int i = base + tid; i < base + SLEN; i += SCN_T) {
            float4 pb = pbp[2 * i];
            float4 p2 = pbp[2 * i + 1];
            float areap = (pb.z - pb.x) * (pb.w - pb.y);
            float iou = iou_exact(pb, areap, gx1, gy1, gx2, gy2, areag);
            float ec = INF_F;
            if (p2.w != 0.0f) ec = cost_exact(p2, gcx, gcy, scores[(size_t)i * NCLS + lab], iou);
            u64 k2 = (((u64)__float_as_uint(ec)) << 32) | (unsigned)i;
            if (k2 < lf[KTOP - 1]) {
                lf[KTOP - 1] = k2;
                #pragma unroll
                for (int s = KTOP - 1; s > 0; --s)
                    if (lf[s] < lf[s - 1]) { u64 t = lf[s]; lf[s] = lf[s - 1]; lf[s - 1] = t; }
            }
        }
        wave_merge_minN<KTOP>(lf, &wco[wid * KTOP], lane);
        __syncthreads();
        if (wid == 0) {
            int p = 0;
            for (int r = 0; r < KTOP; ++r) {
                u64 cur = (lane < NW8 && p < KTOP) ? wco[lane * KTOP + p] : ~0ull;
                u64 bm = wave_min_bc_u64(cur);
                if (cur == bm && bm != ~0ull) p++;
                if (lane == 0) csel[r] = bm;
            }
        }
        __syncthreads();
    }
    if (tid < KTOP) {
        u64* dpc = part_cost + ((size_t)j * SLC + slice) * KTOP;
        dpc[tid] = csel[tid];
    }
}

// ---------- merge 4 slices per GT, compute ks, scatter ----------
__global__ __launch_bounds__(64) void k_merge(
        const float* __restrict__ part_iou, const u64* __restrict__ part_cost,
        int* count, int* firstgt) {
    const int j = blockIdx.x;
    const int lane = threadIdx.x;
    float vi = (lane < SLC * KTOP) ? part_iou[(size_t)j * SLC * KTOP + lane] : NEGINF;
    float tsum = 0.0f;
    for (int r = 0; r < KTOP; ++r) {
        float bm = wave_max_bc_f32(vi);
        u64 m = __ballot(vi == bm && bm != NEGINF);
        int first = __ffsll(m) - 1;
        if (lane == first) vi = NEGINF;
        tsum += (bm == NEGINF) ? 0.0f : bm;   // descending-order sum (missing = 0, as ref)
    }
    int ks = (int)tsum;
    if (ks < 1) ks = 1;
    u64 kc = (lane < SLC * KTOP) ? part_cost[(size_t)j * SLC * KTOP + lane] : ~0ull;
    u64 mine = ~0ull;
    for (int r = 0; r < KTOP; ++r) {
        u64 bm = wave_min_bc_u64(kc);
        if (kc == bm && bm != ~0ull) kc = ~0ull;
        if (lane == r) mine = bm;
    }
    if (lane < KTOP && lane < ks && mine != ~0ull) {
        int idx = (int)(unsigned)(mine & 0xFFFFFFFFull);
        atomicAdd(&count[idx], 1);
        atomicMin(&firstgt[idx], j);
    }
}

// ---------- per-prior finalize; multi-matched priors -> worklist ----------
__global__ __launch_bounds__(256) void k_assign(
        const float4* __restrict__ pbp, const float* __restrict__ gt,
        const void* labels, const int* flag,
        const int* __restrict__ count, const int* __restrict__ firstgt,
        int* nmulti, int* mlist, float* __restrict__ out) {
    __shared__ float4 gbox[NGT];
    __shared__ int glab[NGT];
    __shared__ float gareas[NGT];
    int tid = threadIdx.x;
    int is64 = *flag;
    {
        float4 b = ((const float4*)gt)[tid];
        gbox[tid] = b;
        glab[tid] = get_label(labels, tid, is64);
        gareas[tid] = (b.z - b.x) * (b.w - b.y);
    }
    __syncthreads();
    int i = blockIdx.x * 256 + tid;
    if (i >= NPRI) return;
    float4 p2 = pbp[2 * i + 1];
    int v = (p2.w != 0.0f) ? 1 : 0;
    int c = count[i];
    float o0 = 0.0f, o1 = -INF_F, o2 = -1.0f;
    if (v && c == 1) {
        int j = firstgt[i];
        float4 pb = pbp[2 * i];
        float areap = (pb.z - pb.x) * (pb.w - pb.y);
        float4 g = gbox[j];
        float iw = fmaxf(fminf(pb.z, g.z) - fmaxf(pb.x, g.x), 0.0f);
        float ih = fmaxf(fminf(pb.w, g.w) - fmaxf(pb.y, g.y), 0.0f);
        float inter = iw * ih;
        float iou = inter / fmaxf(areap + gareas[j] - inter, 1e-6f);
        o0 = (float)(j + 1); o1 = iou; o2 = (float)glab[j];
    } else if (v && c > 1) {
        int pos = atomicAdd(nmulti, 1);
        mlist[pos] = i;
    }
    out[i] = o0;
    out[NPRI + i] = o1;
    out[2 * NPRI + i] = o2;
}

// ---------- one block per multi prior: block argmin over 256 GT costs ----------
__global__ __launch_bounds__(256) void k_multi(
        const float* __restrict__ scores,
        const float4* __restrict__ pbp, const float* __restrict__ gt,
        const void* labels, const int* flag,
        const int* __restrict__ nmulti, const int* __restrict__ mlist,
        float* __restrict__ out) {
    __shared__ float4 gbox[NGT];
    __shared__ int glab[NGT];
    __shared__ float gcxs[NGT], gcys[NGT], gareas[NGT];
    __shared__ u64 red4[4];
    const int tid = threadIdx.x;
    const int is64 = *flag;
    {
        float4 b = ((const float4*)gt)[tid];
        gbox[tid] = b;
        glab[tid] = get_label(labels, tid, is64);
        gcxs[tid] = (b.x + b.z) * 0.5f;
        gcys[tid] = (b.y + b.w) * 0.5f;
        gareas[tid] = (b.z - b.x) * (b.w - b.y);
    }
    __syncthreads();
    const int nm = *nmulti;
    const int j = tid;
    for (int m = blockIdx.x; m < nm; m += gridDim.x) {
        const int i = mlist[m];
        float4 pb = pbp[2 * i];
        float4 p2 = pbp[2 * i + 1];
        float areap = (pb.z - pb.x) * (pb.w - pb.y);

        float4 g = gbox[j];
        float iw = fmaxf(fminf(pb.z, g.z) - fmaxf(pb.x, g.x), 0.0f);
        float ih = fmaxf(fminf(pb.w, g.w) - fmaxf(pb.y, g.y), 0.0f);
        float inter = iw * ih;
        float iou = inter / fmaxf(areap + gareas[j] - inter, 1e-6f);
        float dx = p2.x - gcxs[j], dy = p2.y - gcys[j];
        float dist = sqrtf(dx * dx + dy * dy) / p2.z;
        float soft = exp2f((dist - 3.0f) * L10);
        float l = scores[(size_t)i * NCLS + glab[j]];
        float sig = 1.0f / (1.0f + expf(-l));
        float dd = iou - sig;
        float bce = fmaxf(l, 0.0f) - l * iou + log1pf(expf(-fabsf(l)));
        float cost = bce * (dd * dd) + (-logf(iou + EPS_F) * 3.0f) + soft;

        u64 key = (((u64)__float_as_uint(cost)) << 32) | (unsigned)j;
        u64 v = key;
        #pragma unroll
        for (int off = 32; off > 0; off >>= 1) {
            u64 o = __shfl_down(v, off, 64);
            v = (o < v) ? o : v;
        }
        if ((tid & 63) == 0) red4[tid >> 6] = v;
        __syncthreads();
        u64 best = red4[0];
        #pragma unroll
        for (int q = 1; q < 4; ++q) best = (red4[q] < best) ? red4[q] : best;
        if (key == best) {
            out[i] = (float)(j + 1);
            out[NPRI + i] = iou;
            out[2 * NPRI + i] = (float)glab[j];
        }
        __syncthreads();
    }
}

extern "C" void kernel_launch(void* const* d_in, const int* in_sizes, int n_in,
                              void* d_out, int out_size, void* d_ws, size_t ws_size,
                              hipStream_t stream) {
    const float* scores = (const float*)d_in[0];
    const float* priors = (const float*)d_in[1];
    const float* pboxes = (const float*)d_in[2];
    const float* gt     = (const float*)d_in[3];
    const void*  labels = d_in[4];
    float* out = (float*)d_out;

    char* ws = (char*)d_ws;
    size_t off = 0;
    auto alloc = [&](size_t bytes) { size_t o = off; off = (off + bytes + 255) & ~(size_t)255; return o; };
    int*    flag     = (int*)(ws + alloc(4));
    int*    nmulti   = (int*)(ws + alloc(4));
    int*    count    = (int*)(ws + alloc((size_t)NPRI * 4));
    int*    firstgt  = (int*)(ws + alloc((size_t)NPRI * 4));
    int*    mlist    = (int*)(ws + alloc((size_t)NPRI * 4));
    float*  part_iou = (float*)(ws + alloc((size_t)NGT * SLC * KTOP * 4));
    u64*    part_cost= (u64*)(ws + alloc((size_t)NGT * SLC * KTOP * 8));
    float4* pbp      = (float4*)(ws + alloc((size_t)NPRI * 32));
    (void)ws_size;

    hipLaunchKernelGGL(k_prep, dim3(PREP_BLKS), dim3(256), 0, stream,
                       priors, gt, labels, pboxes, pbp, count, firstgt, flag, nmulti);
    hipLaunchKernelGGL(k_scan, dim3(NGT, SLC), dim3(SCN_T), 0, stream,
                       scores, pbp, gt, labels, flag, part_iou, part_cost);
    hipLaunchKernelGGL(k_merge, dim3(NGT), dim3(64), 0, stream,
                       part_iou, part_cost, count, firstgt);
    hipLaunchKernelGGL(k_assign, dim3((NPRI + 255) / 256), dim3(256), 0, stream,
                       pbp, gt, labels, flag, count, firstgt, nmulti, mlist, out);
    hipLaunchKernelGGL(k_multi, dim3(256), dim3(256), 0, stream,
                       scores, pbp, gt, labels, flag, nmulti, mlist, out);
}